// Round 1
// baseline (516.075 us; speedup 1.0000x reference)
//
#include <hip/hip_runtime.h>
#include <stdint.h>
#include <math.h>

#define DEVI __device__ __forceinline__

typedef __attribute__((ext_vector_type(8))) short sv8;
typedef __attribute__((ext_vector_type(4))) short sv4;
typedef __attribute__((ext_vector_type(4))) float fv4;

typedef __attribute__((address_space(1))) void av1_t;
typedef __attribute__((address_space(3))) void av3_t;

constexpr int Bb = 2, Tt = 2048, Ee = 1024, Hh = 16, Dd = 64, FFd = 4096;
constexpr int NN = Bb * Tt;  // 4096 token rows
constexpr float EPSv = 1e-5f;

DEVI float b2f(unsigned short s) {
  union { unsigned u; float f; } v; v.u = ((unsigned)s) << 16; return v.f;
}
DEVI unsigned short f2b(float f) {
  union { float f; unsigned u; } v; v.f = f;
  return (unsigned short)((v.u + 0x7FFFu + ((v.u >> 16) & 1u)) >> 16);
}

// global -> LDS direct (16B per lane). LDS dest must be wave-uniform base + lane*16.
DEVI void load_lds16(const void* g, void* s) {
  __builtin_amdgcn_global_load_lds((av1_t*)(unsigned long long)g,
                                   (av3_t*)(unsigned)(unsigned long long)s,
                                   16, 0, 0);
}

// ---------------- fp32 -> bf16 convert ----------------
__global__ __launch_bounds__(256) void cvt_kernel(const float* __restrict__ in,
                                                  unsigned short* __restrict__ out, int n) {
  int i = (blockIdx.x * 256 + threadIdx.x) * 4;
  if (i >= n) return;
  float4 v = *(const float4*)(in + i);
  sv4 o;
  o[0] = (short)f2b(v.x); o[1] = (short)f2b(v.y);
  o[2] = (short)f2b(v.z); o[3] = (short)f2b(v.w);
  *(sv4*)(out + i) = o;
}

// ---------------- LayerNorm (fp32 in, bf16 out), one block per row ----------------
__global__ __launch_bounds__(256) void ln_kernel(const float* __restrict__ x,
                                                 const float* __restrict__ g,
                                                 const float* __restrict__ b,
                                                 unsigned short* __restrict__ out) {
  const int row = blockIdx.x, tid = threadIdx.x;
  const float4 v = *(const float4*)(x + (size_t)row * Ee + tid * 4);
  float s = v.x + v.y + v.z + v.w;
  float ss = v.x * v.x + v.y * v.y + v.z * v.z + v.w * v.w;
#pragma unroll
  for (int off = 32; off; off >>= 1) { s += __shfl_down(s, off); ss += __shfl_down(ss, off); }
  __shared__ float red[16];
  const int w = tid >> 6, l = tid & 63;
  if (l == 0) { red[w] = s; red[8 + w] = ss; }
  __syncthreads();
  s = red[0] + red[1] + red[2] + red[3];
  ss = red[8] + red[9] + red[10] + red[11];
  const float mean = s * (1.f / Ee);
  const float rstd = rsqrtf(ss * (1.f / Ee) - mean * mean + EPSv);
  const float4 gv = *(const float4*)(g + tid * 4);
  const float4 bv = *(const float4*)(b + tid * 4);
  sv4 o;
  o[0] = (short)f2b((v.x - mean) * rstd * gv.x + bv.x);
  o[1] = (short)f2b((v.y - mean) * rstd * gv.y + bv.y);
  o[2] = (short)f2b((v.z - mean) * rstd * gv.z + bv.z);
  o[3] = (short)f2b((v.w - mean) * rstd * gv.w + bv.w);
  *(sv4*)(out + (size_t)row * Ee + tid * 4) = o;
}

// ---------------- bf16 GEMM: C[n,m] = sum_k A[n,k]*B[m,k] (+bias) (+res, fp32 out) ----
// 128x128 tile, BK=32, 4 waves (2x2), each wave 64x64 via 4x4 16x16x32 MFMA frags.
template <int OUTF32, int HASBIAS>
__global__ __launch_bounds__(256) void gemm_bt(const unsigned short* __restrict__ A,
                                               const unsigned short* __restrict__ Bw,
                                               void* __restrict__ Cout,
                                               const float* __restrict__ bias,
                                               const float* __restrict__ res,
                                               int M, int K) {
  __shared__ unsigned short lA[128 * 32];
  __shared__ unsigned short lB[128 * 32];
  const int tid = threadIdx.x;
  const int l = tid & 63, w = tid >> 6;
  const int wr = w >> 1, wc = w & 1;
  const int rowbase = blockIdx.y * 128, colbase = blockIdx.x * 128;

  const fv4 zero4 = {0.f, 0.f, 0.f, 0.f};
  fv4 acc[4][4];
#pragma unroll
  for (int i = 0; i < 4; ++i)
#pragma unroll
    for (int j = 0; j < 4; ++j) acc[i][j] = zero4;

  // staging: 512 chunks of 8 bf16 per tile; thread t does chunks t and t+256.
  const int c0 = tid, c1 = tid + 256;
  const unsigned short* Ag0 = A + (size_t)(rowbase + (c0 >> 2)) * K + (c0 & 3) * 8;
  const unsigned short* Ag1 = A + (size_t)(rowbase + (c1 >> 2)) * K + (c1 & 3) * 8;
  const unsigned short* Bg0 = Bw + (size_t)(colbase + (c0 >> 2)) * K + (c0 & 3) * 8;
  const unsigned short* Bg1 = Bw + (size_t)(colbase + (c1 >> 2)) * K + (c1 & 3) * 8;

  const int nk = K >> 5;
  const int kc = (l >> 4) * 8;
  for (int kt = 0; kt < nk; ++kt) {
    __syncthreads();
    load_lds16(Ag0, lA + c0 * 8);
    load_lds16(Ag1, lA + c1 * 8);
    load_lds16(Bg0, lB + c0 * 8);
    load_lds16(Bg1, lB + c1 * 8);
    Ag0 += 32; Ag1 += 32; Bg0 += 32; Bg1 += 32;
    __syncthreads();
    sv8 af[4], bfr[4];
#pragma unroll
    for (int i = 0; i < 4; ++i)
      af[i] = *(const sv8*)(lA + (wr * 64 + i * 16 + (l & 15)) * 32 + kc);
#pragma unroll
    for (int i = 0; i < 4; ++i)
      bfr[i] = *(const sv8*)(lB + (wc * 64 + i * 16 + (l & 15)) * 32 + kc);
#pragma unroll
    for (int mi = 0; mi < 4; ++mi)
#pragma unroll
      for (int ni = 0; ni < 4; ++ni)
        acc[mi][ni] = __builtin_amdgcn_mfma_f32_16x16x32_bf16(af[mi], bfr[ni], acc[mi][ni], 0, 0, 0);
  }

  // C/D layout: col = lane&15, row = (lane>>4)*4 + j   [measured m89/m91]
  const int r0 = rowbase + wr * 64 + ((l >> 4) * 4);
  const int ccol = colbase + wc * 64 + (l & 15);
#pragma unroll
  for (int mi = 0; mi < 4; ++mi) {
#pragma unroll
    for (int j = 0; j < 4; ++j) {
      const size_t r = (size_t)(r0 + mi * 16 + j);
#pragma unroll
      for (int ni = 0; ni < 4; ++ni) {
        const int c = ccol + ni * 16;
        float vv = acc[mi][ni][j];
        if (HASBIAS) vv += bias[c];
        if (OUTF32) {
          ((float*)Cout)[r * M + c] = res[r * M + c] + vv;
        } else {
          ((unsigned short*)Cout)[r * M + c] = f2b(vv);
        }
      }
    }
  }
}

// ---------------- flash attention: 1 block = (b, h, 64 q-rows), 4 waves x 16 rows ---
__global__ __launch_bounds__(256) void attn_kernel(const unsigned short* __restrict__ Q,
                                                   const unsigned short* __restrict__ Kb,
                                                   const unsigned short* __restrict__ Vb,
                                                   unsigned short* __restrict__ O) {
  const int bh = blockIdx.y;
  const int b = bh / Hh, h = bh % Hh;
  const int q0 = blockIdx.x * 64;
  const int tid = threadIdx.x, l = tid & 63, w = tid >> 6;
  const size_t base = (size_t)b * Tt * Ee + (size_t)h * Dd;

  __shared__ unsigned short Kt[64 * 64];
  __shared__ unsigned short Vt[64 * 64];
  __shared__ unsigned short Pt[4][16 * 64];

  // Q fragments held in registers: A-layout row = l&15, k-chunk = (l>>4)*8
  sv8 qf0, qf1;
  {
    const unsigned short* qp = Q + base + (size_t)(q0 + w * 16 + (l & 15)) * Ee + (l >> 4) * 8;
    qf0 = *(const sv8*)qp;
    qf1 = *(const sv8*)(qp + 32);
  }

  const fv4 zero4 = {0.f, 0.f, 0.f, 0.f};
  fv4 acc_o[4];
#pragma unroll
  for (int i = 0; i < 4; ++i) acc_o[i] = zero4;
  float Mx[4], Lx[4];
#pragma unroll
  for (int j = 0; j < 4; ++j) { Mx[j] = -INFINITY; Lx[j] = 0.f; }

  const int c0 = tid, c1 = tid + 256;
  const int r0c = c0 >> 3, x0c = (c0 & 7) * 8;
  const int r1c = c1 >> 3, x1c = (c1 & 7) * 8;

  for (int kt = 0; kt < Tt / 64; ++kt) {
    __syncthreads();
    {
      const size_t g0 = base + (size_t)(kt * 64 + r0c) * Ee + x0c;
      const size_t g1 = base + (size_t)(kt * 64 + r1c) * Ee + x1c;
      load_lds16(Kb + g0, Kt + c0 * 8);
      load_lds16(Kb + g1, Kt + c1 * 8);
      load_lds16(Vb + g0, Vt + c0 * 8);
      load_lds16(Vb + g1, Vt + c1 * 8);
    }
    __syncthreads();

    // S = Q K^T (per wave: 16 q-rows x 64 k-cols)
    fv4 s[4];
#pragma unroll
    for (int ks = 0; ks < 4; ++ks) {
      const sv8 kf0 = *(const sv8*)(Kt + (ks * 16 + (l & 15)) * 64 + (l >> 4) * 8);
      const sv8 kf1 = *(const sv8*)(Kt + (ks * 16 + (l & 15)) * 64 + 32 + (l >> 4) * 8);
      fv4 t = zero4;
      t = __builtin_amdgcn_mfma_f32_16x16x32_bf16(qf0, kf0, t, 0, 0, 0);
      t = __builtin_amdgcn_mfma_f32_16x16x32_bf16(qf1, kf1, t, 0, 0, 0);
      s[ks] = t;
    }

    // online softmax (rows live on 16-lane groups; reduce with shfl_xor width 16)
    float mnew[4], alpha[4], ls[4];
#pragma unroll
    for (int j = 0; j < 4; ++j) {
      float mt = fmaxf(fmaxf(s[0][j], s[1][j]), fmaxf(s[2][j], s[3][j])) * 0.125f;
#pragma unroll
      for (int off = 1; off < 16; off <<= 1) mt = fmaxf(mt, __shfl_xor(mt, off, 16));
      mnew[j] = fmaxf(Mx[j], mt);
      alpha[j] = __expf(Mx[j] - mnew[j]);
      Mx[j] = mnew[j];
      ls[j] = 0.f;
    }
#pragma unroll
    for (int ks = 0; ks < 4; ++ks)
#pragma unroll
      for (int j = 0; j < 4; ++j) {
        const float p = __expf(s[ks][j] * 0.125f - mnew[j]);
        s[ks][j] = p;
        ls[j] += p;
      }
#pragma unroll
    for (int j = 0; j < 4; ++j) {
      float t = ls[j];
#pragma unroll
      for (int off = 1; off < 16; off <<= 1) t += __shfl_xor(t, off, 16);
      Lx[j] = Lx[j] * alpha[j] + t;
    }
    // P: C-layout -> per-wave LDS [16 q][64 k] so PV can read A-layout
#pragma unroll
    for (int ks = 0; ks < 4; ++ks)
#pragma unroll
      for (int j = 0; j < 4; ++j)
        Pt[w][((l >> 4) * 4 + j) * 64 + ks * 16 + (l & 15)] = f2b(s[ks][j]);
#pragma unroll
    for (int dsb = 0; dsb < 4; ++dsb)
#pragma unroll
      for (int j = 0; j < 4; ++j) acc_o[dsb][j] *= alpha[j];
    asm volatile("s_waitcnt lgkmcnt(0)" ::: "memory");

    // O += P V  (V frag: strided scalar LDS reads — correctness-first)
#pragma unroll
    for (int kcn = 0; kcn < 2; ++kcn) {
      const sv8 pf = *(const sv8*)(&Pt[w][(l & 15) * 64 + kcn * 32 + (l >> 4) * 8]);
#pragma unroll
      for (int dsb = 0; dsb < 4; ++dsb) {
        sv8 vf;
#pragma unroll
        for (int j = 0; j < 8; ++j)
          vf[j] = (short)Vt[(kcn * 32 + (l >> 4) * 8 + j) * 64 + dsb * 16 + (l & 15)];
        acc_o[dsb] = __builtin_amdgcn_mfma_f32_16x16x32_bf16(pf, vf, acc_o[dsb], 0, 0, 0);
      }
    }
  }

#pragma unroll
  for (int j = 0; j < 4; ++j) {
    const float inv = 1.f / Lx[j];
    unsigned short* op = O + base + (size_t)(q0 + w * 16 + (l >> 4) * 4 + j) * Ee;
#pragma unroll
    for (int dsb = 0; dsb < 4; ++dsb)
      op[dsb * 16 + (l & 15)] = f2b(acc_o[dsb][j] * inv);
  }
}

// ---------------- GEGLU: f = a * gelu_exact(g) ----------------
__global__ __launch_bounds__(256) void geglu_kernel(const unsigned short* __restrict__ u,
                                                    unsigned short* __restrict__ f) {
  const int t = blockIdx.x * 256 + threadIdx.x;
  const int n = t >> 10;            // FFd/4 = 1024 threads per row
  const int j4 = (t & 1023) * 4;
  const unsigned short* ua = u + (size_t)n * (2 * FFd) + j4;
  const sv4 av = *(const sv4*)ua;
  const sv4 gv = *(const sv4*)(ua + FFd);
  sv4 o;
#pragma unroll
  for (int i = 0; i < 4; ++i) {
    const float a = b2f((unsigned short)av[i]);
    const float g = b2f((unsigned short)gv[i]);
    o[i] = (short)f2b(a * 0.5f * g * (1.f + erff(g * 0.70710678118654752f)));
  }
  *(sv4*)(f + (size_t)n * FFd + j4) = o;
}

extern "C" void kernel_launch(void* const* d_in, const int* in_sizes, int n_in,
                              void* d_out, int out_size, void* d_ws, size_t ws_size,
                              hipStream_t stream) {
  (void)in_sizes; (void)n_in; (void)out_size; (void)ws_size;
  const float* src  = (const float*)d_in[0];
  const float* Wq   = (const float*)d_in[1];
  const float* Wk   = (const float*)d_in[2];
  const float* Wv   = (const float*)d_in[3];
  const float* Wo   = (const float*)d_in[4];
  const float* W1   = (const float*)d_in[5];
  const float* b1   = (const float*)d_in[6];
  const float* W2   = (const float*)d_in[7];
  const float* b2   = (const float*)d_in[8];
  const float* ln1w = (const float*)d_in[9];
  const float* ln1b = (const float*)d_in[10];
  const float* ln2w = (const float*)d_in[11];
  const float* ln2b = (const float*)d_in[12];
  float* out = (float*)d_out;

  char* ws = (char*)d_ws;
  size_t off = 0;
  auto alloc = [&](size_t bytes) { char* p = ws + off; off += bytes; return p; };
  unsigned short* wq16 = (unsigned short*)alloc((size_t)Ee * Ee * 2);
  unsigned short* wk16 = (unsigned short*)alloc((size_t)Ee * Ee * 2);
  unsigned short* wv16 = (unsigned short*)alloc((size_t)Ee * Ee * 2);
  unsigned short* wo16 = (unsigned short*)alloc((size_t)Ee * Ee * 2);
  unsigned short* w116 = (unsigned short*)alloc((size_t)2 * FFd * Ee * 2);
  unsigned short* w216 = (unsigned short*)alloc((size_t)Ee * FFd * 2);
  unsigned short* h16  = (unsigned short*)alloc((size_t)NN * Ee * 2);
  unsigned short* q16  = (unsigned short*)alloc((size_t)NN * Ee * 2);
  unsigned short* k16  = (unsigned short*)alloc((size_t)NN * Ee * 2);
  unsigned short* v16  = (unsigned short*)alloc((size_t)NN * Ee * 2);
  unsigned short* a16  = (unsigned short*)alloc((size_t)NN * Ee * 2);
  float* xbuf          = (float*)alloc((size_t)NN * Ee * 4);
  unsigned short* u16  = (unsigned short*)alloc((size_t)NN * 2 * FFd * 2);
  unsigned short* f16  = q16;  // reuse q/k/v/attn region (32 MB) after attention done

  dim3 blk(256);
  cvt_kernel<<<dim3(Ee * Ee / 1024), blk, 0, stream>>>(Wq, wq16, Ee * Ee);
  cvt_kernel<<<dim3(Ee * Ee / 1024), blk, 0, stream>>>(Wk, wk16, Ee * Ee);
  cvt_kernel<<<dim3(Ee * Ee / 1024), blk, 0, stream>>>(Wv, wv16, Ee * Ee);
  cvt_kernel<<<dim3(Ee * Ee / 1024), blk, 0, stream>>>(Wo, wo16, Ee * Ee);
  cvt_kernel<<<dim3(2 * FFd * Ee / 1024), blk, 0, stream>>>(W1, w116, 2 * FFd * Ee);
  cvt_kernel<<<dim3(Ee * FFd / 1024), blk, 0, stream>>>(W2, w216, Ee * FFd);

  ln_kernel<<<dim3(NN), blk, 0, stream>>>(src, ln1w, ln1b, h16);

  gemm_bt<0, 0><<<dim3(Ee / 128, NN / 128), blk, 0, stream>>>(h16, wq16, q16, nullptr, nullptr, Ee, Ee);
  gemm_bt<0, 0><<<dim3(Ee / 128, NN / 128), blk, 0, stream>>>(h16, wk16, k16, nullptr, nullptr, Ee, Ee);
  gemm_bt<0, 0><<<dim3(Ee / 128, NN / 128), blk, 0, stream>>>(h16, wv16, v16, nullptr, nullptr, Ee, Ee);

  attn_kernel<<<dim3(Tt / 64, Bb * Hh), blk, 0, stream>>>(q16, k16, v16, a16);

  gemm_bt<1, 0><<<dim3(Ee / 128, NN / 128), blk, 0, stream>>>(a16, wo16, xbuf, nullptr, src, Ee, Ee);

  ln_kernel<<<dim3(NN), blk, 0, stream>>>(xbuf, ln2w, ln2b, h16);

  gemm_bt<0, 1><<<dim3(2 * FFd / 128, NN / 128), blk, 0, stream>>>(h16, w116, u16, b1, nullptr, 2 * FFd, Ee);

  geglu_kernel<<<dim3(NN * FFd / 1024), blk, 0, stream>>>(u16, f16);

  gemm_bt<1, 1><<<dim3(Ee / 128, NN / 128), blk, 0, stream>>>(f16, w216, out, b2, xbuf, Ee, FFd);
}

// Round 2
// 471.915 us; speedup vs baseline: 1.0936x; 1.0936x over previous
//
#include <hip/hip_runtime.h>
#include <stdint.h>
#include <math.h>

#define DEVI __device__ __forceinline__

typedef __attribute__((ext_vector_type(8))) short sv8;
typedef __attribute__((ext_vector_type(4))) short sv4;
typedef __attribute__((ext_vector_type(4))) float fv4;

typedef __attribute__((address_space(1))) void av1_t;
typedef __attribute__((address_space(3))) void av3_t;

constexpr int Bb = 2, Tt = 2048, Ee = 1024, Hh = 16, Dd = 64, FFd = 4096;
constexpr int NN = Bb * Tt;  // 4096 token rows
constexpr float EPSv = 1e-5f;

DEVI float b2f(unsigned short s) {
  union { unsigned u; float f; } v; v.u = ((unsigned)s) << 16; return v.f;
}
DEVI unsigned short f2b(float f) {
  union { float f; unsigned u; } v; v.f = f;
  return (unsigned short)((v.u + 0x7FFFu + ((v.u >> 16) & 1u)) >> 16);
}

// global -> LDS direct (16B per lane). LDS dest must be wave-uniform base + lane*16.
DEVI void load_lds16(const void* g, void* s) {
  __builtin_amdgcn_global_load_lds((av1_t*)(unsigned long long)g,
                                   (av3_t*)(unsigned)(unsigned long long)s,
                                   16, 0, 0);
}

// ---------------- fp32 -> bf16 convert ----------------
__global__ __launch_bounds__(256) void cvt_kernel(const float* __restrict__ in,
                                                  unsigned short* __restrict__ out, int n) {
  int i = (blockIdx.x * 256 + threadIdx.x) * 4;
  if (i >= n) return;
  float4 v = *(const float4*)(in + i);
  sv4 o;
  o[0] = (short)f2b(v.x); o[1] = (short)f2b(v.y);
  o[2] = (short)f2b(v.z); o[3] = (short)f2b(v.w);
  *(sv4*)(out + i) = o;
}

// ---------------- LayerNorm (fp32 in, bf16 out), one block per row ----------------
__global__ __launch_bounds__(256) void ln_kernel(const float* __restrict__ x,
                                                 const float* __restrict__ g,
                                                 const float* __restrict__ b,
                                                 unsigned short* __restrict__ out) {
  const int row = blockIdx.x, tid = threadIdx.x;
  const float4 v = *(const float4*)(x + (size_t)row * Ee + tid * 4);
  float s = v.x + v.y + v.z + v.w;
  float ss = v.x * v.x + v.y * v.y + v.z * v.z + v.w * v.w;
#pragma unroll
  for (int off = 32; off; off >>= 1) { s += __shfl_down(s, off); ss += __shfl_down(ss, off); }
  __shared__ float red[16];
  const int w = tid >> 6, l = tid & 63;
  if (l == 0) { red[w] = s; red[8 + w] = ss; }
  __syncthreads();
  s = red[0] + red[1] + red[2] + red[3];
  ss = red[8] + red[9] + red[10] + red[11];
  const float mean = s * (1.f / Ee);
  const float rstd = rsqrtf(ss * (1.f / Ee) - mean * mean + EPSv);
  const float4 gv = *(const float4*)(g + tid * 4);
  const float4 bv = *(const float4*)(b + tid * 4);
  sv4 o;
  o[0] = (short)f2b((v.x - mean) * rstd * gv.x + bv.x);
  o[1] = (short)f2b((v.y - mean) * rstd * gv.y + bv.y);
  o[2] = (short)f2b((v.z - mean) * rstd * gv.z + bv.z);
  o[3] = (short)f2b((v.w - mean) * rstd * gv.w + bv.w);
  *(sv4*)(out + (size_t)row * Ee + tid * 4) = o;
}

// ---------------- bf16 GEMM: C[n,m] = sum_k A[n,k]*B[m,k] (+bias) (+res, fp32 out) ----
// 128x128 tile, BK=32, 4 waves (2x2), each wave 64x64 via 4x4 16x16x32 MFMA frags.
template <int OUTF32, int HASBIAS>
__global__ __launch_bounds__(256) void gemm_bt(const unsigned short* __restrict__ A,
                                               const unsigned short* __restrict__ Bw,
                                               void* __restrict__ Cout,
                                               const float* __restrict__ bias,
                                               const float* __restrict__ res,
                                               int M, int K) {
  __shared__ unsigned short lA[128 * 32];
  __shared__ unsigned short lB[128 * 32];
  const int tid = threadIdx.x;
  const int l = tid & 63, w = tid >> 6;
  const int wr = w >> 1, wc = w & 1;
  const int rowbase = blockIdx.y * 128, colbase = blockIdx.x * 128;

  const fv4 zero4 = {0.f, 0.f, 0.f, 0.f};
  fv4 acc[4][4];
#pragma unroll
  for (int i = 0; i < 4; ++i)
#pragma unroll
    for (int j = 0; j < 4; ++j) acc[i][j] = zero4;

  // staging: 512 chunks of 8 bf16 per tile; thread t does chunks t and t+256.
  const int c0 = tid, c1 = tid + 256;
  const unsigned short* Ag0 = A + (size_t)(rowbase + (c0 >> 2)) * K + (c0 & 3) * 8;
  const unsigned short* Ag1 = A + (size_t)(rowbase + (c1 >> 2)) * K + (c1 & 3) * 8;
  const unsigned short* Bg0 = Bw + (size_t)(colbase + (c0 >> 2)) * K + (c0 & 3) * 8;
  const unsigned short* Bg1 = Bw + (size_t)(colbase + (c1 >> 2)) * K + (c1 & 3) * 8;

  const int nk = K >> 5;
  const int kc = (l >> 4) * 8;
  for (int kt = 0; kt < nk; ++kt) {
    __syncthreads();
    load_lds16(Ag0, lA + c0 * 8);
    load_lds16(Ag1, lA + c1 * 8);
    load_lds16(Bg0, lB + c0 * 8);
    load_lds16(Bg1, lB + c1 * 8);
    Ag0 += 32; Ag1 += 32; Bg0 += 32; Bg1 += 32;
    __syncthreads();
    sv8 af[4], bfr[4];
#pragma unroll
    for (int i = 0; i < 4; ++i)
      af[i] = *(const sv8*)(lA + (wr * 64 + i * 16 + (l & 15)) * 32 + kc);
#pragma unroll
    for (int i = 0; i < 4; ++i)
      bfr[i] = *(const sv8*)(lB + (wc * 64 + i * 16 + (l & 15)) * 32 + kc);
#pragma unroll
    for (int mi = 0; mi < 4; ++mi)
#pragma unroll
      for (int ni = 0; ni < 4; ++ni)
        acc[mi][ni] = __builtin_amdgcn_mfma_f32_16x16x32_bf16(af[mi], bfr[ni], acc[mi][ni], 0, 0, 0);
  }

  // C/D layout: col = lane&15, row = (lane>>4)*4 + j   [measured m89/m91]
  const int r0 = rowbase + wr * 64 + ((l >> 4) * 4);
  const int ccol = colbase + wc * 64 + (l & 15);
#pragma unroll
  for (int mi = 0; mi < 4; ++mi) {
#pragma unroll
    for (int j = 0; j < 4; ++j) {
      const size_t r = (size_t)(r0 + mi * 16 + j);
#pragma unroll
      for (int ni = 0; ni < 4; ++ni) {
        const int c = ccol + ni * 16;
        float vv = acc[mi][ni][j];
        if (HASBIAS) vv += bias[c];
        if (OUTF32) {
          ((float*)Cout)[r * M + c] = res[r * M + c] + vv;
        } else {
          ((unsigned short*)Cout)[r * M + c] = f2b(vv);
        }
      }
    }
  }
}

// ---------------- flash attention: 1 block = (b, h, 64 q-rows), 4 waves x 16 rows ---
// LDS bank-conflict-free layouts:
//   Kt[row][kchunk]: stored with kchunk' = kchunk ^ (row&7), realized by pre-swizzling
//                    the global_load_lds SOURCE (LDS dest stays linear; rule #21).
//   Vt[d][kchunk]  : transposed V, reg-staged; kchunk' = kchunk ^ (d&7) ^ ((d>>3)&7)
//                    (writes: d&7==j const, d>>3==lane&7 -> 2 lanes/bank = free;
//                     reads: surjective 3-bit map -> LDS minimum).
//   Pt[q][kchunk]  : kchunk' = kchunk ^ (q&7)  (writes 4-way, reads free).
__global__ __launch_bounds__(256) void attn_kernel(const unsigned short* __restrict__ Q,
                                                   const unsigned short* __restrict__ Kb,
                                                   const unsigned short* __restrict__ Vb,
                                                   unsigned short* __restrict__ O) {
  const int bh = blockIdx.y;
  const int b = bh / Hh, h = bh % Hh;
  const int q0 = blockIdx.x * 64;
  const int tid = threadIdx.x, l = tid & 63, w = tid >> 6;
  const size_t base = (size_t)b * Tt * Ee + (size_t)h * Dd;

  __shared__ unsigned short Kt[64 * 64];
  __shared__ unsigned short Vt[64 * 64];
  __shared__ unsigned short Pt[4][16 * 64];

  // Q fragments held in registers: A-layout row = l&15, k-chunk = (l>>4)*8
  sv8 qf0, qf1;
  {
    const unsigned short* qp = Q + base + (size_t)(q0 + w * 16 + (l & 15)) * Ee + (l >> 4) * 8;
    qf0 = *(const sv8*)qp;
    qf1 = *(const sv8*)(qp + 32);
  }

  const fv4 zero4 = {0.f, 0.f, 0.f, 0.f};
  fv4 acc_o[4];
#pragma unroll
  for (int i = 0; i < 4; ++i) acc_o[i] = zero4;
  float Mx[4], Lx[4];
#pragma unroll
  for (int j = 0; j < 4; ++j) { Mx[j] = -INFINITY; Lx[j] = 0.f; }

  const int c0 = tid, c1 = tid + 256;
  const int r0c = c0 >> 3, xc0 = c0 & 7;   // chunk -> (row, chunk-in-row)
  const int r1c = c1 >> 3, xc1 = c1 & 7;   // xc1 == xc0

  for (int kt = 0; kt < Tt / 64; ++kt) {
    __syncthreads();
    // --- K: global->LDS direct, pre-swizzled source (chunk' = chunk ^ (row&7)) ---
    load_lds16(Kb + base + (size_t)(kt * 64 + r0c) * Ee + (xc0 ^ (r0c & 7)) * 8, Kt + c0 * 8);
    load_lds16(Kb + base + (size_t)(kt * 64 + r1c) * Ee + (xc1 ^ (r1c & 7)) * 8, Kt + c1 * 8);
    // --- V: reg-stage, write transposed+swizzled ---
    const sv8 v0 = *(const sv8*)(Vb + base + (size_t)(kt * 64 + r0c) * Ee + xc0 * 8);
    const sv8 v1 = *(const sv8*)(Vb + base + (size_t)(kt * 64 + r1c) * Ee + xc1 * 8);
#pragma unroll
    for (int j = 0; j < 8; ++j) {
      const int d = xc0 * 8 + j;  // d&7 == j, d>>3 == xc0
      Vt[d * 64 + ((((r0c >> 3) ^ j ^ xc0) & 7) * 8) + (r0c & 7)] = v0[j];
      Vt[d * 64 + ((((r1c >> 3) ^ j ^ xc1) & 7) * 8) + (r1c & 7)] = v1[j];
    }
    __syncthreads();

    // --- S = Q K^T (per wave: 16 q-rows x 64 k-cols) ---
    fv4 s[4];
    __builtin_amdgcn_s_setprio(1);
#pragma unroll
    for (int ks = 0; ks < 4; ++ks) {
      const int row = ks * 16 + (l & 15);
      const sv8 kf0 = *(const sv8*)(Kt + row * 64 + (((l >> 4) ^ (row & 7)) * 8));
      const sv8 kf1 = *(const sv8*)(Kt + row * 64 + (((4 + (l >> 4)) ^ (row & 7)) * 8));
      fv4 t = zero4;
      t = __builtin_amdgcn_mfma_f32_16x16x32_bf16(qf0, kf0, t, 0, 0, 0);
      t = __builtin_amdgcn_mfma_f32_16x16x32_bf16(qf1, kf1, t, 0, 0, 0);
      s[ks] = t;
    }
    __builtin_amdgcn_s_setprio(0);

    // --- online softmax (rows on 16-lane groups; reduce with shfl_xor width 16) ---
    float mnew[4], alpha[4], ls[4];
#pragma unroll
    for (int j = 0; j < 4; ++j) {
      float mt = fmaxf(fmaxf(s[0][j], s[1][j]), fmaxf(s[2][j], s[3][j])) * 0.125f;
#pragma unroll
      for (int off = 1; off < 16; off <<= 1) mt = fmaxf(mt, __shfl_xor(mt, off, 16));
      mnew[j] = fmaxf(Mx[j], mt);
      alpha[j] = __expf(Mx[j] - mnew[j]);
      Mx[j] = mnew[j];
      ls[j] = 0.f;
    }
#pragma unroll
    for (int ks = 0; ks < 4; ++ks)
#pragma unroll
      for (int j = 0; j < 4; ++j) {
        const float p = __expf(s[ks][j] * 0.125f - mnew[j]);
        s[ks][j] = p;
        ls[j] += p;
      }
#pragma unroll
    for (int j = 0; j < 4; ++j) {
      float t = ls[j];
#pragma unroll
      for (int off = 1; off < 16; off <<= 1) t += __shfl_xor(t, off, 16);
      Lx[j] = Lx[j] * alpha[j] + t;
    }
    // --- P: C-layout -> per-wave LDS (swizzled) so PV reads A-layout b128 ---
#pragma unroll
    for (int ks = 0; ks < 4; ++ks)
#pragma unroll
      for (int j = 0; j < 4; ++j) {
        const int q = (l >> 4) * 4 + j, k = ks * 16 + (l & 15);
        Pt[w][q * 64 + ((((k >> 3) ^ (q & 7)) & 7) * 8) + (k & 7)] = f2b(s[ks][j]);
      }
#pragma unroll
    for (int dsb = 0; dsb < 4; ++dsb)
#pragma unroll
      for (int j = 0; j < 4; ++j) acc_o[dsb][j] *= alpha[j];
    asm volatile("s_waitcnt lgkmcnt(0)" ::: "memory");

    // --- O += P V : all-vector b128 reads from swizzled Pt/Vt ---
    __builtin_amdgcn_s_setprio(1);
#pragma unroll
    for (int kcn = 0; kcn < 2; ++kcn) {
      const int qr = l & 15;
      const sv8 pf = *(const sv8*)(&Pt[w][qr * 64 + (((kcn * 4 + (l >> 4)) ^ (qr & 7)) * 8)]);
#pragma unroll
      for (int dsb = 0; dsb < 4; ++dsb) {
        const int d = dsb * 16 + (l & 15);
        const sv8 vf = *(const sv8*)(Vt + d * 64 +
                        ((((kcn * 4 + (l >> 4)) ^ (d & 7) ^ ((d >> 3) & 7)) & 7) * 8));
        acc_o[dsb] = __builtin_amdgcn_mfma_f32_16x16x32_bf16(pf, vf, acc_o[dsb], 0, 0, 0);
      }
    }
    __builtin_amdgcn_s_setprio(0);
  }

#pragma unroll
  for (int j = 0; j < 4; ++j) {
    const float inv = 1.f / Lx[j];
    unsigned short* op = O + base + (size_t)(q0 + w * 16 + (l >> 4) * 4 + j) * Ee;
#pragma unroll
    for (int dsb = 0; dsb < 4; ++dsb)
      op[dsb * 16 + (l & 15)] = f2b(acc_o[dsb][j] * inv);
  }
}

// ---------------- GEGLU: f = a * gelu_exact(g) ----------------
__global__ __launch_bounds__(256) void geglu_kernel(const unsigned short* __restrict__ u,
                                                    unsigned short* __restrict__ f) {
  const int t = blockIdx.x * 256 + threadIdx.x;
  const int n = t >> 10;            // FFd/4 = 1024 threads per row
  const int j4 = (t & 1023) * 4;
  const unsigned short* ua = u + (size_t)n * (2 * FFd) + j4;
  const sv4 av = *(const sv4*)ua;
  const sv4 gv = *(const sv4*)(ua + FFd);
  sv4 o;
#pragma unroll
  for (int i = 0; i < 4; ++i) {
    const float a = b2f((unsigned short)av[i]);
    const float g = b2f((unsigned short)gv[i]);
    o[i] = (short)f2b(a * 0.5f * g * (1.f + erff(g * 0.70710678118654752f)));
  }
  *(sv4*)(f + (size_t)n * FFd + j4) = o;
}

extern "C" void kernel_launch(void* const* d_in, const int* in_sizes, int n_in,
                              void* d_out, int out_size, void* d_ws, size_t ws_size,
                              hipStream_t stream) {
  (void)in_sizes; (void)n_in; (void)out_size; (void)ws_size;
  const float* src  = (const float*)d_in[0];
  const float* Wq   = (const float*)d_in[1];
  const float* Wk   = (const float*)d_in[2];
  const float* Wv   = (const float*)d_in[3];
  const float* Wo   = (const float*)d_in[4];
  const float* W1   = (const float*)d_in[5];
  const float* b1   = (const float*)d_in[6];
  const float* W2   = (const float*)d_in[7];
  const float* b2   = (const float*)d_in[8];
  const float* ln1w = (const float*)d_in[9];
  const float* ln1b = (const float*)d_in[10];
  const float* ln2w = (const float*)d_in[11];
  const float* ln2b = (const float*)d_in[12];
  float* out = (float*)d_out;

  char* ws = (char*)d_ws;
  size_t off = 0;
  auto alloc = [&](size_t bytes) { char* p = ws + off; off += bytes; return p; };
  unsigned short* wq16 = (unsigned short*)alloc((size_t)Ee * Ee * 2);
  unsigned short* wk16 = (unsigned short*)alloc((size_t)Ee * Ee * 2);
  unsigned short* wv16 = (unsigned short*)alloc((size_t)Ee * Ee * 2);
  unsigned short* wo16 = (unsigned short*)alloc((size_t)Ee * Ee * 2);
  unsigned short* w116 = (unsigned short*)alloc((size_t)2 * FFd * Ee * 2);
  unsigned short* w216 = (unsigned short*)alloc((size_t)Ee * FFd * 2);
  unsigned short* h16  = (unsigned short*)alloc((size_t)NN * Ee * 2);
  unsigned short* q16  = (unsigned short*)alloc((size_t)NN * Ee * 2);
  unsigned short* k16  = (unsigned short*)alloc((size_t)NN * Ee * 2);
  unsigned short* v16  = (unsigned short*)alloc((size_t)NN * Ee * 2);
  unsigned short* a16  = (unsigned short*)alloc((size_t)NN * Ee * 2);
  float* xbuf          = (float*)alloc((size_t)NN * Ee * 4);
  unsigned short* u16  = (unsigned short*)alloc((size_t)NN * 2 * FFd * 2);
  unsigned short* f16  = q16;  // reuse q/k/v/attn region (32 MB) after attention done

  dim3 blk(256);
  cvt_kernel<<<dim3(Ee * Ee / 1024), blk, 0, stream>>>(Wq, wq16, Ee * Ee);
  cvt_kernel<<<dim3(Ee * Ee / 1024), blk, 0, stream>>>(Wk, wk16, Ee * Ee);
  cvt_kernel<<<dim3(Ee * Ee / 1024), blk, 0, stream>>>(Wv, wv16, Ee * Ee);
  cvt_kernel<<<dim3(Ee * Ee / 1024), blk, 0, stream>>>(Wo, wo16, Ee * Ee);
  cvt_kernel<<<dim3(2 * FFd * Ee / 1024), blk, 0, stream>>>(W1, w116, 2 * FFd * Ee);
  cvt_kernel<<<dim3(Ee * FFd / 1024), blk, 0, stream>>>(W2, w216, Ee * FFd);

  ln_kernel<<<dim3(NN), blk, 0, stream>>>(src, ln1w, ln1b, h16);

  gemm_bt<0, 0><<<dim3(Ee / 128, NN / 128), blk, 0, stream>>>(h16, wq16, q16, nullptr, nullptr, Ee, Ee);
  gemm_bt<0, 0><<<dim3(Ee / 128, NN / 128), blk, 0, stream>>>(h16, wk16, k16, nullptr, nullptr, Ee, Ee);
  gemm_bt<0, 0><<<dim3(Ee / 128, NN / 128), blk, 0, stream>>>(h16, wv16, v16, nullptr, nullptr, Ee, Ee);

  attn_kernel<<<dim3(Tt / 64, Bb * Hh), blk, 0, stream>>>(q16, k16, v16, a16);

  gemm_bt<1, 0><<<dim3(Ee / 128, NN / 128), blk, 0, stream>>>(a16, wo16, xbuf, nullptr, src, Ee, Ee);

  ln_kernel<<<dim3(NN), blk, 0, stream>>>(xbuf, ln2w, ln2b, h16);

  gemm_bt<0, 1><<<dim3(2 * FFd / 128, NN / 128), blk, 0, stream>>>(h16, w116, u16, b1, nullptr, 2 * FFd, Ee);

  geglu_kernel<<<dim3(NN * FFd / 1024), blk, 0, stream>>>(u16, f16);

  gemm_bt<1, 1><<<dim3(Ee / 128, NN / 128), blk, 0, stream>>>(f16, w216, out, b2, xbuf, Ee, FFd);
}

// Round 4
// 442.862 us; speedup vs baseline: 1.1653x; 1.0656x over previous
//
#include <hip/hip_runtime.h>
#include <stdint.h>
#include <math.h>

#define DEVI __device__ __forceinline__

typedef __attribute__((ext_vector_type(8))) short sv8;
typedef __attribute__((ext_vector_type(4))) short sv4;
typedef __attribute__((ext_vector_type(4))) float fv4;

typedef __attribute__((address_space(1))) void av1_t;
typedef __attribute__((address_space(3))) void av3_t;

constexpr int Bb = 2, Tt = 2048, Ee = 1024, Hh = 16, Dd = 64, FFd = 4096;
constexpr int NN = Bb * Tt;  // 4096 token rows
constexpr float EPSv = 1e-5f;

DEVI float b2f(unsigned short s) {
  union { unsigned u; float f; } v; v.u = ((unsigned)s) << 16; return v.f;
}
DEVI unsigned short f2b(float f) {
  union { float f; unsigned u; } v; v.f = f;
  return (unsigned short)((v.u + 0x7FFFu + ((v.u >> 16) & 1u)) >> 16);
}

// global -> LDS direct (16B per lane). LDS dest must be wave-uniform base + lane*16.
DEVI void load_lds16(const void* g, void* s) {
  __builtin_amdgcn_global_load_lds((av1_t*)(unsigned long long)g,
                                   (av3_t*)(unsigned)(unsigned long long)s,
                                   16, 0, 0);
}

// ---------------- fp32 -> bf16 convert ----------------
__global__ __launch_bounds__(256) void cvt_kernel(const float* __restrict__ in,
                                                  unsigned short* __restrict__ out, int n) {
  int i = (blockIdx.x * 256 + threadIdx.x) * 4;
  if (i >= n) return;
  float4 v = *(const float4*)(in + i);
  sv4 o;
  o[0] = (short)f2b(v.x); o[1] = (short)f2b(v.y);
  o[2] = (short)f2b(v.z); o[3] = (short)f2b(v.w);
  *(sv4*)(out + i) = o;
}

// ---------------- LayerNorm (fp32 in, bf16 out), one block per row ----------------
__global__ __launch_bounds__(256) void ln_kernel(const float* __restrict__ x,
                                                 const float* __restrict__ g,
                                                 const float* __restrict__ b,
                                                 unsigned short* __restrict__ out) {
  const int row = blockIdx.x, tid = threadIdx.x;
  const float4 v = *(const float4*)(x + (size_t)row * Ee + tid * 4);
  float s = v.x + v.y + v.z + v.w;
  float ss = v.x * v.x + v.y * v.y + v.z * v.z + v.w * v.w;
#pragma unroll
  for (int off = 32; off; off >>= 1) { s += __shfl_down(s, off); ss += __shfl_down(ss, off); }
  __shared__ float red[16];
  const int w = tid >> 6, l = tid & 63;
  if (l == 0) { red[w] = s; red[8 + w] = ss; }
  __syncthreads();
  s = red[0] + red[1] + red[2] + red[3];
  ss = red[8] + red[9] + red[10] + red[11];
  const float mean = s * (1.f / Ee);
  const float rstd = rsqrtf(ss * (1.f / Ee) - mean * mean + EPSv);
  const float4 gv = *(const float4*)(g + tid * 4);
  const float4 bv = *(const float4*)(b + tid * 4);
  sv4 o;
  o[0] = (short)f2b((v.x - mean) * rstd * gv.x + bv.x);
  o[1] = (short)f2b((v.y - mean) * rstd * gv.y + bv.y);
  o[2] = (short)f2b((v.z - mean) * rstd * gv.z + bv.z);
  o[3] = (short)f2b((v.w - mean) * rstd * gv.w + bv.w);
  *(sv4*)(out + (size_t)row * Ee + tid * 4) = o;
}

// ---------------- bf16 GEMM: C[n,m] = sum_k A[n,k]*B[m,k] (+bias) (+res, fp32 out) ----
// 128x128 tile, BK=32, 4 waves (2x2), each wave 64x64 via 4x4 16x16x32 MFMA frags.
template <int OUTF32, int HASBIAS>
__global__ __launch_bounds__(256) void gemm_bt(const unsigned short* __restrict__ A,
                                               const unsigned short* __restrict__ Bw,
                                               void* __restrict__ Cout,
                                               const float* __restrict__ bias,
                                               const float* __restrict__ res,
                                               int M, int K) {
  __shared__ unsigned short lA[128 * 32];
  __shared__ unsigned short lB[128 * 32];
  const int tid = threadIdx.x;
  const int l = tid & 63, w = tid >> 6;
  const int wr = w >> 1, wc = w & 1;
  const int rowbase = blockIdx.y * 128, colbase = blockIdx.x * 128;

  const fv4 zero4 = {0.f, 0.f, 0.f, 0.f};
  fv4 acc[4][4];
#pragma unroll
  for (int i = 0; i < 4; ++i)
#pragma unroll
    for (int j = 0; j < 4; ++j) acc[i][j] = zero4;

  // staging: 512 chunks of 8 bf16 per tile; thread t does chunks t and t+256.
  const int c0 = tid, c1 = tid + 256;
  const unsigned short* Ag0 = A + (size_t)(rowbase + (c0 >> 2)) * K + (c0 & 3) * 8;
  const unsigned short* Ag1 = A + (size_t)(rowbase + (c1 >> 2)) * K + (c1 & 3) * 8;
  const unsigned short* Bg0 = Bw + (size_t)(colbase + (c0 >> 2)) * K + (c0 & 3) * 8;
  const unsigned short* Bg1 = Bw + (size_t)(colbase + (c1 >> 2)) * K + (c1 & 3) * 8;

  const int nk = K >> 5;
  const int kc = (l >> 4) * 8;
  for (int kt = 0; kt < nk; ++kt) {
    __syncthreads();
    load_lds16(Ag0, lA + c0 * 8);
    load_lds16(Ag1, lA + c1 * 8);
    load_lds16(Bg0, lB + c0 * 8);
    load_lds16(Bg1, lB + c1 * 8);
    Ag0 += 32; Ag1 += 32; Bg0 += 32; Bg1 += 32;
    __syncthreads();
    sv8 af[4], bfr[4];
#pragma unroll
    for (int i = 0; i < 4; ++i)
      af[i] = *(const sv8*)(lA + (wr * 64 + i * 16 + (l & 15)) * 32 + kc);
#pragma unroll
    for (int i = 0; i < 4; ++i)
      bfr[i] = *(const sv8*)(lB + (wc * 64 + i * 16 + (l & 15)) * 32 + kc);
#pragma unroll
    for (int mi = 0; mi < 4; ++mi)
#pragma unroll
      for (int ni = 0; ni < 4; ++ni)
        acc[mi][ni] = __builtin_amdgcn_mfma_f32_16x16x32_bf16(af[mi], bfr[ni], acc[mi][ni], 0, 0, 0);
  }

  // C/D layout: col = lane&15, row = (lane>>4)*4 + j   [measured m89/m91]
  const int r0 = rowbase + wr * 64 + ((l >> 4) * 4);
  const int ccol = colbase + wc * 64 + (l & 15);
#pragma unroll
  for (int mi = 0; mi < 4; ++mi) {
#pragma unroll
    for (int j = 0; j < 4; ++j) {
      const size_t r = (size_t)(r0 + mi * 16 + j);
#pragma unroll
      for (int ni = 0; ni < 4; ++ni) {
        const int c = ccol + ni * 16;
        float vv = acc[mi][ni][j];
        if (HASBIAS) vv += bias[c];
        if (OUTF32) {
          ((float*)Cout)[r * M + c] = res[r * M + c] + vv;
        } else {
          ((unsigned short*)Cout)[r * M + c] = f2b(vv);
        }
      }
    }
  }
}

// ---------------- flash attention: 1 block = (b, h, 64 q-rows), 4 waves x 16 rows ---
// R2-verified LDS layouts (bank-conflict-reduced):
//   Kt[row][kchunk]: kchunk' = kchunk ^ (row&7) via pre-swizzled global_load_lds source.
//   Vt[d][kchunk]  : transposed V, reg-staged; kchunk' = kchunk ^ (d&7) ^ ((d>>3)&7).
//   Pt[q][kchunk]  : kchunk' = kchunk ^ (q&7).
// exp2-domain online softmax (scale folded with log2e).
__global__ __launch_bounds__(256) void attn_kernel(const unsigned short* __restrict__ Q,
                                                   const unsigned short* __restrict__ Kb,
                                                   const unsigned short* __restrict__ Vb,
                                                   unsigned short* __restrict__ O,
                                                   int ld) {
  const int bh = blockIdx.y;
  const int b = bh / Hh, h = bh % Hh;
  const int q0 = blockIdx.x * 64;
  const int tid = threadIdx.x, l = tid & 63, w = tid >> 6;
  const size_t base = (size_t)b * Tt * ld + (size_t)h * Dd;
  const size_t baseO = (size_t)b * Tt * Ee + (size_t)h * Dd;

  __shared__ unsigned short Kt[64 * 64];
  __shared__ unsigned short Vt[64 * 64];
  __shared__ unsigned short Pt[4][16 * 64];

  // Q fragments held in registers: A-layout row = l&15, k-chunk = (l>>4)*8
  sv8 qf0, qf1;
  {
    const unsigned short* qp = Q + base + (size_t)(q0 + w * 16 + (l & 15)) * ld + (l >> 4) * 8;
    qf0 = *(const sv8*)qp;
    qf1 = *(const sv8*)(qp + 32);
  }

  const fv4 zero4 = {0.f, 0.f, 0.f, 0.f};
  fv4 acc_o[4];
#pragma unroll
  for (int i = 0; i < 4; ++i) acc_o[i] = zero4;
  float Mx[4], Lx[4];
#pragma unroll
  for (int j = 0; j < 4; ++j) { Mx[j] = -INFINITY; Lx[j] = 0.f; }

  const float s2 = 0.125f * 1.4426950408889634f;  // 1/sqrt(D) * log2(e)

  const int c0 = tid, c1 = tid + 256;
  const int r0c = c0 >> 3, xc0 = c0 & 7;   // chunk -> (row, chunk-in-row)
  const int r1c = c1 >> 3, xc1 = c1 & 7;   // xc1 == xc0

  for (int kt = 0; kt < Tt / 64; ++kt) {
    __syncthreads();
    // --- K: global->LDS direct, pre-swizzled source (chunk' = chunk ^ (row&7)) ---
    load_lds16(Kb + base + (size_t)(kt * 64 + r0c) * ld + (xc0 ^ (r0c & 7)) * 8, Kt + c0 * 8);
    load_lds16(Kb + base + (size_t)(kt * 64 + r1c) * ld + (xc1 ^ (r1c & 7)) * 8, Kt + c1 * 8);
    // --- V: reg-stage, write transposed+swizzled ---
    const sv8 v0 = *(const sv8*)(Vb + base + (size_t)(kt * 64 + r0c) * ld + xc0 * 8);
    const sv8 v1 = *(const sv8*)(Vb + base + (size_t)(kt * 64 + r1c) * ld + xc1 * 8);
#pragma unroll
    for (int j = 0; j < 8; ++j) {
      const int d = xc0 * 8 + j;  // d&7 == j, d>>3 == xc0
      Vt[d * 64 + ((((r0c >> 3) ^ j ^ xc0) & 7) * 8) + (r0c & 7)] = v0[j];
      Vt[d * 64 + ((((r1c >> 3) ^ j ^ xc1) & 7) * 8) + (r1c & 7)] = v1[j];
    }
    __syncthreads();

    // --- S = Q K^T (per wave: 16 q-rows x 64 k-cols) ---
    fv4 s[4];
    __builtin_amdgcn_s_setprio(1);
#pragma unroll
    for (int ks = 0; ks < 4; ++ks) {
      const int row = ks * 16 + (l & 15);
      const sv8 kf0 = *(const sv8*)(Kt + row * 64 + (((l >> 4) ^ (row & 7)) * 8));
      const sv8 kf1 = *(const sv8*)(Kt + row * 64 + (((4 + (l >> 4)) ^ (row & 7)) * 8));
      fv4 t = zero4;
      t = __builtin_amdgcn_mfma_f32_16x16x32_bf16(qf0, kf0, t, 0, 0, 0);
      t = __builtin_amdgcn_mfma_f32_16x16x32_bf16(qf1, kf1, t, 0, 0, 0);
      s[ks] = t;
    }
    __builtin_amdgcn_s_setprio(0);

    // --- online softmax in exp2 domain (rows on 16-lane groups) ---
    float mnew[4], alpha[4], ls[4];
#pragma unroll
    for (int j = 0; j < 4; ++j) {
      float mt = fmaxf(fmaxf(s[0][j], s[1][j]), fmaxf(s[2][j], s[3][j])) * s2;
#pragma unroll
      for (int off = 1; off < 16; off <<= 1) mt = fmaxf(mt, __shfl_xor(mt, off, 16));
      mnew[j] = fmaxf(Mx[j], mt);
      alpha[j] = exp2f(Mx[j] - mnew[j]);
      Mx[j] = mnew[j];
      ls[j] = 0.f;
    }
#pragma unroll
    for (int ks = 0; ks < 4; ++ks)
#pragma unroll
      for (int j = 0; j < 4; ++j) {
        const float p = exp2f(s[ks][j] * s2 - mnew[j]);
        s[ks][j] = p;
        ls[j] += p;
      }
#pragma unroll
    for (int j = 0; j < 4; ++j) {
      float t = ls[j];
#pragma unroll
      for (int off = 1; off < 16; off <<= 1) t += __shfl_xor(t, off, 16);
      Lx[j] = Lx[j] * alpha[j] + t;
    }
    // --- P: C-layout -> per-wave LDS (swizzled) so PV reads A-layout b128 ---
#pragma unroll
    for (int ks = 0; ks < 4; ++ks)
#pragma unroll
      for (int j = 0; j < 4; ++j) {
        const int q = (l >> 4) * 4 + j, k = ks * 16 + (l & 15);
        Pt[w][q * 64 + ((((k >> 3) ^ (q & 7)) & 7) * 8) + (k & 7)] = f2b(s[ks][j]);
      }
#pragma unroll
    for (int dsb = 0; dsb < 4; ++dsb)
#pragma unroll
      for (int j = 0; j < 4; ++j) acc_o[dsb][j] *= alpha[j];
    asm volatile("s_waitcnt lgkmcnt(0)" ::: "memory");

    // --- O += P V : all-vector b128 reads from swizzled Pt/Vt ---
    __builtin_amdgcn_s_setprio(1);
#pragma unroll
    for (int kcn = 0; kcn < 2; ++kcn) {
      const int qr = l & 15;
      const sv8 pf = *(const sv8*)(&Pt[w][qr * 64 + (((kcn * 4 + (l >> 4)) ^ (qr & 7)) * 8)]);
#pragma unroll
      for (int dsb = 0; dsb < 4; ++dsb) {
        const int d = dsb * 16 + (l & 15);
        const sv8 vf = *(const sv8*)(Vt + d * 64 +
                        ((((kcn * 4 + (l >> 4)) ^ (d & 7) ^ ((d >> 3) & 7)) & 7) * 8));
        acc_o[dsb] = __builtin_amdgcn_mfma_f32_16x16x32_bf16(pf, vf, acc_o[dsb], 0, 0, 0);
      }
    }
    __builtin_amdgcn_s_setprio(0);
  }

#pragma unroll
  for (int j = 0; j < 4; ++j) {
    const float inv = 1.f / Lx[j];
    unsigned short* op = O + baseO + (size_t)(q0 + w * 16 + (l >> 4) * 4 + j) * Ee;
#pragma unroll
    for (int dsb = 0; dsb < 4; ++dsb)
      op[dsb * 16 + (l & 15)] = f2b(acc_o[dsb][j] * inv);
  }
}

// ---------------- GEGLU: f = a * gelu_exact(g) ----------------
__global__ __launch_bounds__(256) void geglu_kernel(const unsigned short* __restrict__ u,
                                                    unsigned short* __restrict__ f) {
  const int t = blockIdx.x * 256 + threadIdx.x;
  const int n = t >> 10;            // FFd/4 = 1024 threads per row
  const int j4 = (t & 1023) * 4;
  const unsigned short* ua = u + (size_t)n * (2 * FFd) + j4;
  const sv4 av = *(const sv4*)ua;
  const sv4 gv = *(const sv4*)(ua + FFd);
  sv4 o;
#pragma unroll
  for (int i = 0; i < 4; ++i) {
    const float a = b2f((unsigned short)av[i]);
    const float g = b2f((unsigned short)gv[i]);
    o[i] = (short)f2b(a * 0.5f * g * (1.f + erff(g * 0.70710678118654752f)));
  }
  *(sv4*)(f + (size_t)n * FFd + j4) = o;
}

extern "C" void kernel_launch(void* const* d_in, const int* in_sizes, int n_in,
                              void* d_out, int out_size, void* d_ws, size_t ws_size,
                              hipStream_t stream) {
  (void)in_sizes; (void)n_in; (void)out_size; (void)ws_size;
  const float* src  = (const float*)d_in[0];
  const float* Wq   = (const float*)d_in[1];
  const float* Wk   = (const float*)d_in[2];
  const float* Wv   = (const float*)d_in[3];
  const float* Wo   = (const float*)d_in[4];
  const float* W1   = (const float*)d_in[5];
  const float* b1   = (const float*)d_in[6];
  const float* W2   = (const float*)d_in[7];
  const float* b2   = (const float*)d_in[8];
  const float* ln1w = (const float*)d_in[9];
  const float* ln1b = (const float*)d_in[10];
  const float* ln2w = (const float*)d_in[11];
  const float* ln2b = (const float*)d_in[12];
  float* out = (float*)d_out;

  char* ws = (char*)d_ws;
  size_t off = 0;
  auto alloc = [&](size_t bytes) { char* p = ws + off; off += bytes; return p; };
  unsigned short* wqkv = (unsigned short*)alloc((size_t)3 * Ee * Ee * 2);  // Wq|Wk|Wv rows
  unsigned short* wo16 = (unsigned short*)alloc((size_t)Ee * Ee * 2);
  unsigned short* w116 = (unsigned short*)alloc((size_t)2 * FFd * Ee * 2);
  unsigned short* w216 = (unsigned short*)alloc((size_t)Ee * FFd * 2);
  unsigned short* h16  = (unsigned short*)alloc((size_t)NN * Ee * 2);
  unsigned short* qkv  = (unsigned short*)alloc((size_t)NN * 3 * Ee * 2);  // [row][3E]
  unsigned short* a16  = (unsigned short*)alloc((size_t)NN * Ee * 2);
  float* xbuf          = (float*)alloc((size_t)NN * Ee * 4);
  unsigned short* u16  = (unsigned short*)alloc((size_t)NN * 2 * FFd * 2);
  unsigned short* f16  = qkv;  // reuse qkv+a16 region (33.5 MB) after attention done

  dim3 blk(256);
  cvt_kernel<<<dim3(Ee * Ee / 1024), blk, 0, stream>>>(Wq, wqkv, Ee * Ee);
  cvt_kernel<<<dim3(Ee * Ee / 1024), blk, 0, stream>>>(Wk, wqkv + Ee * Ee, Ee * Ee);
  cvt_kernel<<<dim3(Ee * Ee / 1024), blk, 0, stream>>>(Wv, wqkv + 2 * Ee * Ee, Ee * Ee);
  cvt_kernel<<<dim3(Ee * Ee / 1024), blk, 0, stream>>>(Wo, wo16, Ee * Ee);
  cvt_kernel<<<dim3(2 * FFd * Ee / 1024), blk, 0, stream>>>(W1, w116, 2 * FFd * Ee);
  cvt_kernel<<<dim3(Ee * FFd / 1024), blk, 0, stream>>>(W2, w216, Ee * FFd);

  ln_kernel<<<dim3(NN), blk, 0, stream>>>(src, ln1w, ln1b, h16);

  // fused QKV projection: [4096,1024] x [3072,1024]^T -> [4096,3072]
  gemm_bt<0, 0><<<dim3(3 * Ee / 128, NN / 128), blk, 0, stream>>>(h16, wqkv, qkv, nullptr, nullptr, 3 * Ee, Ee);

  attn_kernel<<<dim3(Tt / 64, Bb * Hh), blk, 0, stream>>>(qkv, qkv + Ee, qkv + 2 * Ee, a16, 3 * Ee);

  gemm_bt<1, 0><<<dim3(Ee / 128, NN / 128), blk, 0, stream>>>(a16, wo16, xbuf, nullptr, src, Ee, Ee);

  ln_kernel<<<dim3(NN), blk, 0, stream>>>(xbuf, ln2w, ln2b, h16);

  gemm_bt<0, 1><<<dim3(2 * FFd / 128, NN / 128), blk, 0, stream>>>(h16, w116, u16, b1, nullptr, 2 * FFd, Ee);

  geglu_kernel<<<dim3(NN * FFd / 1024), blk, 0, stream>>>(u16, f16);

  gemm_bt<1, 1><<<dim3(Ee / 128, NN / 128), blk, 0, stream>>>(f16, w216, out, b2, xbuf, Ee, FFd);
}

// Round 5
// 425.644 us; speedup vs baseline: 1.2125x; 1.0405x over previous
//
#include <hip/hip_runtime.h>
#include <stdint.h>
#include <math.h>

#define DEVI __device__ __forceinline__

typedef __attribute__((ext_vector_type(8))) short sv8;
typedef __attribute__((ext_vector_type(4))) short sv4;
typedef __attribute__((ext_vector_type(4))) float fv4;

typedef __attribute__((address_space(1))) void av1_t;
typedef __attribute__((address_space(3))) void av3_t;

constexpr int Bb = 2, Tt = 2048, Ee = 1024, Hh = 16, Dd = 64, FFd = 4096;
constexpr int NN = Bb * Tt;  // 4096 token rows
constexpr float EPSv = 1e-5f;

DEVI float b2f(unsigned short s) {
  union { unsigned u; float f; } v; v.u = ((unsigned)s) << 16; return v.f;
}
DEVI unsigned short f2b(float f) {
  union { float f; unsigned u; } v; v.f = f;
  return (unsigned short)((v.u + 0x7FFFu + ((v.u >> 16) & 1u)) >> 16);
}

// global -> LDS direct (16B per lane). LDS dest must be wave-uniform base + lane*16.
DEVI void load_lds16(const void* g, void* s) {
  __builtin_amdgcn_global_load_lds((av1_t*)(unsigned long long)g,
                                   (av3_t*)(unsigned)(unsigned long long)s,
                                   16, 0, 0);
}

// ---------------- fp32 -> bf16 convert ----------------
__global__ __launch_bounds__(256) void cvt_kernel(const float* __restrict__ in,
                                                  unsigned short* __restrict__ out, int n) {
  int i = (blockIdx.x * 256 + threadIdx.x) * 4;
  if (i >= n) return;
  float4 v = *(const float4*)(in + i);
  sv4 o;
  o[0] = (short)f2b(v.x); o[1] = (short)f2b(v.y);
  o[2] = (short)f2b(v.z); o[3] = (short)f2b(v.w);
  *(sv4*)(out + i) = o;
}

// ---------------- LayerNorm (fp32 in, bf16 out), one block per row ----------------
__global__ __launch_bounds__(256) void ln_kernel(const float* __restrict__ x,
                                                 const float* __restrict__ g,
                                                 const float* __restrict__ b,
                                                 unsigned short* __restrict__ out) {
  const int row = blockIdx.x, tid = threadIdx.x;
  const float4 v = *(const float4*)(x + (size_t)row * Ee + tid * 4);
  float s = v.x + v.y + v.z + v.w;
  float ss = v.x * v.x + v.y * v.y + v.z * v.z + v.w * v.w;
#pragma unroll
  for (int off = 32; off; off >>= 1) { s += __shfl_down(s, off); ss += __shfl_down(ss, off); }
  __shared__ float red[16];
  const int w = tid >> 6, l = tid & 63;
  if (l == 0) { red[w] = s; red[8 + w] = ss; }
  __syncthreads();
  s = red[0] + red[1] + red[2] + red[3];
  ss = red[8] + red[9] + red[10] + red[11];
  const float mean = s * (1.f / Ee);
  const float rstd = rsqrtf(ss * (1.f / Ee) - mean * mean + EPSv);
  const float4 gv = *(const float4*)(g + tid * 4);
  const float4 bv = *(const float4*)(b + tid * 4);
  sv4 o;
  o[0] = (short)f2b((v.x - mean) * rstd * gv.x + bv.x);
  o[1] = (short)f2b((v.y - mean) * rstd * gv.y + bv.y);
  o[2] = (short)f2b((v.z - mean) * rstd * gv.z + bv.z);
  o[3] = (short)f2b((v.w - mean) * rstd * gv.w + bv.w);
  *(sv4*)(out + (size_t)row * Ee + tid * 4) = o;
}

// ---------------- bf16 GEMM: C[n,m] = sum_k A[n,k]*B[m,k] (+bias) (+res, fp32 out) ----
// 128xBN tile, BK=32, 4 waves (2x2). BN=128: wave 64x64 (4x4 frags); BN=64: wave 64x32
// (4x2 frags, 512-block grids for the M=1024 GEMMs that would otherwise be 1 block/CU).
template <int OUTF32, int HASBIAS, int BN>
__global__ __launch_bounds__(256) void gemm_bt(const unsigned short* __restrict__ A,
                                               const unsigned short* __restrict__ Bw,
                                               void* __restrict__ Cout,
                                               const float* __restrict__ bias,
                                               const float* __restrict__ res,
                                               int M, int K) {
  constexpr int NI = BN / 32;  // per-wave n-frags (wave covers BN/2 cols)
  __shared__ unsigned short lA[128 * 32];
  __shared__ unsigned short lB[BN * 32];
  const int tid = threadIdx.x;
  const int l = tid & 63, w = tid >> 6;
  const int wr = w >> 1, wc = w & 1;
  const int rowbase = blockIdx.y * 128, colbase = blockIdx.x * BN;

  const fv4 zero4 = {0.f, 0.f, 0.f, 0.f};
  fv4 acc[4][NI];
#pragma unroll
  for (int i = 0; i < 4; ++i)
#pragma unroll
    for (int j = 0; j < NI; ++j) acc[i][j] = zero4;

  // staging: A = 512 chunks of 8 bf16 (threads do c0,c1); B = BN*4 chunks.
  const int c0 = tid, c1 = tid + 256;
  const unsigned short* Ag0 = A + (size_t)(rowbase + (c0 >> 2)) * K + (c0 & 3) * 8;
  const unsigned short* Ag1 = A + (size_t)(rowbase + (c1 >> 2)) * K + (c1 & 3) * 8;
  const unsigned short* Bg0 = Bw + (size_t)(colbase + (c0 >> 2)) * K + (c0 & 3) * 8;
  const unsigned short* Bg1 = Bw + (size_t)(colbase + ((BN == 128 ? c1 : c0) >> 2)) * K + (c0 & 3) * 8;

  const int nk = K >> 5;
  const int kc = (l >> 4) * 8;
  for (int kt = 0; kt < nk; ++kt) {
    __syncthreads();
    load_lds16(Ag0, lA + c0 * 8);
    load_lds16(Ag1, lA + c1 * 8);
    load_lds16(Bg0, lB + c0 * 8);
    if (BN == 128) load_lds16(Bg1, lB + c1 * 8);
    Ag0 += 32; Ag1 += 32; Bg0 += 32; Bg1 += 32;
    __syncthreads();
    sv8 af[4], bfr[NI];
#pragma unroll
    for (int i = 0; i < 4; ++i)
      af[i] = *(const sv8*)(lA + (wr * 64 + i * 16 + (l & 15)) * 32 + kc);
#pragma unroll
    for (int i = 0; i < NI; ++i)
      bfr[i] = *(const sv8*)(lB + (wc * (BN / 2) + i * 16 + (l & 15)) * 32 + kc);
#pragma unroll
    for (int mi = 0; mi < 4; ++mi)
#pragma unroll
      for (int ni = 0; ni < NI; ++ni)
        acc[mi][ni] = __builtin_amdgcn_mfma_f32_16x16x32_bf16(af[mi], bfr[ni], acc[mi][ni], 0, 0, 0);
  }

  // C/D layout: col = lane&15, row = (lane>>4)*4 + j   [measured m89/m91]
  const int r0 = rowbase + wr * 64 + ((l >> 4) * 4);
  const int ccol = colbase + wc * (BN / 2) + (l & 15);
#pragma unroll
  for (int mi = 0; mi < 4; ++mi) {
#pragma unroll
    for (int j = 0; j < 4; ++j) {
      const size_t r = (size_t)(r0 + mi * 16 + j);
#pragma unroll
      for (int ni = 0; ni < NI; ++ni) {
        const int c = ccol + ni * 16;
        float vv = acc[mi][ni][j];
        if (HASBIAS) vv += bias[c];
        if (OUTF32) {
          ((float*)Cout)[r * M + c] = res[r * M + c] + vv;
        } else {
          ((unsigned short*)Cout)[r * M + c] = f2b(vv);
        }
      }
    }
  }
}

// ---------------- flash attention: 1 block = (b, h, 64 q-rows), 4 waves x 16 rows ---
// Double-buffered K/V staging (prefetch tile t+1 at top of iter t; HBM latency hides
// under QK^T/softmax/PV). R2-verified swizzled LDS layouts. exp2-domain softmax with
// defer-max (T13): skip rescale when max grew by < 11.5 (log2 units).
__global__ __launch_bounds__(256) void attn_kernel(const unsigned short* __restrict__ Q,
                                                   const unsigned short* __restrict__ Kb,
                                                   const unsigned short* __restrict__ Vb,
                                                   unsigned short* __restrict__ O,
                                                   int ld) {
  const int bh = blockIdx.y;
  const int b = bh / Hh, h = bh % Hh;
  const int q0 = blockIdx.x * 64;
  const int tid = threadIdx.x, l = tid & 63, w = tid >> 6;
  const size_t base = (size_t)b * Tt * ld + (size_t)h * Dd;
  const size_t baseO = (size_t)b * Tt * Ee + (size_t)h * Dd;

  __shared__ unsigned short Kt[2][64 * 64];
  __shared__ unsigned short Vt[2][64 * 64];
  __shared__ unsigned short Pt[4][16 * 64];

  // Q fragments held in registers: A-layout row = l&15, k-chunk = (l>>4)*8
  sv8 qf0, qf1;
  {
    const unsigned short* qp = Q + base + (size_t)(q0 + w * 16 + (l & 15)) * ld + (l >> 4) * 8;
    qf0 = *(const sv8*)qp;
    qf1 = *(const sv8*)(qp + 32);
  }

  const fv4 zero4 = {0.f, 0.f, 0.f, 0.f};
  fv4 acc_o[4];
#pragma unroll
  for (int i = 0; i < 4; ++i) acc_o[i] = zero4;
  float Mx[4], Lx[4];
#pragma unroll
  for (int j = 0; j < 4; ++j) { Mx[j] = -INFINITY; Lx[j] = 0.f; }

  const float s2 = 0.125f * 1.4426950408889634f;  // 1/sqrt(D) * log2(e)

  const int c0 = tid, c1 = tid + 256;
  const int r0c = c0 >> 3, xc0 = c0 & 7;   // chunk -> (row, chunk-in-row)
  const int r1c = c1 >> 3, xc1 = c1 & 7;   // xc1 == xc0

  sv8 v0, v1;  // V prefetch registers (live across the compute phase)

  // ---- prologue: stage tile 0 ----
  load_lds16(Kb + base + (size_t)(r0c)*ld + (xc0 ^ (r0c & 7)) * 8, Kt[0] + c0 * 8);
  load_lds16(Kb + base + (size_t)(r1c)*ld + (xc1 ^ (r1c & 7)) * 8, Kt[0] + c1 * 8);
  v0 = *(const sv8*)(Vb + base + (size_t)(r0c)*ld + xc0 * 8);
  v1 = *(const sv8*)(Vb + base + (size_t)(r1c)*ld + xc1 * 8);
#pragma unroll
  for (int j = 0; j < 8; ++j) {
    const int d = xc0 * 8 + j;
    Vt[0][d * 64 + ((((r0c >> 3) ^ j ^ xc0) & 7) * 8) + (r0c & 7)] = v0[j];
    Vt[0][d * 64 + ((((r1c >> 3) ^ j ^ xc1) & 7) * 8) + (r1c & 7)] = v1[j];
  }
  __syncthreads();

  int cur = 0;
  for (int kt = 0; kt < Tt / 64; ++kt) {
    const int nx = cur ^ 1;
    const bool pre = (kt + 1 < Tt / 64);
    // ---- prefetch tile kt+1 (async; consumed after B1) ----
    if (pre) {
      load_lds16(Kb + base + (size_t)((kt + 1) * 64 + r0c) * ld + (xc0 ^ (r0c & 7)) * 8, Kt[nx] + c0 * 8);
      load_lds16(Kb + base + (size_t)((kt + 1) * 64 + r1c) * ld + (xc1 ^ (r1c & 7)) * 8, Kt[nx] + c1 * 8);
      v0 = *(const sv8*)(Vb + base + (size_t)((kt + 1) * 64 + r0c) * ld + xc0 * 8);
      v1 = *(const sv8*)(Vb + base + (size_t)((kt + 1) * 64 + r1c) * ld + xc1 * 8);
    }

    // --- S = Q K^T (per wave: 16 q-rows x 64 k-cols) from Kt[cur] ---
    fv4 s[4];
    __builtin_amdgcn_s_setprio(1);
#pragma unroll
    for (int ks = 0; ks < 4; ++ks) {
      const int row = ks * 16 + (l & 15);
      const sv8 kf0 = *(const sv8*)(Kt[cur] + row * 64 + (((l >> 4) ^ (row & 7)) * 8));
      const sv8 kf1 = *(const sv8*)(Kt[cur] + row * 64 + (((4 + (l >> 4)) ^ (row & 7)) * 8));
      fv4 t = zero4;
      t = __builtin_amdgcn_mfma_f32_16x16x32_bf16(qf0, kf0, t, 0, 0, 0);
      t = __builtin_amdgcn_mfma_f32_16x16x32_bf16(qf1, kf1, t, 0, 0, 0);
      s[ks] = t;
    }
    __builtin_amdgcn_s_setprio(0);

    // --- online softmax, exp2 domain, defer-max ---
    float mt[4];
#pragma unroll
    for (int j = 0; j < 4; ++j) {
      float m = fmaxf(fmaxf(s[0][j], s[1][j]), fmaxf(s[2][j], s[3][j])) * s2;
#pragma unroll
      for (int off = 1; off < 16; off <<= 1) m = fmaxf(m, __shfl_xor(m, off, 16));
      mt[j] = m;
    }
    bool need = false;
#pragma unroll
    for (int j = 0; j < 4; ++j) need = need || (mt[j] > Mx[j] + 11.5f);
    if (__any(need)) {
#pragma unroll
      for (int j = 0; j < 4; ++j) {
        const float mnew = fmaxf(Mx[j], mt[j]);
        const float alpha = exp2f(Mx[j] - mnew);
        Mx[j] = mnew;
        Lx[j] *= alpha;
#pragma unroll
        for (int dsb = 0; dsb < 4; ++dsb) acc_o[dsb][j] *= alpha;
      }
    }
    float ls[4];
#pragma unroll
    for (int j = 0; j < 4; ++j) ls[j] = 0.f;
#pragma unroll
    for (int ks = 0; ks < 4; ++ks)
#pragma unroll
      for (int j = 0; j < 4; ++j) {
        const float p = exp2f(s[ks][j] * s2 - Mx[j]);
        s[ks][j] = p;
        ls[j] += p;
      }
#pragma unroll
    for (int j = 0; j < 4; ++j) {
      float t = ls[j];
#pragma unroll
      for (int off = 1; off < 16; off <<= 1) t += __shfl_xor(t, off, 16);
      Lx[j] += t;
    }
    // --- P: C-layout -> per-wave LDS (swizzled) so PV reads A-layout b128 ---
#pragma unroll
    for (int ks = 0; ks < 4; ++ks)
#pragma unroll
      for (int j = 0; j < 4; ++j) {
        const int q = (l >> 4) * 4 + j, k = ks * 16 + (l & 15);
        Pt[w][q * 64 + ((((k >> 3) ^ (q & 7)) & 7) * 8) + (k & 7)] = f2b(s[ks][j]);
      }
    asm volatile("s_waitcnt lgkmcnt(0)" ::: "memory");

    // --- O += P V : all-vector b128 reads from swizzled Pt/Vt[cur] ---
    __builtin_amdgcn_s_setprio(1);
#pragma unroll
    for (int kcn = 0; kcn < 2; ++kcn) {
      const int qr = l & 15;
      const sv8 pf = *(const sv8*)(&Pt[w][qr * 64 + (((kcn * 4 + (l >> 4)) ^ (qr & 7)) * 8)]);
#pragma unroll
      for (int dsb = 0; dsb < 4; ++dsb) {
        const int d = dsb * 16 + (l & 15);
        const sv8 vf = *(const sv8*)(Vt[cur] + d * 64 +
                        ((((kcn * 4 + (l >> 4)) ^ (d & 7) ^ ((d >> 3) & 7)) & 7) * 8));
        acc_o[dsb] = __builtin_amdgcn_mfma_f32_16x16x32_bf16(pf, vf, acc_o[dsb], 0, 0, 0);
      }
    }
    __builtin_amdgcn_s_setprio(0);

    __syncthreads();  // B1: all PV reads of Vt[cur] done; K prefetch (vmcnt) drained
    if (pre) {
#pragma unroll
      for (int j = 0; j < 8; ++j) {
        const int d = xc0 * 8 + j;
        Vt[nx][d * 64 + ((((r0c >> 3) ^ j ^ xc0) & 7) * 8) + (r0c & 7)] = v0[j];
        Vt[nx][d * 64 + ((((r1c >> 3) ^ j ^ xc1) & 7) * 8) + (r1c & 7)] = v1[j];
      }
    }
    __syncthreads();  // B2: Vt[nx] visible to all
    cur = nx;
  }

#pragma unroll
  for (int j = 0; j < 4; ++j) {
    const float inv = 1.f / Lx[j];
    unsigned short* op = O + baseO + (size_t)(q0 + w * 16 + (l >> 4) * 4 + j) * Ee;
#pragma unroll
    for (int dsb = 0; dsb < 4; ++dsb)
      op[dsb * 16 + (l & 15)] = f2b(acc_o[dsb][j] * inv);
  }
}

// ---------------- GEGLU: f = a * gelu_exact(g) ----------------
__global__ __launch_bounds__(256) void geglu_kernel(const unsigned short* __restrict__ u,
                                                    unsigned short* __restrict__ f) {
  const int t = blockIdx.x * 256 + threadIdx.x;
  const int n = t >> 10;            // FFd/4 = 1024 threads per row
  const int j4 = (t & 1023) * 4;
  const unsigned short* ua = u + (size_t)n * (2 * FFd) + j4;
  const sv4 av = *(const sv4*)ua;
  const sv4 gv = *(const sv4*)(ua + FFd);
  sv4 o;
#pragma unroll
  for (int i = 0; i < 4; ++i) {
    const float a = b2f((unsigned short)av[i]);
    const float g = b2f((unsigned short)gv[i]);
    o[i] = (short)f2b(a * 0.5f * g * (1.f + erff(g * 0.70710678118654752f)));
  }
  *(sv4*)(f + (size_t)n * FFd + j4) = o;
}

extern "C" void kernel_launch(void* const* d_in, const int* in_sizes, int n_in,
                              void* d_out, int out_size, void* d_ws, size_t ws_size,
                              hipStream_t stream) {
  (void)in_sizes; (void)n_in; (void)out_size; (void)ws_size;
  const float* src  = (const float*)d_in[0];
  const float* Wq   = (const float*)d_in[1];
  const float* Wk   = (const float*)d_in[2];
  const float* Wv   = (const float*)d_in[3];
  const float* Wo   = (const float*)d_in[4];
  const float* W1   = (const float*)d_in[5];
  const float* b1   = (const float*)d_in[6];
  const float* W2   = (const float*)d_in[7];
  const float* b2   = (const float*)d_in[8];
  const float* ln1w = (const float*)d_in[9];
  const float* ln1b = (const float*)d_in[10];
  const float* ln2w = (const float*)d_in[11];
  const float* ln2b = (const float*)d_in[12];
  float* out = (float*)d_out;

  char* ws = (char*)d_ws;
  size_t off = 0;
  auto alloc = [&](size_t bytes) { char* p = ws + off; off += bytes; return p; };
  unsigned short* wqkv = (unsigned short*)alloc((size_t)3 * Ee * Ee * 2);  // Wq|Wk|Wv rows
  unsigned short* wo16 = (unsigned short*)alloc((size_t)Ee * Ee * 2);
  unsigned short* w116 = (unsigned short*)alloc((size_t)2 * FFd * Ee * 2);
  unsigned short* w216 = (unsigned short*)alloc((size_t)Ee * FFd * 2);
  unsigned short* h16  = (unsigned short*)alloc((size_t)NN * Ee * 2);
  unsigned short* qkv  = (unsigned short*)alloc((size_t)NN * 3 * Ee * 2);  // [row][3E]
  unsigned short* a16  = (unsigned short*)alloc((size_t)NN * Ee * 2);
  float* xbuf          = (float*)alloc((size_t)NN * Ee * 4);
  unsigned short* u16  = (unsigned short*)alloc((size_t)NN * 2 * FFd * 2);
  unsigned short* f16  = qkv;  // reuse qkv+a16 region (33.5 MB) after attention done

  dim3 blk(256);
  cvt_kernel<<<dim3(Ee * Ee / 1024), blk, 0, stream>>>(Wq, wqkv, Ee * Ee);
  cvt_kernel<<<dim3(Ee * Ee / 1024), blk, 0, stream>>>(Wk, wqkv + Ee * Ee, Ee * Ee);
  cvt_kernel<<<dim3(Ee * Ee / 1024), blk, 0, stream>>>(Wv, wqkv + 2 * Ee * Ee, Ee * Ee);
  cvt_kernel<<<dim3(Ee * Ee / 1024), blk, 0, stream>>>(Wo, wo16, Ee * Ee);
  cvt_kernel<<<dim3(2 * FFd * Ee / 1024), blk, 0, stream>>>(W1, w116, 2 * FFd * Ee);
  cvt_kernel<<<dim3(Ee * FFd / 1024), blk, 0, stream>>>(W2, w216, Ee * FFd);

  ln_kernel<<<dim3(NN), blk, 0, stream>>>(src, ln1w, ln1b, h16);

  // fused QKV projection: [4096,1024] x [3072,1024]^T -> [4096,3072]
  gemm_bt<0, 0, 128><<<dim3(3 * Ee / 128, NN / 128), blk, 0, stream>>>(h16, wqkv, qkv, nullptr, nullptr, 3 * Ee, Ee);

  attn_kernel<<<dim3(Tt / 64, Bb * Hh), blk, 0, stream>>>(qkv, qkv + Ee, qkv + 2 * Ee, a16, 3 * Ee);

  // Wo projection + residual (BN=64: 512 blocks, 2/CU)
  gemm_bt<1, 0, 64><<<dim3(Ee / 64, NN / 128), blk, 0, stream>>>(a16, wo16, xbuf, nullptr, src, Ee, Ee);

  ln_kernel<<<dim3(NN), blk, 0, stream>>>(xbuf, ln2w, ln2b, h16);

  gemm_bt<0, 1, 128><<<dim3(2 * FFd / 128, NN / 128), blk, 0, stream>>>(h16, w116, u16, b1, nullptr, 2 * FFd, Ee);

  geglu_kernel<<<dim3(NN * FFd / 1024), blk, 0, stream>>>(u16, f16);

  // W2 projection + bias + residual (BN=64: 512 blocks, 2/CU)
  gemm_bt<1, 1, 64><<<dim3(Ee / 64, NN / 128), blk, 0, stream>>>(f16, w216, out, b2, xbuf, Ee, FFd);
}

// Round 6
// 380.796 us; speedup vs baseline: 1.3553x; 1.1178x over previous
//
#include <hip/hip_runtime.h>
#include <stdint.h>
#include <math.h>

#define DEVI __device__ __forceinline__

typedef __attribute__((ext_vector_type(8))) short sv8;
typedef __attribute__((ext_vector_type(4))) short sv4;
typedef __attribute__((ext_vector_type(4))) float fv4;

typedef __attribute__((address_space(1))) void av1_t;
typedef __attribute__((address_space(3))) void av3_t;

constexpr int Bb = 2, Tt = 2048, Ee = 1024, Hh = 16, Dd = 64, FFd = 4096;
constexpr int NN = Bb * Tt;  // 4096 token rows
constexpr float EPSv = 1e-5f;

DEVI float b2f(unsigned short s) {
  union { unsigned u; float f; } v; v.u = ((unsigned)s) << 16; return v.f;
}
DEVI unsigned short f2b(float f) {
  union { float f; unsigned u; } v; v.f = f;
  return (unsigned short)((v.u + 0x7FFFu + ((v.u >> 16) & 1u)) >> 16);
}
DEVI unsigned short f2b_rtz(float f) {  // truncation: 1 VALU op (softmax P only)
  union { float f; unsigned u; } v; v.f = f;
  return (unsigned short)(v.u >> 16);
}

// global -> LDS direct (16B per lane). LDS dest must be wave-uniform base + lane*16.
DEVI void load_lds16(const void* g, void* s) {
  __builtin_amdgcn_global_load_lds((av1_t*)(unsigned long long)g,
                                   (av3_t*)(unsigned)(unsigned long long)s,
                                   16, 0, 0);
}

// ---------------- fp32 -> bf16 convert (optional scale fold) ----------------
__global__ __launch_bounds__(256) void cvt_kernel(const float* __restrict__ in,
                                                  unsigned short* __restrict__ out, int n,
                                                  float scale) {
  int i = (blockIdx.x * 256 + threadIdx.x) * 4;
  if (i >= n) return;
  float4 v = *(const float4*)(in + i);
  sv4 o;
  o[0] = (short)f2b(v.x * scale); o[1] = (short)f2b(v.y * scale);
  o[2] = (short)f2b(v.z * scale); o[3] = (short)f2b(v.w * scale);
  *(sv4*)(out + i) = o;
}

// ---------------- LayerNorm (fp32 in, bf16 out), one block per row ----------------
__global__ __launch_bounds__(256) void ln_kernel(const float* __restrict__ x,
                                                 const float* __restrict__ g,
                                                 const float* __restrict__ b,
                                                 unsigned short* __restrict__ out) {
  const int row = blockIdx.x, tid = threadIdx.x;
  const float4 v = *(const float4*)(x + (size_t)row * Ee + tid * 4);
  float s = v.x + v.y + v.z + v.w;
  float ss = v.x * v.x + v.y * v.y + v.z * v.z + v.w * v.w;
#pragma unroll
  for (int off = 32; off; off >>= 1) { s += __shfl_down(s, off); ss += __shfl_down(ss, off); }
  __shared__ float red[16];
  const int w = tid >> 6, l = tid & 63;
  if (l == 0) { red[w] = s; red[8 + w] = ss; }
  __syncthreads();
  s = red[0] + red[1] + red[2] + red[3];
  ss = red[8] + red[9] + red[10] + red[11];
  const float mean = s * (1.f / Ee);
  const float rstd = rsqrtf(ss * (1.f / Ee) - mean * mean + EPSv);
  const float4 gv = *(const float4*)(g + tid * 4);
  const float4 bv = *(const float4*)(b + tid * 4);
  sv4 o;
  o[0] = (short)f2b((v.x - mean) * rstd * gv.x + bv.x);
  o[1] = (short)f2b((v.y - mean) * rstd * gv.y + bv.y);
  o[2] = (short)f2b((v.z - mean) * rstd * gv.z + bv.z);
  o[3] = (short)f2b((v.w - mean) * rstd * gv.w + bv.w);
  *(sv4*)(out + (size_t)row * Ee + tid * 4) = o;
}

// ---------------- bf16 GEMM: C[n,m] = sum_k A[n,k]*B[m,k] (+bias) (+res, fp32 out) ----
// 128xBN tile, BK=32, 4 waves (2x2). BN=128: wave 64x64 (4x4 frags); BN=64: wave 64x32
// (4x2 frags, 512-block grids for the M=1024 GEMMs that would otherwise be 1 block/CU).
template <int OUTF32, int HASBIAS, int BN>
__global__ __launch_bounds__(256) void gemm_bt(const unsigned short* __restrict__ A,
                                               const unsigned short* __restrict__ Bw,
                                               void* __restrict__ Cout,
                                               const float* __restrict__ bias,
                                               const float* __restrict__ res,
                                               int M, int K) {
  constexpr int NI = BN / 32;  // per-wave n-frags (wave covers BN/2 cols)
  __shared__ unsigned short lA[128 * 32];
  __shared__ unsigned short lB[BN * 32];
  const int tid = threadIdx.x;
  const int l = tid & 63, w = tid >> 6;
  const int wr = w >> 1, wc = w & 1;
  const int rowbase = blockIdx.y * 128, colbase = blockIdx.x * BN;

  const fv4 zero4 = {0.f, 0.f, 0.f, 0.f};
  fv4 acc[4][NI];
#pragma unroll
  for (int i = 0; i < 4; ++i)
#pragma unroll
    for (int j = 0; j < NI; ++j) acc[i][j] = zero4;

  // staging: A = 512 chunks of 8 bf16 (threads do c0,c1); B = BN*4 chunks.
  const int c0 = tid, c1 = tid + 256;
  const unsigned short* Ag0 = A + (size_t)(rowbase + (c0 >> 2)) * K + (c0 & 3) * 8;
  const unsigned short* Ag1 = A + (size_t)(rowbase + (c1 >> 2)) * K + (c1 & 3) * 8;
  const unsigned short* Bg0 = Bw + (size_t)(colbase + (c0 >> 2)) * K + (c0 & 3) * 8;
  const unsigned short* Bg1 = Bw + (size_t)(colbase + ((BN == 128 ? c1 : c0) >> 2)) * K + (c0 & 3) * 8;

  const int nk = K >> 5;
  const int kc = (l >> 4) * 8;
  for (int kt = 0; kt < nk; ++kt) {
    __syncthreads();
    load_lds16(Ag0, lA + c0 * 8);
    load_lds16(Ag1, lA + c1 * 8);
    load_lds16(Bg0, lB + c0 * 8);
    if (BN == 128) load_lds16(Bg1, lB + c1 * 8);
    Ag0 += 32; Ag1 += 32; Bg0 += 32; Bg1 += 32;
    __syncthreads();
    sv8 af[4], bfr[NI];
#pragma unroll
    for (int i = 0; i < 4; ++i)
      af[i] = *(const sv8*)(lA + (wr * 64 + i * 16 + (l & 15)) * 32 + kc);
#pragma unroll
    for (int i = 0; i < NI; ++i)
      bfr[i] = *(const sv8*)(lB + (wc * (BN / 2) + i * 16 + (l & 15)) * 32 + kc);
#pragma unroll
    for (int mi = 0; mi < 4; ++mi)
#pragma unroll
      for (int ni = 0; ni < NI; ++ni)
        acc[mi][ni] = __builtin_amdgcn_mfma_f32_16x16x32_bf16(af[mi], bfr[ni], acc[mi][ni], 0, 0, 0);
  }

  // C/D layout: col = lane&15, row = (lane>>4)*4 + j   [measured m89/m91]
  const int r0 = rowbase + wr * 64 + ((l >> 4) * 4);
  const int ccol = colbase + wc * (BN / 2) + (l & 15);
#pragma unroll
  for (int mi = 0; mi < 4; ++mi) {
#pragma unroll
    for (int j = 0; j < 4; ++j) {
      const size_t r = (size_t)(r0 + mi * 16 + j);
#pragma unroll
      for (int ni = 0; ni < NI; ++ni) {
        const int c = ccol + ni * 16;
        float vv = acc[mi][ni][j];
        if (HASBIAS) vv += bias[c];
        if (OUTF32) {
          ((float*)Cout)[r * M + c] = res[r * M + c] + vv;
        } else {
          ((unsigned short*)Cout)[r * M + c] = f2b(vv);
        }
      }
    }
  }
}

// ---------------- flash attention: 1 block = (b, h, 64 q-rows), 4 waves x 16 rows ---
// Double-buffered K/V staging; R2-verified swizzled LDS layouts.
// Softmax (exp2 domain; S pre-scaled via Wq *= 1/sqrt(D)*log2e):
//   - GROUP max: one Mx per 16-lane group (valid: any consistent per-row offset works;
//     bf16 P carries exponent so low rows lose no precision).
//   - steady state per tile: lane-local max tree + 1 cmp; NO cross-lane reductions.
//   - deferred denominator: per-lane partials Lp[j]; single 16-lane reduce at the end.
//   - rescale branch (rare, ~tile 0 only): group max reduce + alpha on Lp/acc.
// XCD-bijective swizzle: 4 consecutive bh per XCD -> K/V (2MB) resident in one L2.
__global__ __launch_bounds__(256) void attn_kernel(const unsigned short* __restrict__ Q,
                                                   const unsigned short* __restrict__ Kb,
                                                   const unsigned short* __restrict__ Vb,
                                                   unsigned short* __restrict__ O,
                                                   int ld) {
  const int bidl = ((blockIdx.x & 7) << 7) + (blockIdx.x >> 3);  // 1024 = 8 XCD x 128
  const int bh = bidl >> 5;
  const int b = bh / Hh, h = bh % Hh;
  const int q0 = (bidl & 31) * 64;
  const int tid = threadIdx.x, l = tid & 63, w = tid >> 6;
  const size_t base = (size_t)b * Tt * ld + (size_t)h * Dd;
  const size_t baseO = (size_t)b * Tt * Ee + (size_t)h * Dd;

  __shared__ unsigned short Kt[2][64 * 64];
  __shared__ unsigned short Vt[2][64 * 64];
  __shared__ unsigned short Pt[4][16 * 64];

  // Q fragments held in registers: A-layout row = l&15, k-chunk = (l>>4)*8
  sv8 qf0, qf1;
  {
    const unsigned short* qp = Q + base + (size_t)(q0 + w * 16 + (l & 15)) * ld + (l >> 4) * 8;
    qf0 = *(const sv8*)qp;
    qf1 = *(const sv8*)(qp + 32);
  }

  const fv4 zero4 = {0.f, 0.f, 0.f, 0.f};
  fv4 acc_o[4];
#pragma unroll
  for (int i = 0; i < 4; ++i) acc_o[i] = zero4;
  float Mx = -INFINITY;
  float Lp[4];
#pragma unroll
  for (int j = 0; j < 4; ++j) Lp[j] = 0.f;

  const int c0 = tid, c1 = tid + 256;
  const int r0c = c0 >> 3, xc0 = c0 & 7;   // chunk -> (row, chunk-in-row)
  const int r1c = c1 >> 3, xc1 = c1 & 7;   // xc1 == xc0

  sv8 v0, v1;  // V prefetch registers (live across the compute phase)

  // ---- prologue: stage tile 0 ----
  load_lds16(Kb + base + (size_t)(r0c)*ld + (xc0 ^ (r0c & 7)) * 8, Kt[0] + c0 * 8);
  load_lds16(Kb + base + (size_t)(r1c)*ld + (xc1 ^ (r1c & 7)) * 8, Kt[0] + c1 * 8);
  v0 = *(const sv8*)(Vb + base + (size_t)(r0c)*ld + xc0 * 8);
  v1 = *(const sv8*)(Vb + base + (size_t)(r1c)*ld + xc1 * 8);
#pragma unroll
  for (int j = 0; j < 8; ++j) {
    const int d = xc0 * 8 + j;
    Vt[0][d * 64 + ((((r0c >> 3) ^ j ^ xc0) & 7) * 8) + (r0c & 7)] = v0[j];
    Vt[0][d * 64 + ((((r1c >> 3) ^ j ^ xc1) & 7) * 8) + (r1c & 7)] = v1[j];
  }
  __syncthreads();

  int cur = 0;
  for (int kt = 0; kt < Tt / 64; ++kt) {
    const int nx = cur ^ 1;
    const bool pre = (kt + 1 < Tt / 64);
    // ---- prefetch tile kt+1 (async; consumed after B1) ----
    if (pre) {
      load_lds16(Kb + base + (size_t)((kt + 1) * 64 + r0c) * ld + (xc0 ^ (r0c & 7)) * 8, Kt[nx] + c0 * 8);
      load_lds16(Kb + base + (size_t)((kt + 1) * 64 + r1c) * ld + (xc1 ^ (r1c & 7)) * 8, Kt[nx] + c1 * 8);
      v0 = *(const sv8*)(Vb + base + (size_t)((kt + 1) * 64 + r0c) * ld + xc0 * 8);
      v1 = *(const sv8*)(Vb + base + (size_t)((kt + 1) * 64 + r1c) * ld + xc1 * 8);
    }

    // --- S = Q K^T (per wave: 16 q-rows x 64 k-cols) from Kt[cur]; pre-scaled ---
    fv4 s[4];
    __builtin_amdgcn_s_setprio(1);
#pragma unroll
    for (int ks = 0; ks < 4; ++ks) {
      const int row = ks * 16 + (l & 15);
      const sv8 kf0 = *(const sv8*)(Kt[cur] + row * 64 + (((l >> 4) ^ (row & 7)) * 8));
      const sv8 kf1 = *(const sv8*)(Kt[cur] + row * 64 + (((4 + (l >> 4)) ^ (row & 7)) * 8));
      fv4 t = zero4;
      t = __builtin_amdgcn_mfma_f32_16x16x32_bf16(qf0, kf0, t, 0, 0, 0);
      t = __builtin_amdgcn_mfma_f32_16x16x32_bf16(qf1, kf1, t, 0, 0, 0);
      s[ks] = t;
    }
    __builtin_amdgcn_s_setprio(0);

    // --- lane-local overflow check (max3-friendly tree over 16 elems) ---
    float m01 = fmaxf(fmaxf(s[0][0], s[0][1]), fmaxf(s[0][2], s[0][3]));
    float m1 = fmaxf(fmaxf(s[1][0], s[1][1]), fmaxf(s[1][2], s[1][3]));
    float m2 = fmaxf(fmaxf(s[2][0], s[2][1]), fmaxf(s[2][2], s[2][3]));
    float m3 = fmaxf(fmaxf(s[3][0], s[3][1]), fmaxf(s[3][2], s[3][3]));
    float tm = fmaxf(fmaxf(m01, m1), fmaxf(m2, m3));
    if (__any(tm > Mx + 11.5f)) {
      // group max -> rescale (rare; always fires on tile 0 where Mx = -inf)
      float mt = tm;
#pragma unroll
      for (int off = 1; off < 16; off <<= 1) mt = fmaxf(mt, __shfl_xor(mt, off, 16));
      const float mnew = fmaxf(Mx, mt);
      const float alpha = exp2f(Mx - mnew);  // tile 0: exp2(-inf) = 0
      Mx = mnew;
#pragma unroll
      for (int j = 0; j < 4; ++j) {
        Lp[j] *= alpha;
#pragma unroll
        for (int dsb = 0; dsb < 4; ++dsb) acc_o[dsb][j] *= alpha;
      }
    }
    // --- p = exp2(s - Mx); accumulate per-lane partial sums; store P (trunc bf16) ---
#pragma unroll
    for (int ks = 0; ks < 4; ++ks)
#pragma unroll
      for (int j = 0; j < 4; ++j) {
        const float p = exp2f(s[ks][j] - Mx);
        s[ks][j] = p;
        Lp[j] += p;
      }
#pragma unroll
    for (int ks = 0; ks < 4; ++ks)
#pragma unroll
      for (int j = 0; j < 4; ++j) {
        const int q = (l >> 4) * 4 + j, k = ks * 16 + (l & 15);
        Pt[w][q * 64 + ((((k >> 3) ^ (q & 7)) & 7) * 8) + (k & 7)] = f2b_rtz(s[ks][j]);
      }
    asm volatile("s_waitcnt lgkmcnt(0)" ::: "memory");

    // --- O += P V : all-vector b128 reads from swizzled Pt/Vt[cur] ---
    __builtin_amdgcn_s_setprio(1);
#pragma unroll
    for (int kcn = 0; kcn < 2; ++kcn) {
      const int qr = l & 15;
      const sv8 pf = *(const sv8*)(&Pt[w][qr * 64 + (((kcn * 4 + (l >> 4)) ^ (qr & 7)) * 8)]);
#pragma unroll
      for (int dsb = 0; dsb < 4; ++dsb) {
        const int d = dsb * 16 + (l & 15);
        const sv8 vf = *(const sv8*)(Vt[cur] + d * 64 +
                        ((((kcn * 4 + (l >> 4)) ^ (d & 7) ^ ((d >> 3) & 7)) & 7) * 8));
        acc_o[dsb] = __builtin_amdgcn_mfma_f32_16x16x32_bf16(pf, vf, acc_o[dsb], 0, 0, 0);
      }
    }
    __builtin_amdgcn_s_setprio(0);

    __syncthreads();  // B1: all PV reads of Vt[cur] done; K prefetch (vmcnt) drained
    if (pre) {
#pragma unroll
      for (int j = 0; j < 8; ++j) {
        const int d = xc0 * 8 + j;
        Vt[nx][d * 64 + ((((r0c >> 3) ^ j ^ xc0) & 7) * 8) + (r0c & 7)] = v0[j];
        Vt[nx][d * 64 + ((((r1c >> 3) ^ j ^ xc1) & 7) * 8) + (r1c & 7)] = v1[j];
      }
    }
    __syncthreads();  // B2: Vt[nx] visible to all
    cur = nx;
  }

  // ---- deferred denominator: one 16-lane reduce per q-row, then write O ----
#pragma unroll
  for (int j = 0; j < 4; ++j) {
    float t = Lp[j];
#pragma unroll
    for (int off = 1; off < 16; off <<= 1) t += __shfl_xor(t, off, 16);
    const float inv = 1.f / t;
    unsigned short* op = O + baseO + (size_t)(q0 + w * 16 + (l >> 4) * 4 + j) * Ee;
#pragma unroll
    for (int dsb = 0; dsb < 4; ++dsb)
      op[dsb * 16 + (l & 15)] = f2b(acc_o[dsb][j] * inv);
  }
}

// ---------------- GEGLU: f = a * gelu_exact(g) ----------------
__global__ __launch_bounds__(256) void geglu_kernel(const unsigned short* __restrict__ u,
                                                    unsigned short* __restrict__ f) {
  const int t = blockIdx.x * 256 + threadIdx.x;
  const int n = t >> 10;            // FFd/4 = 1024 threads per row
  const int j4 = (t & 1023) * 4;
  const unsigned short* ua = u + (size_t)n * (2 * FFd) + j4;
  const sv4 av = *(const sv4*)ua;
  const sv4 gv = *(const sv4*)(ua + FFd);
  sv4 o;
#pragma unroll
  for (int i = 0; i < 4; ++i) {
    const float a = b2f((unsigned short)av[i]);
    const float g = b2f((unsigned short)gv[i]);
    o[i] = (short)f2b(a * 0.5f * g * (1.f + erff(g * 0.70710678118654752f)));
  }
  *(sv4*)(f + (size_t)n * FFd + j4) = o;
}

extern "C" void kernel_launch(void* const* d_in, const int* in_sizes, int n_in,
                              void* d_out, int out_size, void* d_ws, size_t ws_size,
                              hipStream_t stream) {
  (void)in_sizes; (void)n_in; (void)out_size; (void)ws_size;
  const float* src  = (const float*)d_in[0];
  const float* Wq   = (const float*)d_in[1];
  const float* Wk   = (const float*)d_in[2];
  const float* Wv   = (const float*)d_in[3];
  const float* Wo   = (const float*)d_in[4];
  const float* W1   = (const float*)d_in[5];
  const float* b1   = (const float*)d_in[6];
  const float* W2   = (const float*)d_in[7];
  const float* b2   = (const float*)d_in[8];
  const float* ln1w = (const float*)d_in[9];
  const float* ln1b = (const float*)d_in[10];
  const float* ln2w = (const float*)d_in[11];
  const float* ln2b = (const float*)d_in[12];
  float* out = (float*)d_out;

  char* ws = (char*)d_ws;
  size_t off = 0;
  auto alloc = [&](size_t bytes) { char* p = ws + off; off += bytes; return p; };
  unsigned short* wqkv = (unsigned short*)alloc((size_t)3 * Ee * Ee * 2);  // Wq|Wk|Wv rows
  unsigned short* wo16 = (unsigned short*)alloc((size_t)Ee * Ee * 2);
  unsigned short* w116 = (unsigned short*)alloc((size_t)2 * FFd * Ee * 2);
  unsigned short* w216 = (unsigned short*)alloc((size_t)Ee * FFd * 2);
  unsigned short* h16  = (unsigned short*)alloc((size_t)NN * Ee * 2);
  unsigned short* qkv  = (unsigned short*)alloc((size_t)NN * 3 * Ee * 2);  // [row][3E]
  unsigned short* a16  = (unsigned short*)alloc((size_t)NN * Ee * 2);
  float* xbuf          = (float*)alloc((size_t)NN * Ee * 4);
  unsigned short* u16  = (unsigned short*)alloc((size_t)NN * 2 * FFd * 2);
  unsigned short* f16  = qkv;  // reuse qkv+a16 region (33.5 MB) after attention done

  const float s2 = 0.125f * 1.4426950408889634f;  // 1/sqrt(D) * log2(e), folded into Wq

  dim3 blk(256);
  cvt_kernel<<<dim3(Ee * Ee / 1024), blk, 0, stream>>>(Wq, wqkv, Ee * Ee, s2);
  cvt_kernel<<<dim3(Ee * Ee / 1024), blk, 0, stream>>>(Wk, wqkv + Ee * Ee, Ee * Ee, 1.0f);
  cvt_kernel<<<dim3(Ee * Ee / 1024), blk, 0, stream>>>(Wv, wqkv + 2 * Ee * Ee, Ee * Ee, 1.0f);
  cvt_kernel<<<dim3(Ee * Ee / 1024), blk, 0, stream>>>(Wo, wo16, Ee * Ee, 1.0f);
  cvt_kernel<<<dim3(2 * FFd * Ee / 1024), blk, 0, stream>>>(W1, w116, 2 * FFd * Ee, 1.0f);
  cvt_kernel<<<dim3(Ee * FFd / 1024), blk, 0, stream>>>(W2, w216, Ee * FFd, 1.0f);

  ln_kernel<<<dim3(NN), blk, 0, stream>>>(src, ln1w, ln1b, h16);

  // fused QKV projection: [4096,1024] x [3072,1024]^T -> [4096,3072]
  gemm_bt<0, 0, 128><<<dim3(3 * Ee / 128, NN / 128), blk, 0, stream>>>(h16, wqkv, qkv, nullptr, nullptr, 3 * Ee, Ee);

  attn_kernel<<<dim3(1024), blk, 0, stream>>>(qkv, qkv + Ee, qkv + 2 * Ee, a16, 3 * Ee);

  // Wo projection + residual (BN=64: 512 blocks, 2/CU)
  gemm_bt<1, 0, 64><<<dim3(Ee / 64, NN / 128), blk, 0, stream>>>(a16, wo16, xbuf, nullptr, src, Ee, Ee);

  ln_kernel<<<dim3(NN), blk, 0, stream>>>(xbuf, ln2w, ln2b, h16);

  gemm_bt<0, 1, 128><<<dim3(2 * FFd / 128, NN / 128), blk, 0, stream>>>(h16, w116, u16, b1, nullptr, 2 * FFd, Ee);

  geglu_kernel<<<dim3(NN * FFd / 1024), blk, 0, stream>>>(u16, f16);

  // W2 projection + bias + residual (BN=64: 512 blocks, 2/CU)
  gemm_bt<1, 1, 64><<<dim3(Ee / 64, NN / 128), blk, 0, stream>>>(f16, w216, out, b2, xbuf, Ee, FFd);
}

// Round 7
// 376.579 us; speedup vs baseline: 1.3704x; 1.0112x over previous
//
#include <hip/hip_runtime.h>
#include <stdint.h>
#include <math.h>

#define DEVI __device__ __forceinline__

typedef __attribute__((ext_vector_type(8))) short sv8;
typedef __attribute__((ext_vector_type(4))) short sv4;
typedef __attribute__((ext_vector_type(4))) float fv4;

typedef __attribute__((address_space(1))) void av1_t;
typedef __attribute__((address_space(3))) void av3_t;

constexpr int Bb = 2, Tt = 2048, Ee = 1024, Hh = 16, Dd = 64, FFd = 4096;
constexpr int NN = Bb * Tt;  // 4096 token rows
constexpr float EPSv = 1e-5f;

DEVI float b2f(unsigned short s) {
  union { unsigned u; float f; } v; v.u = ((unsigned)s) << 16; return v.f;
}
DEVI unsigned short f2b(float f) {
  union { float f; unsigned u; } v; v.f = f;
  return (unsigned short)((v.u + 0x7FFFu + ((v.u >> 16) & 1u)) >> 16);
}
DEVI unsigned short f2b_rtz(float f) {  // truncation: 1 VALU op (softmax P only)
  union { float f; unsigned u; } v; v.f = f;
  return (unsigned short)(v.u >> 16);
}

// global -> LDS direct (16B per lane). LDS dest must be wave-uniform base + lane*16.
DEVI void load_lds16(const void* g, void* s) {
  __builtin_amdgcn_global_load_lds((av1_t*)(unsigned long long)g,
                                   (av3_t*)(unsigned)(unsigned long long)s,
                                   16, 0, 0);
}

// ---------------- fp32 -> bf16 convert (optional scale fold) ----------------
__global__ __launch_bounds__(256) void cvt_kernel(const float* __restrict__ in,
                                                  unsigned short* __restrict__ out, int n,
                                                  float scale) {
  int i = (blockIdx.x * 256 + threadIdx.x) * 4;
  if (i >= n) return;
  float4 v = *(const float4*)(in + i);
  sv4 o;
  o[0] = (short)f2b(v.x * scale); o[1] = (short)f2b(v.y * scale);
  o[2] = (short)f2b(v.z * scale); o[3] = (short)f2b(v.w * scale);
  *(sv4*)(out + i) = o;
}

// ---------------- W1 convert with row interleave: out[2j]=W1[j], out[2j+1]=W1[j+FFd] -
__global__ __launch_bounds__(256) void cvt_w1_kernel(const float* __restrict__ in,
                                                     unsigned short* __restrict__ out) {
  int i = (blockIdx.x * 256 + threadIdx.x) * 4;  // flat over 2*FFd*Ee
  const int r = i >> 10, c = i & 1023;
  const int rp = (r < FFd) ? (2 * r) : (2 * (r - FFd) + 1);
  float4 v = *(const float4*)(in + i);
  sv4 o;
  o[0] = (short)f2b(v.x); o[1] = (short)f2b(v.y);
  o[2] = (short)f2b(v.z); o[3] = (short)f2b(v.w);
  *(sv4*)(out + (size_t)rp * Ee + c) = o;
}

// ---------------- V transpose: qkv V-slice [t][h*64+d] -> vT[b][h][d][t] ----------
__global__ __launch_bounds__(256) void vt_kernel(const unsigned short* __restrict__ qkv,
                                                 unsigned short* __restrict__ vT) {
  const int bh = blockIdx.y;               // b*16+h
  const int b = bh >> 4, h = bh & 15;
  const int tt = blockIdx.x * 64;          // token tile
  const int tid = threadIdx.x;
  __shared__ unsigned short tile[64][65];  // +1 pad
  const int tr = tid >> 2, tc4 = (tid & 3) * 16;
  const unsigned short* src = qkv + (size_t)(b * Tt + tt + tr) * (3 * Ee) + 2 * Ee + h * 64 + tc4;
  const sv8 a0 = *(const sv8*)src;
  const sv8 a1 = *(const sv8*)(src + 8);
#pragma unroll
  for (int j = 0; j < 8; ++j) { tile[tr][tc4 + j] = a0[j]; tile[tr][tc4 + 8 + j] = a1[j]; }
  __syncthreads();
  unsigned short* dst = vT + ((size_t)bh * 64 + tr) * Tt + tt + tc4;
  sv8 o0, o1;
#pragma unroll
  for (int j = 0; j < 8; ++j) { o0[j] = (short)tile[tc4 + j][tr]; o1[j] = (short)tile[tc4 + 8 + j][tr]; }
  *(sv8*)dst = o0;
  *(sv8*)(dst + 8) = o1;
}

// ---------------- LayerNorm (fp32 in, bf16 out), one block per row ----------------
__global__ __launch_bounds__(256) void ln_kernel(const float* __restrict__ x,
                                                 const float* __restrict__ g,
                                                 const float* __restrict__ b,
                                                 unsigned short* __restrict__ out) {
  const int row = blockIdx.x, tid = threadIdx.x;
  const float4 v = *(const float4*)(x + (size_t)row * Ee + tid * 4);
  float s = v.x + v.y + v.z + v.w;
  float ss = v.x * v.x + v.y * v.y + v.z * v.z + v.w * v.w;
#pragma unroll
  for (int off = 32; off; off >>= 1) { s += __shfl_down(s, off); ss += __shfl_down(ss, off); }
  __shared__ float red[16];
  const int w = tid >> 6, l = tid & 63;
  if (l == 0) { red[w] = s; red[8 + w] = ss; }
  __syncthreads();
  s = red[0] + red[1] + red[2] + red[3];
  ss = red[8] + red[9] + red[10] + red[11];
  const float mean = s * (1.f / Ee);
  const float rstd = rsqrtf(ss * (1.f / Ee) - mean * mean + EPSv);
  const float4 gv = *(const float4*)(g + tid * 4);
  const float4 bv = *(const float4*)(b + tid * 4);
  sv4 o;
  o[0] = (short)f2b((v.x - mean) * rstd * gv.x + bv.x);
  o[1] = (short)f2b((v.y - mean) * rstd * gv.y + bv.y);
  o[2] = (short)f2b((v.z - mean) * rstd * gv.z + bv.z);
  o[3] = (short)f2b((v.w - mean) * rstd * gv.w + bv.w);
  *(sv4*)(out + (size_t)row * Ee + tid * 4) = o;
}

// ---------------- bf16 GEMM: C[n,m] = sum_k A[n,k]*B[m,k] variants ----------------
// 128xBN tile, BK=32, 4 waves (2x2). GEGLU=1: interleaved-W1 output; epilogue computes
// f[r][c>>1] = (even col + b1) * gelu_exact(odd col + b1') via lane-pair shfl; writes
// bf16 f with stride M/2. (bias pointer = raw fp32 b1 of length M.)
template <int OUTF32, int HASBIAS, int BN, int GEGLU>
__global__ __launch_bounds__(256) void gemm_bt(const unsigned short* __restrict__ A,
                                               const unsigned short* __restrict__ Bw,
                                               void* __restrict__ Cout,
                                               const float* __restrict__ bias,
                                               const float* __restrict__ res,
                                               int M, int K) {
  constexpr int NI = BN / 32;  // per-wave n-frags (wave covers BN/2 cols)
  __shared__ unsigned short lA[128 * 32];
  __shared__ unsigned short lB[BN * 32];
  const int tid = threadIdx.x;
  const int l = tid & 63, w = tid >> 6;
  const int wr = w >> 1, wc = w & 1;
  const int rowbase = blockIdx.y * 128, colbase = blockIdx.x * BN;

  const fv4 zero4 = {0.f, 0.f, 0.f, 0.f};
  fv4 acc[4][NI];
#pragma unroll
  for (int i = 0; i < 4; ++i)
#pragma unroll
    for (int j = 0; j < NI; ++j) acc[i][j] = zero4;

  // staging: A = 512 chunks of 8 bf16 (threads do c0,c1); B = BN*4 chunks.
  const int c0 = tid, c1 = tid + 256;
  const unsigned short* Ag0 = A + (size_t)(rowbase + (c0 >> 2)) * K + (c0 & 3) * 8;
  const unsigned short* Ag1 = A + (size_t)(rowbase + (c1 >> 2)) * K + (c1 & 3) * 8;
  const unsigned short* Bg0 = Bw + (size_t)(colbase + (c0 >> 2)) * K + (c0 & 3) * 8;
  const unsigned short* Bg1 = Bw + (size_t)(colbase + ((BN == 128 ? c1 : c0) >> 2)) * K + (c0 & 3) * 8;

  const int nk = K >> 5;
  const int kc = (l >> 4) * 8;
  for (int kt = 0; kt < nk; ++kt) {
    __syncthreads();
    load_lds16(Ag0, lA + c0 * 8);
    load_lds16(Ag1, lA + c1 * 8);
    load_lds16(Bg0, lB + c0 * 8);
    if (BN == 128) load_lds16(Bg1, lB + c1 * 8);
    Ag0 += 32; Ag1 += 32; Bg0 += 32; Bg1 += 32;
    __syncthreads();
    sv8 af[4], bfr[NI];
#pragma unroll
    for (int i = 0; i < 4; ++i)
      af[i] = *(const sv8*)(lA + (wr * 64 + i * 16 + (l & 15)) * 32 + kc);
#pragma unroll
    for (int i = 0; i < NI; ++i)
      bfr[i] = *(const sv8*)(lB + (wc * (BN / 2) + i * 16 + (l & 15)) * 32 + kc);
#pragma unroll
    for (int mi = 0; mi < 4; ++mi)
#pragma unroll
      for (int ni = 0; ni < NI; ++ni)
        acc[mi][ni] = __builtin_amdgcn_mfma_f32_16x16x32_bf16(af[mi], bfr[ni], acc[mi][ni], 0, 0, 0);
  }

  // C/D layout: col = lane&15, row = (lane>>4)*4 + j   [measured m89/m91]
  const int r0 = rowbase + wr * 64 + ((l >> 4) * 4);
  const int ccol = colbase + wc * (BN / 2) + (l & 15);
#pragma unroll
  for (int mi = 0; mi < 4; ++mi) {
#pragma unroll
    for (int j = 0; j < 4; ++j) {
      const size_t r = (size_t)(r0 + mi * 16 + j);
#pragma unroll
      for (int ni = 0; ni < NI; ++ni) {
        const int c = ccol + ni * 16;
        if (GEGLU) {
          // interleaved bias: b1'[c] = b1[(c>>1) + (c&1)*(M/2)]
          const float vvb = acc[mi][ni][j] + bias[(c >> 1) + (c & 1) * (M >> 1)];
          const float gel = 0.5f * vvb * (1.f + erff(vvb * 0.70710678118654752f));
          const float ge = __shfl_xor(gel, 1);
          if (!(l & 1))
            ((unsigned short*)Cout)[r * (M >> 1) + (c >> 1)] = f2b(vvb * ge);
        } else {
          float vv = acc[mi][ni][j];
          if (HASBIAS) vv += bias[c];
          if (OUTF32) {
            ((float*)Cout)[r * M + c] = res[r * M + c] + vv;
          } else {
            ((unsigned short*)Cout)[r * M + c] = f2b(vv);
          }
        }
      }
    }
  }
}

// ---------------- flash attention: 1 block = (b, h, 64 q-rows), 4 waves x 16 rows ---
// K AND V both staged via global_load_lds with pre-swizzled source (V from the
// pre-transposed vT[b][h][d][t] buffer) -> no reg-staging, ONE barrier per iter.
// Softmax: exp2 domain (scale folded into Wq), group max, deferred denominator.
// XCD-bijective swizzle: K/V working set resident in one XCD's L2.
__global__ __launch_bounds__(256) void attn_kernel(const unsigned short* __restrict__ Q,
                                                   const unsigned short* __restrict__ Kb,
                                                   const unsigned short* __restrict__ vT,
                                                   unsigned short* __restrict__ O,
                                                   int ld) {
  const int bidl = ((blockIdx.x & 7) << 7) + (blockIdx.x >> 3);  // 1024 = 8 XCD x 128
  const int bh = bidl >> 5;
  const int b = bh / Hh, h = bh % Hh;
  const int q0 = (bidl & 31) * 64;
  const int tid = threadIdx.x, l = tid & 63, w = tid >> 6;
  const size_t base = (size_t)b * Tt * ld + (size_t)h * Dd;
  const size_t baseO = (size_t)b * Tt * Ee + (size_t)h * Dd;
  const unsigned short* vTb = vT + (size_t)bh * 64 * Tt;  // [64 d][2048 t]

  __shared__ unsigned short Kt[2][64 * 64];
  __shared__ unsigned short Vt[2][64 * 64];
  __shared__ unsigned short Pt[4][16 * 64];

  // Q fragments held in registers: A-layout row = l&15, k-chunk = (l>>4)*8
  sv8 qf0, qf1;
  {
    const unsigned short* qp = Q + base + (size_t)(q0 + w * 16 + (l & 15)) * ld + (l >> 4) * 8;
    qf0 = *(const sv8*)qp;
    qf1 = *(const sv8*)(qp + 32);
  }

  const fv4 zero4 = {0.f, 0.f, 0.f, 0.f};
  fv4 acc_o[4];
#pragma unroll
  for (int i = 0; i < 4; ++i) acc_o[i] = zero4;
  float Mx = -INFINITY;
  float Lp[4];
#pragma unroll
  for (int j = 0; j < 4; ++j) Lp[j] = 0.f;

  const int c0 = tid, c1 = tid + 256;
  const int r0c = c0 >> 3, xc0 = c0 & 7;   // chunk -> (row, chunk-in-row)
  const int r1c = c1 >> 3, xc1 = c1 & 7;   // xc1 == xc0

  // ---- prologue: stage tile 0 (K rows = tokens; V rows = d from vT) ----
  load_lds16(Kb + base + (size_t)(r0c)*ld + (xc0 ^ (r0c & 7)) * 8, Kt[0] + c0 * 8);
  load_lds16(Kb + base + (size_t)(r1c)*ld + (xc1 ^ (r1c & 7)) * 8, Kt[0] + c1 * 8);
  load_lds16(vTb + (size_t)(r0c)*Tt + (xc0 ^ (r0c & 7)) * 8, Vt[0] + c0 * 8);
  load_lds16(vTb + (size_t)(r1c)*Tt + (xc1 ^ (r1c & 7)) * 8, Vt[0] + c1 * 8);
  __syncthreads();

  int cur = 0;
  for (int kt = 0; kt < Tt / 64; ++kt) {
    const int nx = cur ^ 1;
    // ---- prefetch tile kt+1 (async; drained by the end-of-iter barrier) ----
    if (kt + 1 < Tt / 64) {
      load_lds16(Kb + base + (size_t)((kt + 1) * 64 + r0c) * ld + (xc0 ^ (r0c & 7)) * 8, Kt[nx] + c0 * 8);
      load_lds16(Kb + base + (size_t)((kt + 1) * 64 + r1c) * ld + (xc1 ^ (r1c & 7)) * 8, Kt[nx] + c1 * 8);
      load_lds16(vTb + (size_t)(r0c)*Tt + (kt + 1) * 64 + (xc0 ^ (r0c & 7)) * 8, Vt[nx] + c0 * 8);
      load_lds16(vTb + (size_t)(r1c)*Tt + (kt + 1) * 64 + (xc1 ^ (r1c & 7)) * 8, Vt[nx] + c1 * 8);
    }

    // --- S = Q K^T (per wave: 16 q-rows x 64 k-cols) from Kt[cur]; pre-scaled ---
    fv4 s[4];
    __builtin_amdgcn_s_setprio(1);
#pragma unroll
    for (int ks = 0; ks < 4; ++ks) {
      const int row = ks * 16 + (l & 15);
      const sv8 kf0 = *(const sv8*)(Kt[cur] + row * 64 + (((l >> 4) ^ (row & 7)) * 8));
      const sv8 kf1 = *(const sv8*)(Kt[cur] + row * 64 + (((4 + (l >> 4)) ^ (row & 7)) * 8));
      fv4 t = zero4;
      t = __builtin_amdgcn_mfma_f32_16x16x32_bf16(qf0, kf0, t, 0, 0, 0);
      t = __builtin_amdgcn_mfma_f32_16x16x32_bf16(qf1, kf1, t, 0, 0, 0);
      s[ks] = t;
    }
    __builtin_amdgcn_s_setprio(0);

    // --- lane-local overflow check ---
    float m01 = fmaxf(fmaxf(s[0][0], s[0][1]), fmaxf(s[0][2], s[0][3]));
    float m1 = fmaxf(fmaxf(s[1][0], s[1][1]), fmaxf(s[1][2], s[1][3]));
    float m2 = fmaxf(fmaxf(s[2][0], s[2][1]), fmaxf(s[2][2], s[2][3]));
    float m3 = fmaxf(fmaxf(s[3][0], s[3][1]), fmaxf(s[3][2], s[3][3]));
    float tm = fmaxf(fmaxf(m01, m1), fmaxf(m2, m3));
    if (__any(tm > Mx + 11.5f)) {
      // group max -> rescale (rare; always fires on tile 0 where Mx = -inf)
      float mt = tm;
#pragma unroll
      for (int off = 1; off < 16; off <<= 1) mt = fmaxf(mt, __shfl_xor(mt, off, 16));
      const float mnew = fmaxf(Mx, mt);
      const float alpha = exp2f(Mx - mnew);  // tile 0: exp2(-inf) = 0
      Mx = mnew;
#pragma unroll
      for (int j = 0; j < 4; ++j) {
        Lp[j] *= alpha;
#pragma unroll
        for (int dsb = 0; dsb < 4; ++dsb) acc_o[dsb][j] *= alpha;
      }
    }
    // --- p = exp2(s - Mx); per-lane partial sums; store P (trunc bf16) ---
#pragma unroll
    for (int ks = 0; ks < 4; ++ks)
#pragma unroll
      for (int j = 0; j < 4; ++j) {
        const float p = exp2f(s[ks][j] - Mx);
        s[ks][j] = p;
        Lp[j] += p;
      }
#pragma unroll
    for (int ks = 0; ks < 4; ++ks)
#pragma unroll
      for (int j = 0; j < 4; ++j) {
        const int q = (l >> 4) * 4 + j, k = ks * 16 + (l & 15);
        Pt[w][q * 64 + ((((k >> 3) ^ (q & 7)) & 7) * 8) + (k & 7)] = f2b_rtz(s[ks][j]);
      }
    asm volatile("s_waitcnt lgkmcnt(0)" ::: "memory");

    // --- O += P V : b128 reads from swizzled Pt / Vt[cur] (d-major rows) ---
    __builtin_amdgcn_s_setprio(1);
#pragma unroll
    for (int kcn = 0; kcn < 2; ++kcn) {
      const int qr = l & 15;
      const sv8 pf = *(const sv8*)(&Pt[w][qr * 64 + (((kcn * 4 + (l >> 4)) ^ (qr & 7)) * 8)]);
#pragma unroll
      for (int dsb = 0; dsb < 4; ++dsb) {
        const int row = dsb * 16 + (l & 15);
        const int chunk = kcn * 4 + (l >> 4);
        const sv8 vf = *(const sv8*)(Vt[cur] + row * 64 + ((chunk ^ (row & 7)) * 8));
        acc_o[dsb] = __builtin_amdgcn_mfma_f32_16x16x32_bf16(pf, vf, acc_o[dsb], 0, 0, 0);
      }
    }
    __builtin_amdgcn_s_setprio(0);

    __syncthreads();  // drains prefetch vmcnt; all waves done reading [cur]
    cur = nx;
  }

  // ---- deferred denominator: one 16-lane reduce per q-row, then write O ----
#pragma unroll
  for (int j = 0; j < 4; ++j) {
    float t = Lp[j];
#pragma unroll
    for (int off = 1; off < 16; off <<= 1) t += __shfl_xor(t, off, 16);
    const float inv = 1.f / t;
    unsigned short* op = O + baseO + (size_t)(q0 + w * 16 + (l >> 4) * 4 + j) * Ee;
#pragma unroll
    for (int dsb = 0; dsb < 4; ++dsb)
      op[dsb * 16 + (l & 15)] = f2b(acc_o[dsb][j] * inv);
  }
}

extern "C" void kernel_launch(void* const* d_in, const int* in_sizes, int n_in,
                              void* d_out, int out_size, void* d_ws, size_t ws_size,
                              hipStream_t stream) {
  (void)in_sizes; (void)n_in; (void)out_size; (void)ws_size;
  const float* src  = (const float*)d_in[0];
  const float* Wq   = (const float*)d_in[1];
  const float* Wk   = (const float*)d_in[2];
  const float* Wv   = (const float*)d_in[3];
  const float* Wo   = (const float*)d_in[4];
  const float* W1   = (const float*)d_in[5];
  const float* b1   = (const float*)d_in[6];
  const float* W2   = (const float*)d_in[7];
  const float* b2   = (const float*)d_in[8];
  const float* ln1w = (const float*)d_in[9];
  const float* ln1b = (const float*)d_in[10];
  const float* ln2w = (const float*)d_in[11];
  const float* ln2b = (const float*)d_in[12];
  float* out = (float*)d_out;

  char* ws = (char*)d_ws;
  size_t off = 0;
  auto alloc = [&](size_t bytes) { char* p = ws + off; off += bytes; return p; };
  unsigned short* wqkv = (unsigned short*)alloc((size_t)3 * Ee * Ee * 2);  // Wq|Wk|Wv rows
  unsigned short* wo16 = (unsigned short*)alloc((size_t)Ee * Ee * 2);
  unsigned short* w116 = (unsigned short*)alloc((size_t)2 * FFd * Ee * 2); // interleaved
  unsigned short* w216 = (unsigned short*)alloc((size_t)Ee * FFd * 2);
  unsigned short* h16  = (unsigned short*)alloc((size_t)NN * Ee * 2);
  unsigned short* qkv  = (unsigned short*)alloc((size_t)NN * 3 * Ee * 2);  // [row][3E]
  unsigned short* a16  = (unsigned short*)alloc((size_t)NN * Ee * 2);
  float* xbuf          = (float*)alloc((size_t)NN * Ee * 4);
  unsigned short* vT   = (unsigned short*)alloc((size_t)NN * Ee * 2);      // [b][h][64][T]
  unsigned short* f16  = qkv;  // reuse qkv+a16 region (32 MB) after attention done

  const float s2 = 0.125f * 1.4426950408889634f;  // 1/sqrt(D) * log2(e), folded into Wq

  dim3 blk(256);
  cvt_kernel<<<dim3(Ee * Ee / 1024), blk, 0, stream>>>(Wq, wqkv, Ee * Ee, s2);
  cvt_kernel<<<dim3(Ee * Ee / 1024), blk, 0, stream>>>(Wk, wqkv + Ee * Ee, Ee * Ee, 1.0f);
  cvt_kernel<<<dim3(Ee * Ee / 1024), blk, 0, stream>>>(Wv, wqkv + 2 * Ee * Ee, Ee * Ee, 1.0f);
  cvt_kernel<<<dim3(Ee * Ee / 1024), blk, 0, stream>>>(Wo, wo16, Ee * Ee, 1.0f);
  cvt_w1_kernel<<<dim3(2 * FFd * Ee / 1024), blk, 0, stream>>>(W1, w116);
  cvt_kernel<<<dim3(Ee * FFd / 1024), blk, 0, stream>>>(W2, w216, Ee * FFd, 1.0f);

  ln_kernel<<<dim3(NN), blk, 0, stream>>>(src, ln1w, ln1b, h16);

  // fused QKV projection: [4096,1024] x [3072,1024]^T -> [4096,3072]
  gemm_bt<0, 0, 128, 0><<<dim3(3 * Ee / 128, NN / 128), blk, 0, stream>>>(h16, wqkv, qkv, nullptr, nullptr, 3 * Ee, Ee);

  // V transpose: [t][h*64+d] -> vT[b][h][d][t]
  vt_kernel<<<dim3(Tt / 64, Bb * Hh), blk, 0, stream>>>(qkv, vT);

  attn_kernel<<<dim3(1024), blk, 0, stream>>>(qkv, qkv + Ee, vT, a16, 3 * Ee);

  // Wo projection + residual (BN=64: 512 blocks, 2/CU)
  gemm_bt<1, 0, 64, 0><<<dim3(Ee / 64, NN / 128), blk, 0, stream>>>(a16, wo16, xbuf, nullptr, src, Ee, Ee);

  ln_kernel<<<dim3(NN), blk, 0, stream>>>(xbuf, ln2w, ln2b, h16);

  // W1 (interleaved) + fused GEGLU epilogue -> f16 [4096][4096]
  gemm_bt<0, 0, 128, 1><<<dim3(2 * FFd / 128, NN / 128), blk, 0, stream>>>(h16, w116, f16, b1, nullptr, 2 * FFd, Ee);

  // W2 projection + bias + residual (BN=64: 512 blocks, 2/CU)
  gemm_bt<1, 1, 64, 0><<<dim3(Ee / 64, NN / 128), blk, 0, stream>>>(f16, w216, out, b2, xbuf, Ee, FFd);
}

// Round 8
// 362.200 us; speedup vs baseline: 1.4248x; 1.0397x over previous
//
#include <hip/hip_runtime.h>
#include <stdint.h>
#include <math.h>

#define DEVI __device__ __forceinline__

typedef __attribute__((ext_vector_type(8))) short sv8;
typedef __attribute__((ext_vector_type(4))) short sv4;
typedef __attribute__((ext_vector_type(4))) float fv4;

typedef __attribute__((address_space(1))) void av1_t;
typedef __attribute__((address_space(3))) void av3_t;

constexpr int Bb = 2, Tt = 2048, Ee = 1024, Hh = 16, Dd = 64, FFd = 4096;
constexpr int NN = Bb * Tt;  // 4096 token rows
constexpr float EPSv = 1e-5f;

DEVI float b2f(unsigned short s) {
  union { unsigned u; float f; } v; v.u = ((unsigned)s) << 16; return v.f;
}
DEVI unsigned short f2b(float f) {
  union { float f; unsigned u; } v; v.f = f;
  return (unsigned short)((v.u + 0x7FFFu + ((v.u >> 16) & 1u)) >> 16);
}
DEVI unsigned short f2b_rtz(float f) {  // truncation: 1 VALU op (softmax P only)
  union { float f; unsigned u; } v; v.f = f;
  return (unsigned short)(v.u >> 16);
}

// global -> LDS direct (16B per lane). LDS dest must be wave-uniform base + lane*16.
DEVI void load_lds16(const void* g, void* s) {
  __builtin_amdgcn_global_load_lds((av1_t*)(unsigned long long)g,
                                   (av3_t*)(unsigned)(unsigned long long)s,
                                   16, 0, 0);
}

// ---------------- fp32 -> bf16 convert (optional scale fold) ----------------
__global__ __launch_bounds__(256) void cvt_kernel(const float* __restrict__ in,
                                                  unsigned short* __restrict__ out, int n,
                                                  float scale) {
  int i = (blockIdx.x * 256 + threadIdx.x) * 4;
  if (i >= n) return;
  float4 v = *(const float4*)(in + i);
  sv4 o;
  o[0] = (short)f2b(v.x * scale); o[1] = (short)f2b(v.y * scale);
  o[2] = (short)f2b(v.z * scale); o[3] = (short)f2b(v.w * scale);
  *(sv4*)(out + i) = o;
}

// -------- W1 convert, block-16 interleave: a-row r -> 32*(r>>4)+(r&15);
//          gate-row (r-FFd) -> 32*((r-FFd)>>4)+16+(r&15). Even 16-col fragment = a,
//          odd = gate, SAME output cols -> lane-local GEGLU in the GEMM epilogue.
__global__ __launch_bounds__(256) void cvt_w1_kernel(const float* __restrict__ in,
                                                     unsigned short* __restrict__ out) {
  int i = (blockIdx.x * 256 + threadIdx.x) * 4;  // flat over 2*FFd*Ee
  const int r = i >> 10, c = i & 1023;
  const int rp = (r < FFd) ? ((r >> 4) * 32 + (r & 15))
                           : (((r - FFd) >> 4) * 32 + 16 + (r & 15));
  float4 v = *(const float4*)(in + i);
  sv4 o;
  o[0] = (short)f2b(v.x); o[1] = (short)f2b(v.y);
  o[2] = (short)f2b(v.z); o[3] = (short)f2b(v.w);
  *(sv4*)(out + (size_t)rp * Ee + c) = o;
}

// ---------------- V transpose: qkv V-slice [t][h*64+d] -> vT[b][h][d][t] ----------
__global__ __launch_bounds__(256) void vt_kernel(const unsigned short* __restrict__ qkv,
                                                 unsigned short* __restrict__ vT) {
  const int bh = blockIdx.y;               // b*16+h
  const int b = bh >> 4, h = bh & 15;
  const int tt = blockIdx.x * 64;          // token tile
  const int tid = threadIdx.x;
  __shared__ unsigned short tile[64][65];  // +1 pad
  const int tr = tid >> 2, tc4 = (tid & 3) * 16;
  const unsigned short* src = qkv + (size_t)(b * Tt + tt + tr) * (3 * Ee) + 2 * Ee + h * 64 + tc4;
  const sv8 a0 = *(const sv8*)src;
  const sv8 a1 = *(const sv8*)(src + 8);
#pragma unroll
  for (int j = 0; j < 8; ++j) { tile[tr][tc4 + j] = a0[j]; tile[tr][tc4 + 8 + j] = a1[j]; }
  __syncthreads();
  unsigned short* dst = vT + ((size_t)bh * 64 + tr) * Tt + tt + tc4;
  sv8 o0, o1;
#pragma unroll
  for (int j = 0; j < 8; ++j) { o0[j] = (short)tile[tc4 + j][tr]; o1[j] = (short)tile[tc4 + 8 + j][tr]; }
  *(sv8*)dst = o0;
  *(sv8*)(dst + 8) = o1;
}

// ---------------- LayerNorm (fp32 in, bf16 out), one block per row ----------------
__global__ __launch_bounds__(256) void ln_kernel(const float* __restrict__ x,
                                                 const float* __restrict__ g,
                                                 const float* __restrict__ b,
                                                 unsigned short* __restrict__ out) {
  const int row = blockIdx.x, tid = threadIdx.x;
  const float4 v = *(const float4*)(x + (size_t)row * Ee + tid * 4);
  float s = v.x + v.y + v.z + v.w;
  float ss = v.x * v.x + v.y * v.y + v.z * v.z + v.w * v.w;
#pragma unroll
  for (int off = 32; off; off >>= 1) { s += __shfl_down(s, off); ss += __shfl_down(ss, off); }
  __shared__ float red[16];
  const int w = tid >> 6, l = tid & 63;
  if (l == 0) { red[w] = s; red[8 + w] = ss; }
  __syncthreads();
  s = red[0] + red[1] + red[2] + red[3];
  ss = red[8] + red[9] + red[10] + red[11];
  const float mean = s * (1.f / Ee);
  const float rstd = rsqrtf(ss * (1.f / Ee) - mean * mean + EPSv);
  const float4 gv = *(const float4*)(g + tid * 4);
  const float4 bv = *(const float4*)(b + tid * 4);
  sv4 o;
  o[0] = (short)f2b((v.x - mean) * rstd * gv.x + bv.x);
  o[1] = (short)f2b((v.y - mean) * rstd * gv.y + bv.y);
  o[2] = (short)f2b((v.z - mean) * rstd * gv.z + bv.z);
  o[3] = (short)f2b((v.w - mean) * rstd * gv.w + bv.w);
  *(sv4*)(out + (size_t)row * Ee + tid * 4) = o;
}

// ---------------- bf16 GEMM: C[n,m] = sum_k A[n,k]*B[m,k] variants ----------------
// 128xBN tile, BK=32, 4 waves (2x2). GEGLU=1 (block-16 interleaved W1): even/odd
// 16-col fragments are a/gate for the SAME output cols -> lane-local epilogue,
// f[r][ocol] = (a+b1a) * gelu_tanh(g+b1g), bf16 out stride M/2. No shfl, no branch.
template <int OUTF32, int HASBIAS, int BN, int GEGLU>
__global__ __launch_bounds__(256) void gemm_bt(const unsigned short* __restrict__ A,
                                               const unsigned short* __restrict__ Bw,
                                               void* __restrict__ Cout,
                                               const float* __restrict__ bias,
                                               const float* __restrict__ res,
                                               int M, int K) {
  constexpr int NI = BN / 32;  // per-wave n-frags (wave covers BN/2 cols)
  __shared__ unsigned short lA[128 * 32];
  __shared__ unsigned short lB[BN * 32];
  const int tid = threadIdx.x;
  const int l = tid & 63, w = tid >> 6;
  const int wr = w >> 1, wc = w & 1;
  const int rowbase = blockIdx.y * 128, colbase = blockIdx.x * BN;

  const fv4 zero4 = {0.f, 0.f, 0.f, 0.f};
  fv4 acc[4][NI];
#pragma unroll
  for (int i = 0; i < 4; ++i)
#pragma unroll
    for (int j = 0; j < NI; ++j) acc[i][j] = zero4;

  // staging: A = 512 chunks of 8 bf16 (threads do c0,c1); B = BN*4 chunks.
  const int c0 = tid, c1 = tid + 256;
  const unsigned short* Ag0 = A + (size_t)(rowbase + (c0 >> 2)) * K + (c0 & 3) * 8;
  const unsigned short* Ag1 = A + (size_t)(rowbase + (c1 >> 2)) * K + (c1 & 3) * 8;
  const unsigned short* Bg0 = Bw + (size_t)(colbase + (c0 >> 2)) * K + (c0 & 3) * 8;
  const unsigned short* Bg1 = Bw + (size_t)(colbase + ((BN == 128 ? c1 : c0) >> 2)) * K + (c0 & 3) * 8;

  const int nk = K >> 5;
  const int kc = (l >> 4) * 8;
  for (int kt = 0; kt < nk; ++kt) {
    __syncthreads();
    load_lds16(Ag0, lA + c0 * 8);
    load_lds16(Ag1, lA + c1 * 8);
    load_lds16(Bg0, lB + c0 * 8);
    if (BN == 128) load_lds16(Bg1, lB + c1 * 8);
    Ag0 += 32; Ag1 += 32; Bg0 += 32; Bg1 += 32;
    __syncthreads();
    sv8 af[4], bfr[NI];
#pragma unroll
    for (int i = 0; i < 4; ++i)
      af[i] = *(const sv8*)(lA + (wr * 64 + i * 16 + (l & 15)) * 32 + kc);
#pragma unroll
    for (int i = 0; i < NI; ++i)
      bfr[i] = *(const sv8*)(lB + (wc * (BN / 2) + i * 16 + (l & 15)) * 32 + kc);
#pragma unroll
    for (int mi = 0; mi < 4; ++mi)
#pragma unroll
      for (int ni = 0; ni < NI; ++ni)
        acc[mi][ni] = __builtin_amdgcn_mfma_f32_16x16x32_bf16(af[mi], bfr[ni], acc[mi][ni], 0, 0, 0);
  }

  // C/D layout: col = lane&15, row = (lane>>4)*4 + j   [measured m89/m91]
  const int r0 = rowbase + wr * 64 + ((l >> 4) * 4);
  const int ccol = colbase + wc * (BN / 2) + (l & 15);
#pragma unroll
  for (int mi = 0; mi < 4; ++mi) {
#pragma unroll
    for (int j = 0; j < 4; ++j) {
      const size_t r = (size_t)(r0 + mi * 16 + j);
      if (GEGLU) {
#pragma unroll
        for (int p = 0; p < NI / 2; ++p) {
          const int ca = ccol + p * 32;                      // even fragment (a); bit4 == 0
          const int ocol = ((ca >> 5) << 4) | (ca & 15);     // original column
          const float av = acc[mi][2 * p][j] + bias[ocol];
          const float gv = acc[mi][2 * p + 1][j] + bias[ocol + (M >> 1)];
          // tanh-approx gelu: 0.5*g*(1+tanh(0.79788456*(g+0.044715 g^3)))
          const float y = 0.7978845608028654f * (gv + 0.044715f * gv * gv * gv);
          const float e = exp2f(2.8853900817779268f * y);    // exp(2y)
          const float gel = gv * (1.f - 1.f / (e + 1.f));    // == 0.5*g*(1+tanh(y))
          ((unsigned short*)Cout)[r * (size_t)(M >> 1) + ocol] = f2b(av * gel);
        }
      } else {
#pragma unroll
        for (int ni = 0; ni < NI; ++ni) {
          const int c = ccol + ni * 16;
          float vv = acc[mi][ni][j];
          if (HASBIAS) vv += bias[c];
          if (OUTF32) {
            ((float*)Cout)[r * M + c] = res[r * M + c] + vv;
          } else {
            ((unsigned short*)Cout)[r * M + c] = f2b(vv);
          }
        }
      }
    }
  }
}

// ---------------- flash attention: 1 block = (b, h, 64 q-rows), 4 waves x 16 rows ---
// K AND V both staged via global_load_lds with pre-swizzled source (V from the
// pre-transposed vT[b][h][d][t] buffer) -> no reg-staging, ONE barrier per iter.
// Softmax: exp2 domain (scale folded into Wq), group max, deferred denominator.
// XCD-bijective swizzle: K/V working set resident in one XCD's L2.
__global__ __launch_bounds__(256) void attn_kernel(const unsigned short* __restrict__ Q,
                                                   const unsigned short* __restrict__ Kb,
                                                   const unsigned short* __restrict__ vT,
                                                   unsigned short* __restrict__ O,
                                                   int ld) {
  const int bidl = ((blockIdx.x & 7) << 7) + (blockIdx.x >> 3);  // 1024 = 8 XCD x 128
  const int bh = bidl >> 5;
  const int b = bh / Hh, h = bh % Hh;
  const int q0 = (bidl & 31) * 64;
  const int tid = threadIdx.x, l = tid & 63, w = tid >> 6;
  const size_t base = (size_t)b * Tt * ld + (size_t)h * Dd;
  const size_t baseO = (size_t)b * Tt * Ee + (size_t)h * Dd;
  const unsigned short* vTb = vT + (size_t)bh * 64 * Tt;  // [64 d][2048 t]

  __shared__ unsigned short Kt[2][64 * 64];
  __shared__ unsigned short Vt[2][64 * 64];
  __shared__ unsigned short Pt[4][16 * 64];

  // Q fragments held in registers: A-layout row = l&15, k-chunk = (l>>4)*8
  sv8 qf0, qf1;
  {
    const unsigned short* qp = Q + base + (size_t)(q0 + w * 16 + (l & 15)) * ld + (l >> 4) * 8;
    qf0 = *(const sv8*)qp;
    qf1 = *(const sv8*)(qp + 32);
  }

  const fv4 zero4 = {0.f, 0.f, 0.f, 0.f};
  fv4 acc_o[4];
#pragma unroll
  for (int i = 0; i < 4; ++i) acc_o[i] = zero4;
  float Mx = -INFINITY;
  float Lp[4];
#pragma unroll
  for (int j = 0; j < 4; ++j) Lp[j] = 0.f;

  const int c0 = tid, c1 = tid + 256;
  const int r0c = c0 >> 3, xc0 = c0 & 7;   // chunk -> (row, chunk-in-row)
  const int r1c = c1 >> 3, xc1 = c1 & 7;   // xc1 == xc0

  // ---- prologue: stage tile 0 (K rows = tokens; V rows = d from vT) ----
  load_lds16(Kb + base + (size_t)(r0c)*ld + (xc0 ^ (r0c & 7)) * 8, Kt[0] + c0 * 8);
  load_lds16(Kb + base + (size_t)(r1c)*ld + (xc1 ^ (r1c & 7)) * 8, Kt[0] + c1 * 8);
  load_lds16(vTb + (size_t)(r0c)*Tt + (xc0 ^ (r0c & 7)) * 8, Vt[0] + c0 * 8);
  load_lds16(vTb + (size_t)(r1c)*Tt + (xc1 ^ (r1c & 7)) * 8, Vt[0] + c1 * 8);
  __syncthreads();

  int cur = 0;
  for (int kt = 0; kt < Tt / 64; ++kt) {
    const int nx = cur ^ 1;
    // ---- prefetch tile kt+1 (async; drained by the end-of-iter barrier) ----
    if (kt + 1 < Tt / 64) {
      load_lds16(Kb + base + (size_t)((kt + 1) * 64 + r0c) * ld + (xc0 ^ (r0c & 7)) * 8, Kt[nx] + c0 * 8);
      load_lds16(Kb + base + (size_t)((kt + 1) * 64 + r1c) * ld + (xc1 ^ (r1c & 7)) * 8, Kt[nx] + c1 * 8);
      load_lds16(vTb + (size_t)(r0c)*Tt + (kt + 1) * 64 + (xc0 ^ (r0c & 7)) * 8, Vt[nx] + c0 * 8);
      load_lds16(vTb + (size_t)(r1c)*Tt + (kt + 1) * 64 + (xc1 ^ (r1c & 7)) * 8, Vt[nx] + c1 * 8);
    }

    // --- S = Q K^T (per wave: 16 q-rows x 64 k-cols) from Kt[cur]; pre-scaled ---
    fv4 s[4];
    __builtin_amdgcn_s_setprio(1);
#pragma unroll
    for (int ks = 0; ks < 4; ++ks) {
      const int row = ks * 16 + (l & 15);
      const sv8 kf0 = *(const sv8*)(Kt[cur] + row * 64 + (((l >> 4) ^ (row & 7)) * 8));
      const sv8 kf1 = *(const sv8*)(Kt[cur] + row * 64 + (((4 + (l >> 4)) ^ (row & 7)) * 8));
      fv4 t = zero4;
      t = __builtin_amdgcn_mfma_f32_16x16x32_bf16(qf0, kf0, t, 0, 0, 0);
      t = __builtin_amdgcn_mfma_f32_16x16x32_bf16(qf1, kf1, t, 0, 0, 0);
      s[ks] = t;
    }
    __builtin_amdgcn_s_setprio(0);

    // --- lane-local overflow check ---
    float m01 = fmaxf(fmaxf(s[0][0], s[0][1]), fmaxf(s[0][2], s[0][3]));
    float m1 = fmaxf(fmaxf(s[1][0], s[1][1]), fmaxf(s[1][2], s[1][3]));
    float m2 = fmaxf(fmaxf(s[2][0], s[2][1]), fmaxf(s[2][2], s[2][3]));
    float m3 = fmaxf(fmaxf(s[3][0], s[3][1]), fmaxf(s[3][2], s[3][3]));
    float tm = fmaxf(fmaxf(m01, m1), fmaxf(m2, m3));
    if (__any(tm > Mx + 11.5f)) {
      // group max -> rescale (rare; always fires on tile 0 where Mx = -inf)
      float mt = tm;
#pragma unroll
      for (int off = 1; off < 16; off <<= 1) mt = fmaxf(mt, __shfl_xor(mt, off, 16));
      const float mnew = fmaxf(Mx, mt);
      const float alpha = exp2f(Mx - mnew);  // tile 0: exp2(-inf) = 0
      Mx = mnew;
#pragma unroll
      for (int j = 0; j < 4; ++j) {
        Lp[j] *= alpha;
#pragma unroll
        for (int dsb = 0; dsb < 4; ++dsb) acc_o[dsb][j] *= alpha;
      }
    }
    // --- p = exp2(s - Mx); per-lane partial sums; store P (trunc bf16) ---
#pragma unroll
    for (int ks = 0; ks < 4; ++ks)
#pragma unroll
      for (int j = 0; j < 4; ++j) {
        const float p = exp2f(s[ks][j] - Mx);
        s[ks][j] = p;
        Lp[j] += p;
      }
#pragma unroll
    for (int ks = 0; ks < 4; ++ks)
#pragma unroll
      for (int j = 0; j < 4; ++j) {
        const int q = (l >> 4) * 4 + j, k = ks * 16 + (l & 15);
        Pt[w][q * 64 + ((((k >> 3) ^ (q & 7)) & 7) * 8) + (k & 7)] = f2b_rtz(s[ks][j]);
      }
    asm volatile("s_waitcnt lgkmcnt(0)" ::: "memory");

    // --- O += P V : b128 reads from swizzled Pt / Vt[cur] (d-major rows) ---
    __builtin_amdgcn_s_setprio(1);
#pragma unroll
    for (int kcn = 0; kcn < 2; ++kcn) {
      const int qr = l & 15;
      const sv8 pf = *(const sv8*)(&Pt[w][qr * 64 + (((kcn * 4 + (l >> 4)) ^ (qr & 7)) * 8)]);
#pragma unroll
      for (int dsb = 0; dsb < 4; ++dsb) {
        const int row = dsb * 16 + (l & 15);
        const int chunk = kcn * 4 + (l >> 4);
        const sv8 vf = *(const sv8*)(Vt[cur] + row * 64 + ((chunk ^ (row & 7)) * 8));
        acc_o[dsb] = __builtin_amdgcn_mfma_f32_16x16x32_bf16(pf, vf, acc_o[dsb], 0, 0, 0);
      }
    }
    __builtin_amdgcn_s_setprio(0);

    __syncthreads();  // drains prefetch vmcnt; all waves done reading [cur]
    cur = nx;
  }

  // ---- deferred denominator: one 16-lane reduce per q-row, then write O ----
#pragma unroll
  for (int j = 0; j < 4; ++j) {
    float t = Lp[j];
#pragma unroll
    for (int off = 1; off < 16; off <<= 1) t += __shfl_xor(t, off, 16);
    const float inv = 1.f / t;
    unsigned short* op = O + baseO + (size_t)(q0 + w * 16 + (l >> 4) * 4 + j) * Ee;
#pragma unroll
    for (int dsb = 0; dsb < 4; ++dsb)
      op[dsb * 16 + (l & 15)] = f2b(acc_o[dsb][j] * inv);
  }
}

extern "C" void kernel_launch(void* const* d_in, const int* in_sizes, int n_in,
                              void* d_out, int out_size, void* d_ws, size_t ws_size,
                              hipStream_t stream) {
  (void)in_sizes; (void)n_in; (void)out_size; (void)ws_size;
  const float* src  = (const float*)d_in[0];
  const float* Wq   = (const float*)d_in[1];
  const float* Wk   = (const float*)d_in[2];
  const float* Wv   = (const float*)d_in[3];
  const float* Wo   = (const float*)d_in[4];
  const float* W1   = (const float*)d_in[5];
  const float* b1   = (const float*)d_in[6];
  const float* W2   = (const float*)d_in[7];
  const float* b2   = (const float*)d_in[8];
  const float* ln1w = (const float*)d_in[9];
  const float* ln1b = (const float*)d_in[10];
  const float* ln2w = (const float*)d_in[11];
  const float* ln2b = (const float*)d_in[12];
  float* out = (float*)d_out;

  char* ws = (char*)d_ws;
  size_t off = 0;
  auto alloc = [&](size_t bytes) { char* p = ws + off; off += bytes; return p; };
  unsigned short* wqkv = (unsigned short*)alloc((size_t)3 * Ee * Ee * 2);  // Wq|Wk|Wv rows
  unsigned short* wo16 = (unsigned short*)alloc((size_t)Ee * Ee * 2);
  unsigned short* w116 = (unsigned short*)alloc((size_t)2 * FFd * Ee * 2); // interleaved
  unsigned short* w216 = (unsigned short*)alloc((size_t)Ee * FFd * 2);
  unsigned short* h16  = (unsigned short*)alloc((size_t)NN * Ee * 2);
  unsigned short* qkv  = (unsigned short*)alloc((size_t)NN * 3 * Ee * 2);  // [row][3E]
  unsigned short* a16  = (unsigned short*)alloc((size_t)NN * Ee * 2);
  float* xbuf          = (float*)alloc((size_t)NN * Ee * 4);
  unsigned short* vT   = (unsigned short*)alloc((size_t)NN * Ee * 2);      // [b][h][64][T]
  unsigned short* f16  = qkv;  // reuse qkv+a16 region (32 MB) after attention done

  const float s2 = 0.125f * 1.4426950408889634f;  // 1/sqrt(D) * log2(e), folded into Wq

  dim3 blk(256);
  cvt_kernel<<<dim3(Ee * Ee / 1024), blk, 0, stream>>>(Wq, wqkv, Ee * Ee, s2);
  cvt_kernel<<<dim3(Ee * Ee / 1024), blk, 0, stream>>>(Wk, wqkv + Ee * Ee, Ee * Ee, 1.0f);
  cvt_kernel<<<dim3(Ee * Ee / 1024), blk, 0, stream>>>(Wv, wqkv + 2 * Ee * Ee, Ee * Ee, 1.0f);
  cvt_kernel<<<dim3(Ee * Ee / 1024), blk, 0, stream>>>(Wo, wo16, Ee * Ee, 1.0f);
  cvt_w1_kernel<<<dim3(2 * FFd * Ee / 1024), blk, 0, stream>>>(W1, w116);
  cvt_kernel<<<dim3(Ee * FFd / 1024), blk, 0, stream>>>(W2, w216, Ee * FFd, 1.0f);

  ln_kernel<<<dim3(NN), blk, 0, stream>>>(src, ln1w, ln1b, h16);

  // fused QKV projection: [4096,1024] x [3072,1024]^T -> [4096,3072]
  gemm_bt<0, 0, 128, 0><<<dim3(3 * Ee / 128, NN / 128), blk, 0, stream>>>(h16, wqkv, qkv, nullptr, nullptr, 3 * Ee, Ee);

  // V transpose: [t][h*64+d] -> vT[b][h][d][t]
  vt_kernel<<<dim3(Tt / 64, Bb * Hh), blk, 0, stream>>>(qkv, vT);

  attn_kernel<<<dim3(1024), blk, 0, stream>>>(qkv, qkv + Ee, vT, a16, 3 * Ee);

  // Wo projection + residual (BN=64: 512 blocks, 2/CU)
  gemm_bt<1, 0, 64, 0><<<dim3(Ee / 64, NN / 128), blk, 0, stream>>>(a16, wo16, xbuf, nullptr, src, Ee, Ee);

  ln_kernel<<<dim3(NN), blk, 0, stream>>>(xbuf, ln2w, ln2b, h16);

  // W1 (block-16 interleaved) + lane-local GEGLU epilogue -> f16 [4096][4096]
  gemm_bt<0, 0, 128, 1><<<dim3(2 * FFd / 128, NN / 128), blk, 0, stream>>>(h16, w116, f16, b1, nullptr, 2 * FFd, Ee);

  // W2 projection + bias + residual (BN=64: 512 blocks, 2/CU)
  gemm_bt<1, 1, 64, 0><<<dim3(Ee / 64, NN / 128), blk, 0, stream>>>(f16, w216, out, b2, xbuf, Ee, FFd);
}

// Round 9
// 321.294 us; speedup vs baseline: 1.6062x; 1.1273x over previous
//
#include <hip/hip_runtime.h>
#include <stdint.h>
#include <math.h>

#define DEVI __device__ __forceinline__

typedef __attribute__((ext_vector_type(8))) short sv8;
typedef __attribute__((ext_vector_type(4))) short sv4;
typedef __attribute__((ext_vector_type(4))) float fv4;

typedef __attribute__((address_space(1))) void av1_t;
typedef __attribute__((address_space(3))) void av3_t;

constexpr int Bb = 2, Tt = 2048, Ee = 1024, Hh = 16, Dd = 64, FFd = 4096;
constexpr int NN = Bb * Tt;  // 4096 token rows
constexpr float EPSv = 1e-5f;

DEVI float b2f(unsigned short s) {
  union { unsigned u; float f; } v; v.u = ((unsigned)s) << 16; return v.f;
}
DEVI unsigned short f2b(float f) {
  union { float f; unsigned u; } v; v.f = f;
  return (unsigned short)((v.u + 0x7FFFu + ((v.u >> 16) & 1u)) >> 16);
}
DEVI unsigned short f2b_rtz(float f) {  // truncation: 1 VALU op (softmax P only)
  union { float f; unsigned u; } v; v.f = f;
  return (unsigned short)(v.u >> 16);
}

// global -> LDS direct (16B per lane). LDS dest must be wave-uniform base + lane*16.
DEVI void load_lds16(const void* g, void* s) {
  __builtin_amdgcn_global_load_lds((av1_t*)(unsigned long long)g,
                                   (av3_t*)(unsigned)(unsigned long long)s,
                                   16, 0, 0);
}

// ---------------- fp32 -> bf16 convert (optional scale fold) ----------------
__global__ __launch_bounds__(256) void cvt_kernel(const float* __restrict__ in,
                                                  unsigned short* __restrict__ out, int n,
                                                  float scale) {
  int i = (blockIdx.x * 256 + threadIdx.x) * 4;
  if (i >= n) return;
  float4 v = *(const float4*)(in + i);
  sv4 o;
  o[0] = (short)f2b(v.x * scale); o[1] = (short)f2b(v.y * scale);
  o[2] = (short)f2b(v.z * scale); o[3] = (short)f2b(v.w * scale);
  *(sv4*)(out + i) = o;
}

// -------- W1 convert, block-16 interleave: a-row r -> 32*(r>>4)+(r&15);
//          gate-row (r-FFd) -> 32*((r-FFd)>>4)+16+(r&15). Even 16-col fragment = a,
//          odd = gate, SAME output cols -> lane-local GEGLU in the GEMM epilogue.
__global__ __launch_bounds__(256) void cvt_w1_kernel(const float* __restrict__ in,
                                                     unsigned short* __restrict__ out) {
  int i = (blockIdx.x * 256 + threadIdx.x) * 4;  // flat over 2*FFd*Ee
  const int r = i >> 10, c = i & 1023;
  const int rp = (r < FFd) ? ((r >> 4) * 32 + (r & 15))
                           : (((r - FFd) >> 4) * 32 + 16 + (r & 15));
  float4 v = *(const float4*)(in + i);
  sv4 o;
  o[0] = (short)f2b(v.x); o[1] = (short)f2b(v.y);
  o[2] = (short)f2b(v.z); o[3] = (short)f2b(v.w);
  *(sv4*)(out + (size_t)rp * Ee + c) = o;
}

// ---------------- V transpose: qkv V-slice [t][h*64+d] -> vT[b][h][d][t] ----------
__global__ __launch_bounds__(256) void vt_kernel(const unsigned short* __restrict__ qkv,
                                                 unsigned short* __restrict__ vT) {
  const int bh = blockIdx.y;               // b*16+h
  const int b = bh >> 4, h = bh & 15;
  const int tt = blockIdx.x * 64;          // token tile
  const int tid = threadIdx.x;
  __shared__ unsigned short tile[64][65];  // +1 pad
  const int tr = tid >> 2, tc4 = (tid & 3) * 16;
  const unsigned short* src = qkv + (size_t)(b * Tt + tt + tr) * (3 * Ee) + 2 * Ee + h * 64 + tc4;
  const sv8 a0 = *(const sv8*)src;
  const sv8 a1 = *(const sv8*)(src + 8);
#pragma unroll
  for (int j = 0; j < 8; ++j) { tile[tr][tc4 + j] = a0[j]; tile[tr][tc4 + 8 + j] = a1[j]; }
  __syncthreads();
  unsigned short* dst = vT + ((size_t)bh * 64 + tr) * Tt + tt + tc4;
  sv8 o0, o1;
#pragma unroll
  for (int j = 0; j < 8; ++j) { o0[j] = (short)tile[tc4 + j][tr]; o1[j] = (short)tile[tc4 + 8 + j][tr]; }
  *(sv8*)dst = o0;
  *(sv8*)(dst + 8) = o1;
}

// ---------------- LayerNorm (fp32 in, bf16 out), one block per row ----------------
__global__ __launch_bounds__(256) void ln_kernel(const float* __restrict__ x,
                                                 const float* __restrict__ g,
                                                 const float* __restrict__ b,
                                                 unsigned short* __restrict__ out) {
  const int row = blockIdx.x, tid = threadIdx.x;
  const float4 v = *(const float4*)(x + (size_t)row * Ee + tid * 4);
  float s = v.x + v.y + v.z + v.w;
  float ss = v.x * v.x + v.y * v.y + v.z * v.z + v.w * v.w;
#pragma unroll
  for (int off = 32; off; off >>= 1) { s += __shfl_down(s, off); ss += __shfl_down(ss, off); }
  __shared__ float red[16];
  const int w = tid >> 6, l = tid & 63;
  if (l == 0) { red[w] = s; red[8 + w] = ss; }
  __syncthreads();
  s = red[0] + red[1] + red[2] + red[3];
  ss = red[8] + red[9] + red[10] + red[11];
  const float mean = s * (1.f / Ee);
  const float rstd = rsqrtf(ss * (1.f / Ee) - mean * mean + EPSv);
  const float4 gv = *(const float4*)(g + tid * 4);
  const float4 bv = *(const float4*)(b + tid * 4);
  sv4 o;
  o[0] = (short)f2b((v.x - mean) * rstd * gv.x + bv.x);
  o[1] = (short)f2b((v.y - mean) * rstd * gv.y + bv.y);
  o[2] = (short)f2b((v.z - mean) * rstd * gv.z + bv.z);
  o[3] = (short)f2b((v.w - mean) * rstd * gv.w + bv.w);
  *(sv4*)(out + (size_t)row * Ee + tid * 4) = o;
}

// ---------------- bf16 GEMM: C[n,m] = sum_k A[n,k]*B[m,k] variants ----------------
// 128xBN tile, BK=32, 4 waves (2x2). DOUBLE-BUFFERED LDS, prefetch-at-top, ONE
// barrier per K-step (HBM/L2 staging latency hides under ds_read+MFMA of the
// current tile; end-of-iter barrier's vmcnt drain finds loads already landed).
// GEGLU=1 (block-16 interleaved W1): even/odd 16-col fragments are a/gate for the
// SAME output cols -> lane-local epilogue, bf16 out stride M/2.
template <int OUTF32, int HASBIAS, int BN, int GEGLU>
__global__ __launch_bounds__(256) void gemm_bt(const unsigned short* __restrict__ A,
                                               const unsigned short* __restrict__ Bw,
                                               void* __restrict__ Cout,
                                               const float* __restrict__ bias,
                                               const float* __restrict__ res,
                                               int M, int K) {
  constexpr int NI = BN / 32;  // per-wave n-frags (wave covers BN/2 cols)
  __shared__ unsigned short lA[2][128 * 32];
  __shared__ unsigned short lB[2][BN * 32];
  const int tid = threadIdx.x;
  const int l = tid & 63, w = tid >> 6;
  const int wr = w >> 1, wc = w & 1;
  const int rowbase = blockIdx.y * 128, colbase = blockIdx.x * BN;

  const fv4 zero4 = {0.f, 0.f, 0.f, 0.f};
  fv4 acc[4][NI];
#pragma unroll
  for (int i = 0; i < 4; ++i)
#pragma unroll
    for (int j = 0; j < NI; ++j) acc[i][j] = zero4;

  // staging: A = 512 chunks of 8 bf16 (threads do c0,c1); B = BN*4 chunks.
  const int c0 = tid, c1 = tid + 256;
  const unsigned short* Ag0 = A + (size_t)(rowbase + (c0 >> 2)) * K + (c0 & 3) * 8;
  const unsigned short* Ag1 = A + (size_t)(rowbase + (c1 >> 2)) * K + (c1 & 3) * 8;
  const unsigned short* Bg0 = Bw + (size_t)(colbase + (c0 >> 2)) * K + (c0 & 3) * 8;
  const unsigned short* Bg1 = Bw + (size_t)(colbase + ((BN == 128 ? c1 : c0) >> 2)) * K + (c0 & 3) * 8;

  const int nk = K >> 5;
  const int kc = (l >> 4) * 8;

  // ---- prologue: stage tile 0 into buffer 0 ----
  load_lds16(Ag0, lA[0] + c0 * 8);
  load_lds16(Ag1, lA[0] + c1 * 8);
  load_lds16(Bg0, lB[0] + c0 * 8);
  if (BN == 128) load_lds16(Bg1, lB[0] + c1 * 8);
  Ag0 += 32; Ag1 += 32; Bg0 += 32; Bg1 += 32;
  __syncthreads();

  int cur = 0;
  for (int kt = 0; kt < nk; ++kt) {
    const int nx = cur ^ 1;
    // ---- prefetch tile kt+1 (async; drained by end-of-iter barrier) ----
    if (kt + 1 < nk) {
      load_lds16(Ag0, lA[nx] + c0 * 8);
      load_lds16(Ag1, lA[nx] + c1 * 8);
      load_lds16(Bg0, lB[nx] + c0 * 8);
      if (BN == 128) load_lds16(Bg1, lB[nx] + c1 * 8);
      Ag0 += 32; Ag1 += 32; Bg0 += 32; Bg1 += 32;
    }
    sv8 af[4], bfr[NI];
#pragma unroll
    for (int i = 0; i < 4; ++i)
      af[i] = *(const sv8*)(lA[cur] + (wr * 64 + i * 16 + (l & 15)) * 32 + kc);
#pragma unroll
    for (int i = 0; i < NI; ++i)
      bfr[i] = *(const sv8*)(lB[cur] + (wc * (BN / 2) + i * 16 + (l & 15)) * 32 + kc);
    __builtin_amdgcn_s_setprio(1);
#pragma unroll
    for (int mi = 0; mi < 4; ++mi)
#pragma unroll
      for (int ni = 0; ni < NI; ++ni)
        acc[mi][ni] = __builtin_amdgcn_mfma_f32_16x16x32_bf16(af[mi], bfr[ni], acc[mi][ni], 0, 0, 0);
    __builtin_amdgcn_s_setprio(0);
    __syncthreads();  // drains prefetch vmcnt; all waves done reading buf[cur]
    cur = nx;
  }

  // C/D layout: col = lane&15, row = (lane>>4)*4 + j   [measured m89/m91]
  const int r0 = rowbase + wr * 64 + ((l >> 4) * 4);
  const int ccol = colbase + wc * (BN / 2) + (l & 15);
#pragma unroll
  for (int mi = 0; mi < 4; ++mi) {
#pragma unroll
    for (int j = 0; j < 4; ++j) {
      const size_t r = (size_t)(r0 + mi * 16 + j);
      if (GEGLU) {
#pragma unroll
        for (int p = 0; p < NI / 2; ++p) {
          const int ca = ccol + p * 32;                      // even fragment (a); bit4 == 0
          const int ocol = ((ca >> 5) << 4) | (ca & 15);     // original column
          const float av = acc[mi][2 * p][j] + bias[ocol];
          const float gv = acc[mi][2 * p + 1][j] + bias[ocol + (M >> 1)];
          // tanh-approx gelu: 0.5*g*(1+tanh(0.79788456*(g+0.044715 g^3)))
          const float y = 0.7978845608028654f * (gv + 0.044715f * gv * gv * gv);
          const float e = exp2f(2.8853900817779268f * y);    // exp(2y)
          const float gel = gv * (1.f - 1.f / (e + 1.f));    // == 0.5*g*(1+tanh(y))
          ((unsigned short*)Cout)[r * (size_t)(M >> 1) + ocol] = f2b(av * gel);
        }
      } else {
#pragma unroll
        for (int ni = 0; ni < NI; ++ni) {
          const int c = ccol + ni * 16;
          float vv = acc[mi][ni][j];
          if (HASBIAS) vv += bias[c];
          if (OUTF32) {
            ((float*)Cout)[r * M + c] = res[r * M + c] + vv;
          } else {
            ((unsigned short*)Cout)[r * M + c] = f2b(vv);
          }
        }
      }
    }
  }
}

// ---------------- flash attention: 1 block = (b, h, 64 q-rows), 4 waves x 16 rows ---
// K AND V both staged via global_load_lds with pre-swizzled source (V from the
// pre-transposed vT[b][h][d][t] buffer) -> no reg-staging, ONE barrier per iter.
// Softmax: exp2 domain (scale folded into Wq), group max, deferred denominator.
// XCD-bijective swizzle: K/V working set resident in one XCD's L2.
__global__ __launch_bounds__(256) void attn_kernel(const unsigned short* __restrict__ Q,
                                                   const unsigned short* __restrict__ Kb,
                                                   const unsigned short* __restrict__ vT,
                                                   unsigned short* __restrict__ O,
                                                   int ld) {
  const int bidl = ((blockIdx.x & 7) << 7) + (blockIdx.x >> 3);  // 1024 = 8 XCD x 128
  const int bh = bidl >> 5;
  const int b = bh / Hh, h = bh % Hh;
  const int q0 = (bidl & 31) * 64;
  const int tid = threadIdx.x, l = tid & 63, w = tid >> 6;
  const size_t base = (size_t)b * Tt * ld + (size_t)h * Dd;
  const size_t baseO = (size_t)b * Tt * Ee + (size_t)h * Dd;
  const unsigned short* vTb = vT + (size_t)bh * 64 * Tt;  // [64 d][2048 t]

  __shared__ unsigned short Kt[2][64 * 64];
  __shared__ unsigned short Vt[2][64 * 64];
  __shared__ unsigned short Pt[4][16 * 64];

  // Q fragments held in registers: A-layout row = l&15, k-chunk = (l>>4)*8
  sv8 qf0, qf1;
  {
    const unsigned short* qp = Q + base + (size_t)(q0 + w * 16 + (l & 15)) * ld + (l >> 4) * 8;
    qf0 = *(const sv8*)qp;
    qf1 = *(const sv8*)(qp + 32);
  }

  const fv4 zero4 = {0.f, 0.f, 0.f, 0.f};
  fv4 acc_o[4];
#pragma unroll
  for (int i = 0; i < 4; ++i) acc_o[i] = zero4;
  float Mx = -INFINITY;
  float Lp[4];
#pragma unroll
  for (int j = 0; j < 4; ++j) Lp[j] = 0.f;

  const int c0 = tid, c1 = tid + 256;
  const int r0c = c0 >> 3, xc0 = c0 & 7;   // chunk -> (row, chunk-in-row)
  const int r1c = c1 >> 3, xc1 = c1 & 7;   // xc1 == xc0

  // ---- prologue: stage tile 0 (K rows = tokens; V rows = d from vT) ----
  load_lds16(Kb + base + (size_t)(r0c)*ld + (xc0 ^ (r0c & 7)) * 8, Kt[0] + c0 * 8);
  load_lds16(Kb + base + (size_t)(r1c)*ld + (xc1 ^ (r1c & 7)) * 8, Kt[0] + c1 * 8);
  load_lds16(vTb + (size_t)(r0c)*Tt + (xc0 ^ (r0c & 7)) * 8, Vt[0] + c0 * 8);
  load_lds16(vTb + (size_t)(r1c)*Tt + (xc1 ^ (r1c & 7)) * 8, Vt[0] + c1 * 8);
  __syncthreads();

  int cur = 0;
  for (int kt = 0; kt < Tt / 64; ++kt) {
    const int nx = cur ^ 1;
    // ---- prefetch tile kt+1 (async; drained by the end-of-iter barrier) ----
    if (kt + 1 < Tt / 64) {
      load_lds16(Kb + base + (size_t)((kt + 1) * 64 + r0c) * ld + (xc0 ^ (r0c & 7)) * 8, Kt[nx] + c0 * 8);
      load_lds16(Kb + base + (size_t)((kt + 1) * 64 + r1c) * ld + (xc1 ^ (r1c & 7)) * 8, Kt[nx] + c1 * 8);
      load_lds16(vTb + (size_t)(r0c)*Tt + (kt + 1) * 64 + (xc0 ^ (r0c & 7)) * 8, Vt[nx] + c0 * 8);
      load_lds16(vTb + (size_t)(r1c)*Tt + (kt + 1) * 64 + (xc1 ^ (r1c & 7)) * 8, Vt[nx] + c1 * 8);
    }

    // --- S = Q K^T (per wave: 16 q-rows x 64 k-cols) from Kt[cur]; pre-scaled ---
    fv4 s[4];
    __builtin_amdgcn_s_setprio(1);
#pragma unroll
    for (int ks = 0; ks < 4; ++ks) {
      const int row = ks * 16 + (l & 15);
      const sv8 kf0 = *(const sv8*)(Kt[cur] + row * 64 + (((l >> 4) ^ (row & 7)) * 8));
      const sv8 kf1 = *(const sv8*)(Kt[cur] + row * 64 + (((4 + (l >> 4)) ^ (row & 7)) * 8));
      fv4 t = zero4;
      t = __builtin_amdgcn_mfma_f32_16x16x32_bf16(qf0, kf0, t, 0, 0, 0);
      t = __builtin_amdgcn_mfma_f32_16x16x32_bf16(qf1, kf1, t, 0, 0, 0);
      s[ks] = t;
    }
    __builtin_amdgcn_s_setprio(0);

    // --- lane-local overflow check ---
    float m01 = fmaxf(fmaxf(s[0][0], s[0][1]), fmaxf(s[0][2], s[0][3]));
    float m1 = fmaxf(fmaxf(s[1][0], s[1][1]), fmaxf(s[1][2], s[1][3]));
    float m2 = fmaxf(fmaxf(s[2][0], s[2][1]), fmaxf(s[2][2], s[2][3]));
    float m3 = fmaxf(fmaxf(s[3][0], s[3][1]), fmaxf(s[3][2], s[3][3]));
    float tm = fmaxf(fmaxf(m01, m1), fmaxf(m2, m3));
    if (__any(tm > Mx + 11.5f)) {
      // group max -> rescale (rare; always fires on tile 0 where Mx = -inf)
      float mt = tm;
#pragma unroll
      for (int off = 1; off < 16; off <<= 1) mt = fmaxf(mt, __shfl_xor(mt, off, 16));
      const float mnew = fmaxf(Mx, mt);
      const float alpha = exp2f(Mx - mnew);  // tile 0: exp2(-inf) = 0
      Mx = mnew;
#pragma unroll
      for (int j = 0; j < 4; ++j) {
        Lp[j] *= alpha;
#pragma unroll
        for (int dsb = 0; dsb < 4; ++dsb) acc_o[dsb][j] *= alpha;
      }
    }
    // --- p = exp2(s - Mx); per-lane partial sums; store P (trunc bf16) ---
#pragma unroll
    for (int ks = 0; ks < 4; ++ks)
#pragma unroll
      for (int j = 0; j < 4; ++j) {
        const float p = exp2f(s[ks][j] - Mx);
        s[ks][j] = p;
        Lp[j] += p;
      }
#pragma unroll
    for (int ks = 0; ks < 4; ++ks)
#pragma unroll
      for (int j = 0; j < 4; ++j) {
        const int q = (l >> 4) * 4 + j, k = ks * 16 + (l & 15);
        Pt[w][q * 64 + ((((k >> 3) ^ (q & 7)) & 7) * 8) + (k & 7)] = f2b_rtz(s[ks][j]);
      }
    asm volatile("s_waitcnt lgkmcnt(0)" ::: "memory");

    // --- O += P V : b128 reads from swizzled Pt / Vt[cur] (d-major rows) ---
    __builtin_amdgcn_s_setprio(1);
#pragma unroll
    for (int kcn = 0; kcn < 2; ++kcn) {
      const int qr = l & 15;
      const sv8 pf = *(const sv8*)(&Pt[w][qr * 64 + (((kcn * 4 + (l >> 4)) ^ (qr & 7)) * 8)]);
#pragma unroll
      for (int dsb = 0; dsb < 4; ++dsb) {
        const int row = dsb * 16 + (l & 15);
        const int chunk = kcn * 4 + (l >> 4);
        const sv8 vf = *(const sv8*)(Vt[cur] + row * 64 + ((chunk ^ (row & 7)) * 8));
        acc_o[dsb] = __builtin_amdgcn_mfma_f32_16x16x32_bf16(pf, vf, acc_o[dsb], 0, 0, 0);
      }
    }
    __builtin_amdgcn_s_setprio(0);

    __syncthreads();  // drains prefetch vmcnt; all waves done reading [cur]
    cur = nx;
  }

  // ---- deferred denominator: one 16-lane reduce per q-row, then write O ----
#pragma unroll
  for (int j = 0; j < 4; ++j) {
    float t = Lp[j];
#pragma unroll
    for (int off = 1; off < 16; off <<= 1) t += __shfl_xor(t, off, 16);
    const float inv = 1.f / t;
    unsigned short* op = O + baseO + (size_t)(q0 + w * 16 + (l >> 4) * 4 + j) * Ee;
#pragma unroll
    for (int dsb = 0; dsb < 4; ++dsb)
      op[dsb * 16 + (l & 15)] = f2b(acc_o[dsb][j] * inv);
  }
}

extern "C" void kernel_launch(void* const* d_in, const int* in_sizes, int n_in,
                              void* d_out, int out_size, void* d_ws, size_t ws_size,
                              hipStream_t stream) {
  (void)in_sizes; (void)n_in; (void)out_size; (void)ws_size;
  const float* src  = (const float*)d_in[0];
  const float* Wq   = (const float*)d_in[1];
  const float* Wk   = (const float*)d_in[2];
  const float* Wv   = (const float*)d_in[3];
  const float* Wo   = (const float*)d_in[4];
  const float* W1   = (const float*)d_in[5];
  const float* b1   = (const float*)d_in[6];
  const float* W2   = (const float*)d_in[7];
  const float* b2   = (const float*)d_in[8];
  const float* ln1w = (const float*)d_in[9];
  const float* ln1b = (const float*)d_in[10];
  const float* ln2w = (const float*)d_in[11];
  const float* ln2b = (const float*)d_in[12];
  float* out = (float*)d_out;

  char* ws = (char*)d_ws;
  size_t off = 0;
  auto alloc = [&](size_t bytes) { char* p = ws + off; off += bytes; return p; };
  unsigned short* wqkv = (unsigned short*)alloc((size_t)3 * Ee * Ee * 2);  // Wq|Wk|Wv rows
  unsigned short* wo16 = (unsigned short*)alloc((size_t)Ee * Ee * 2);
  unsigned short* w116 = (unsigned short*)alloc((size_t)2 * FFd * Ee * 2); // interleaved
  unsigned short* w216 = (unsigned short*)alloc((size_t)Ee * FFd * 2);
  unsigned short* h16  = (unsigned short*)alloc((size_t)NN * Ee * 2);
  unsigned short* qkv  = (unsigned short*)alloc((size_t)NN * 3 * Ee * 2);  // [row][3E]
  unsigned short* a16  = (unsigned short*)alloc((size_t)NN * Ee * 2);
  float* xbuf          = (float*)alloc((size_t)NN * Ee * 4);
  unsigned short* vT   = (unsigned short*)alloc((size_t)NN * Ee * 2);      // [b][h][64][T]
  unsigned short* f16  = qkv;  // reuse qkv+a16 region (32 MB) after attention done

  const float s2 = 0.125f * 1.4426950408889634f;  // 1/sqrt(D) * log2(e), folded into Wq

  dim3 blk(256);
  cvt_kernel<<<dim3(Ee * Ee / 1024), blk, 0, stream>>>(Wq, wqkv, Ee * Ee, s2);
  cvt_kernel<<<dim3(Ee * Ee / 1024), blk, 0, stream>>>(Wk, wqkv + Ee * Ee, Ee * Ee, 1.0f);
  cvt_kernel<<<dim3(Ee * Ee / 1024), blk, 0, stream>>>(Wv, wqkv + 2 * Ee * Ee, Ee * Ee, 1.0f);
  cvt_kernel<<<dim3(Ee * Ee / 1024), blk, 0, stream>>>(Wo, wo16, Ee * Ee, 1.0f);
  cvt_w1_kernel<<<dim3(2 * FFd * Ee / 1024), blk, 0, stream>>>(W1, w116);
  cvt_kernel<<<dim3(Ee * FFd / 1024), blk, 0, stream>>>(W2, w216, Ee * FFd, 1.0f);

  ln_kernel<<<dim3(NN), blk, 0, stream>>>(src, ln1w, ln1b, h16);

  // fused QKV projection: [4096,1024] x [3072,1024]^T -> [4096,3072]
  gemm_bt<0, 0, 128, 0><<<dim3(3 * Ee / 128, NN / 128), blk, 0, stream>>>(h16, wqkv, qkv, nullptr, nullptr, 3 * Ee, Ee);

  // V transpose: [t][h*64+d] -> vT[b][h][d][t]
  vt_kernel<<<dim3(Tt / 64, Bb * Hh), blk, 0, stream>>>(qkv, vT);

  attn_kernel<<<dim3(1024), blk, 0, stream>>>(qkv, qkv + Ee, vT, a16, 3 * Ee);

  // Wo projection + residual (BN=64: 512 blocks, 2/CU)
  gemm_bt<1, 0, 64, 0><<<dim3(Ee / 64, NN / 128), blk, 0, stream>>>(a16, wo16, xbuf, nullptr, src, Ee, Ee);

  ln_kernel<<<dim3(NN), blk, 0, stream>>>(xbuf, ln2w, ln2b, h16);

  // W1 (block-16 interleaved) + lane-local GEGLU epilogue -> f16 [4096][4096]
  gemm_bt<0, 0, 128, 1><<<dim3(2 * FFd / 128, NN / 128), blk, 0, stream>>>(h16, w116, f16, b1, nullptr, 2 * FFd, Ee);

  // W2 projection + bias + residual (BN=64: 512 blocks, 2/CU)
  gemm_bt<1, 1, 64, 0><<<dim3(Ee / 64, NN / 128), blk, 0, stream>>>(f16, w216, out, b2, xbuf, Ee, FFd);
}

// Round 10
// 320.006 us; speedup vs baseline: 1.6127x; 1.0040x over previous
//
#include <hip/hip_runtime.h>
#include <stdint.h>
#include <math.h>

#define DEVI __device__ __forceinline__

typedef __attribute__((ext_vector_type(8))) short sv8;
typedef __attribute__((ext_vector_type(4))) short sv4;
typedef __attribute__((ext_vector_type(4))) float fv4;

typedef __attribute__((address_space(1))) void av1_t;
typedef __attribute__((address_space(3))) void av3_t;

constexpr int Bb = 2, Tt = 2048, Ee = 1024, Hh = 16, Dd = 64, FFd = 4096;
constexpr int NN = Bb * Tt;  // 4096 token rows
constexpr float EPSv = 1e-5f;

DEVI float b2f(unsigned short s) {
  union { unsigned u; float f; } v; v.u = ((unsigned)s) << 16; return v.f;
}
DEVI unsigned short f2b(float f) {
  union { float f; unsigned u; } v; v.f = f;
  return (unsigned short)((v.u + 0x7FFFu + ((v.u >> 16) & 1u)) >> 16);
}
DEVI unsigned short f2b_rtz(float f) {  // truncation: 1 VALU op (softmax P only)
  union { float f; unsigned u; } v; v.f = f;
  return (unsigned short)(v.u >> 16);
}

// global -> LDS direct (16B per lane). LDS dest must be wave-uniform base + lane*16.
DEVI void load_lds16(const void* g, void* s) {
  __builtin_amdgcn_global_load_lds((av1_t*)(unsigned long long)g,
                                   (av3_t*)(unsigned)(unsigned long long)s,
                                   16, 0, 0);
}

// ---------------- fp32 -> bf16 convert (optional scale fold) ----------------
__global__ __launch_bounds__(256) void cvt_kernel(const float* __restrict__ in,
                                                  unsigned short* __restrict__ out, int n,
                                                  float scale) {
  int i = (blockIdx.x * 256 + threadIdx.x) * 4;
  if (i >= n) return;
  float4 v = *(const float4*)(in + i);
  sv4 o;
  o[0] = (short)f2b(v.x * scale); o[1] = (short)f2b(v.y * scale);
  o[2] = (short)f2b(v.z * scale); o[3] = (short)f2b(v.w * scale);
  *(sv4*)(out + i) = o;
}

// -------- W1 convert, block-16 interleave: a-row r -> 32*(r>>4)+(r&15);
//          gate-row (r-FFd) -> 32*((r-FFd)>>4)+16+(r&15). Even 16-col fragment = a,
//          odd = gate, SAME output cols -> lane-local GEGLU in the GEMM epilogue.
__global__ __launch_bounds__(256) void cvt_w1_kernel(const float* __restrict__ in,
                                                     unsigned short* __restrict__ out) {
  int i = (blockIdx.x * 256 + threadIdx.x) * 4;  // flat over 2*FFd*Ee
  const int r = i >> 10, c = i & 1023;
  const int rp = (r < FFd) ? ((r >> 4) * 32 + (r & 15))
                           : (((r - FFd) >> 4) * 32 + 16 + (r & 15));
  float4 v = *(const float4*)(in + i);
  sv4 o;
  o[0] = (short)f2b(v.x); o[1] = (short)f2b(v.y);
  o[2] = (short)f2b(v.z); o[3] = (short)f2b(v.w);
  *(sv4*)(out + (size_t)rp * Ee + c) = o;
}

// ---------------- V transpose: qkv V-slice [t][h*64+d] -> vT[b][h][d][t] ----------
__global__ __launch_bounds__(256) void vt_kernel(const unsigned short* __restrict__ qkv,
                                                 unsigned short* __restrict__ vT) {
  const int bh = blockIdx.y;               // b*16+h
  const int b = bh >> 4, h = bh & 15;
  const int tt = blockIdx.x * 64;          // token tile
  const int tid = threadIdx.x;
  __shared__ unsigned short tile[64][65];  // +1 pad
  const int tr = tid >> 2, tc4 = (tid & 3) * 16;
  const unsigned short* src = qkv + (size_t)(b * Tt + tt + tr) * (3 * Ee) + 2 * Ee + h * 64 + tc4;
  const sv8 a0 = *(const sv8*)src;
  const sv8 a1 = *(const sv8*)(src + 8);
#pragma unroll
  for (int j = 0; j < 8; ++j) { tile[tr][tc4 + j] = a0[j]; tile[tr][tc4 + 8 + j] = a1[j]; }
  __syncthreads();
  unsigned short* dst = vT + ((size_t)bh * 64 + tr) * Tt + tt + tc4;
  sv8 o0, o1;
#pragma unroll
  for (int j = 0; j < 8; ++j) { o0[j] = (short)tile[tc4 + j][tr]; o1[j] = (short)tile[tc4 + 8 + j][tr]; }
  *(sv8*)dst = o0;
  *(sv8*)(dst + 8) = o1;
}

// ---------------- LayerNorm (fp32 in, bf16 out), one block per row ----------------
__global__ __launch_bounds__(256) void ln_kernel(const float* __restrict__ x,
                                                 const float* __restrict__ g,
                                                 const float* __restrict__ b,
                                                 unsigned short* __restrict__ out) {
  const int row = blockIdx.x, tid = threadIdx.x;
  const float4 v = *(const float4*)(x + (size_t)row * Ee + tid * 4);
  float s = v.x + v.y + v.z + v.w;
  float ss = v.x * v.x + v.y * v.y + v.z * v.z + v.w * v.w;
#pragma unroll
  for (int off = 32; off; off >>= 1) { s += __shfl_down(s, off); ss += __shfl_down(ss, off); }
  __shared__ float red[16];
  const int w = tid >> 6, l = tid & 63;
  if (l == 0) { red[w] = s; red[8 + w] = ss; }
  __syncthreads();
  s = red[0] + red[1] + red[2] + red[3];
  ss = red[8] + red[9] + red[10] + red[11];
  const float mean = s * (1.f / Ee);
  const float rstd = rsqrtf(ss * (1.f / Ee) - mean * mean + EPSv);
  const float4 gv = *(const float4*)(g + tid * 4);
  const float4 bv = *(const float4*)(b + tid * 4);
  sv4 o;
  o[0] = (short)f2b((v.x - mean) * rstd * gv.x + bv.x);
  o[1] = (short)f2b((v.y - mean) * rstd * gv.y + bv.y);
  o[2] = (short)f2b((v.z - mean) * rstd * gv.z + bv.z);
  o[3] = (short)f2b((v.w - mean) * rstd * gv.w + bv.w);
  *(sv4*)(out + (size_t)row * Ee + tid * 4) = o;
}

// ---------------- bf16 GEMM: C[n,m] = sum_k A[n,k]*B[m,k] variants ----------------
// 128xBN tile, BK=32, 4 waves (2x2). Double-buffered LDS, one barrier per K-step.
// LDS chunk swizzle (T2, rule #21 both-sides): row r's 4 chunks stored permuted as
// chunk' = chunk ^ ((r>>1)&3), via pre-swizzled global_load_lds SOURCE (dest linear);
// fragment reads XOR the same term -> 2 lanes/bank (free) instead of 8-way conflict.
// GEGLU=1 (block-16 interleaved W1): lane-local a/gate epilogue, bf16 out stride M/2.
template <int OUTF32, int HASBIAS, int BN, int GEGLU>
__global__ __launch_bounds__(256) void gemm_bt(const unsigned short* __restrict__ A,
                                               const unsigned short* __restrict__ Bw,
                                               void* __restrict__ Cout,
                                               const float* __restrict__ bias,
                                               const float* __restrict__ res,
                                               int M, int K) {
  constexpr int NI = BN / 32;  // per-wave n-frags (wave covers BN/2 cols)
  __shared__ unsigned short lA[2][128 * 32];
  __shared__ unsigned short lB[2][BN * 32];
  const int tid = threadIdx.x;
  const int l = tid & 63, w = tid >> 6;
  const int wr = w >> 1, wc = w & 1;
  const int rowbase = blockIdx.y * 128, colbase = blockIdx.x * BN;

  const fv4 zero4 = {0.f, 0.f, 0.f, 0.f};
  fv4 acc[4][NI];
#pragma unroll
  for (int i = 0; i < 4; ++i)
#pragma unroll
    for (int j = 0; j < NI; ++j) acc[i][j] = zero4;

  // staging: A = 512 chunks of 8 bf16 (threads do c0,c1); B = BN*4 chunks.
  // source chunk pre-swizzled: x' = x ^ ((row>>1)&3) = (c&3) ^ ((c>>3)&3)
  const int c0 = tid, c1 = tid + 256;
  const int sw0 = ((c0 & 3) ^ ((c0 >> 3) & 3)) * 8;
  const int sw1 = ((c1 & 3) ^ ((c1 >> 3) & 3)) * 8;
  const unsigned short* Ag0 = A + (size_t)(rowbase + (c0 >> 2)) * K + sw0;
  const unsigned short* Ag1 = A + (size_t)(rowbase + (c1 >> 2)) * K + sw1;
  const unsigned short* Bg0 = Bw + (size_t)(colbase + (c0 >> 2)) * K + sw0;
  const unsigned short* Bg1 = Bw + (size_t)(colbase + ((BN == 128 ? c1 : c0) >> 2)) * K +
                              (BN == 128 ? sw1 : sw0);

  const int nk = K >> 5;

  // ---- prologue: stage tile 0 into buffer 0 ----
  load_lds16(Ag0, lA[0] + c0 * 8);
  load_lds16(Ag1, lA[0] + c1 * 8);
  load_lds16(Bg0, lB[0] + c0 * 8);
  if (BN == 128) load_lds16(Bg1, lB[0] + c1 * 8);
  Ag0 += 32; Ag1 += 32; Bg0 += 32; Bg1 += 32;
  __syncthreads();

  int cur = 0;
  for (int kt = 0; kt < nk; ++kt) {
    const int nx = cur ^ 1;
    // ---- prefetch tile kt+1 (async; drained by end-of-iter barrier) ----
    if (kt + 1 < nk) {
      load_lds16(Ag0, lA[nx] + c0 * 8);
      load_lds16(Ag1, lA[nx] + c1 * 8);
      load_lds16(Bg0, lB[nx] + c0 * 8);
      if (BN == 128) load_lds16(Bg1, lB[nx] + c1 * 8);
      Ag0 += 32; Ag1 += 32; Bg0 += 32; Bg1 += 32;
    }
    sv8 af[4], bfr[NI];
#pragma unroll
    for (int i = 0; i < 4; ++i) {
      const int ra = wr * 64 + i * 16 + (l & 15);
      af[i] = *(const sv8*)(lA[cur] + ra * 32 + (((l >> 4) ^ ((ra >> 1) & 3)) * 8));
    }
#pragma unroll
    for (int i = 0; i < NI; ++i) {
      const int rb = wc * (BN / 2) + i * 16 + (l & 15);
      bfr[i] = *(const sv8*)(lB[cur] + rb * 32 + (((l >> 4) ^ ((rb >> 1) & 3)) * 8));
    }
    __builtin_amdgcn_s_setprio(1);
#pragma unroll
    for (int mi = 0; mi < 4; ++mi)
#pragma unroll
      for (int ni = 0; ni < NI; ++ni)
        acc[mi][ni] = __builtin_amdgcn_mfma_f32_16x16x32_bf16(af[mi], bfr[ni], acc[mi][ni], 0, 0, 0);
    __builtin_amdgcn_s_setprio(0);
    __syncthreads();  // drains prefetch vmcnt; all waves done reading buf[cur]
    cur = nx;
  }

  // C/D layout: col = lane&15, row = (lane>>4)*4 + j   [measured m89/m91]
  const int r0 = rowbase + wr * 64 + ((l >> 4) * 4);
  const int ccol = colbase + wc * (BN / 2) + (l & 15);
#pragma unroll
  for (int mi = 0; mi < 4; ++mi) {
#pragma unroll
    for (int j = 0; j < 4; ++j) {
      const size_t r = (size_t)(r0 + mi * 16 + j);
      if (GEGLU) {
#pragma unroll
        for (int p = 0; p < NI / 2; ++p) {
          const int ca = ccol + p * 32;                      // even fragment (a); bit4 == 0
          const int ocol = ((ca >> 5) << 4) | (ca & 15);     // original column
          const float av = acc[mi][2 * p][j] + bias[ocol];
          const float gv = acc[mi][2 * p + 1][j] + bias[ocol + (M >> 1)];
          // tanh-approx gelu: 0.5*g*(1+tanh(0.79788456*(g+0.044715 g^3)))
          const float y = 0.7978845608028654f * (gv + 0.044715f * gv * gv * gv);
          const float e = exp2f(2.8853900817779268f * y);    // exp(2y)
          const float gel = gv * (1.f - 1.f / (e + 1.f));    // == 0.5*g*(1+tanh(y))
          ((unsigned short*)Cout)[r * (size_t)(M >> 1) + ocol] = f2b(av * gel);
        }
      } else {
#pragma unroll
        for (int ni = 0; ni < NI; ++ni) {
          const int c = ccol + ni * 16;
          float vv = acc[mi][ni][j];
          if (HASBIAS) vv += bias[c];
          if (OUTF32) {
            ((float*)Cout)[r * M + c] = res[r * M + c] + vv;
          } else {
            ((unsigned short*)Cout)[r * M + c] = f2b(vv);
          }
        }
      }
    }
  }
}

// ---------------- flash attention: 1 block = (b, h, 64 q-rows), 4 waves x 16 rows ---
// K AND V both staged via global_load_lds with pre-swizzled source (V from the
// pre-transposed vT[b][h][d][t] buffer) -> no reg-staging, ONE barrier per iter.
// Softmax: exp2 domain (scale folded into Wq), group max, deferred denominator.
// XCD-bijective swizzle: K/V working set resident in one XCD's L2.
__global__ __launch_bounds__(256) void attn_kernel(const unsigned short* __restrict__ Q,
                                                   const unsigned short* __restrict__ Kb,
                                                   const unsigned short* __restrict__ vT,
                                                   unsigned short* __restrict__ O,
                                                   int ld) {
  const int bidl = ((blockIdx.x & 7) << 7) + (blockIdx.x >> 3);  // 1024 = 8 XCD x 128
  const int bh = bidl >> 5;
  const int b = bh / Hh, h = bh % Hh;
  const int q0 = (bidl & 31) * 64;
  const int tid = threadIdx.x, l = tid & 63, w = tid >> 6;
  const size_t base = (size_t)b * Tt * ld + (size_t)h * Dd;
  const size_t baseO = (size_t)b * Tt * Ee + (size_t)h * Dd;
  const unsigned short* vTb = vT + (size_t)bh * 64 * Tt;  // [64 d][2048 t]

  __shared__ unsigned short Kt[2][64 * 64];
  __shared__ unsigned short Vt[2][64 * 64];
  __shared__ unsigned short Pt[4][16 * 64];

  // Q fragments held in registers: A-layout row = l&15, k-chunk = (l>>4)*8
  sv8 qf0, qf1;
  {
    const unsigned short* qp = Q + base + (size_t)(q0 + w * 16 + (l & 15)) * ld + (l >> 4) * 8;
    qf0 = *(const sv8*)qp;
    qf1 = *(const sv8*)(qp + 32);
  }

  const fv4 zero4 = {0.f, 0.f, 0.f, 0.f};
  fv4 acc_o[4];
#pragma unroll
  for (int i = 0; i < 4; ++i) acc_o[i] = zero4;
  float Mx = -INFINITY;
  float Lp[4];
#pragma unroll
  for (int j = 0; j < 4; ++j) Lp[j] = 0.f;

  const int c0 = tid, c1 = tid + 256;
  const int r0c = c0 >> 3, xc0 = c0 & 7;   // chunk -> (row, chunk-in-row)
  const int r1c = c1 >> 3, xc1 = c1 & 7;   // xc1 == xc0

  // ---- prologue: stage tile 0 (K rows = tokens; V rows = d from vT) ----
  load_lds16(Kb + base + (size_t)(r0c)*ld + (xc0 ^ (r0c & 7)) * 8, Kt[0] + c0 * 8);
  load_lds16(Kb + base + (size_t)(r1c)*ld + (xc1 ^ (r1c & 7)) * 8, Kt[0] + c1 * 8);
  load_lds16(vTb + (size_t)(r0c)*Tt + (xc0 ^ (r0c & 7)) * 8, Vt[0] + c0 * 8);
  load_lds16(vTb + (size_t)(r1c)*Tt + (xc1 ^ (r1c & 7)) * 8, Vt[0] + c1 * 8);
  __syncthreads();

  int cur = 0;
  for (int kt = 0; kt < Tt / 64; ++kt) {
    const int nx = cur ^ 1;
    // ---- prefetch tile kt+1 (async; drained by the end-of-iter barrier) ----
    if (kt + 1 < Tt / 64) {
      load_lds16(Kb + base + (size_t)((kt + 1) * 64 + r0c) * ld + (xc0 ^ (r0c & 7)) * 8, Kt[nx] + c0 * 8);
      load_lds16(Kb + base + (size_t)((kt + 1) * 64 + r1c) * ld + (xc1 ^ (r1c & 7)) * 8, Kt[nx] + c1 * 8);
      load_lds16(vTb + (size_t)(r0c)*Tt + (kt + 1) * 64 + (xc0 ^ (r0c & 7)) * 8, Vt[nx] + c0 * 8);
      load_lds16(vTb + (size_t)(r1c)*Tt + (kt + 1) * 64 + (xc1 ^ (r1c & 7)) * 8, Vt[nx] + c1 * 8);
    }

    // --- S = Q K^T (per wave: 16 q-rows x 64 k-cols) from Kt[cur]; pre-scaled ---
    fv4 s[4];
    __builtin_amdgcn_s_setprio(1);
#pragma unroll
    for (int ks = 0; ks < 4; ++ks) {
      const int row = ks * 16 + (l & 15);
      const sv8 kf0 = *(const sv8*)(Kt[cur] + row * 64 + (((l >> 4) ^ (row & 7)) * 8));
      const sv8 kf1 = *(const sv8*)(Kt[cur] + row * 64 + (((4 + (l >> 4)) ^ (row & 7)) * 8));
      fv4 t = zero4;
      t = __builtin_amdgcn_mfma_f32_16x16x32_bf16(qf0, kf0, t, 0, 0, 0);
      t = __builtin_amdgcn_mfma_f32_16x16x32_bf16(qf1, kf1, t, 0, 0, 0);
      s[ks] = t;
    }
    __builtin_amdgcn_s_setprio(0);

    // --- lane-local overflow check ---
    float m01 = fmaxf(fmaxf(s[0][0], s[0][1]), fmaxf(s[0][2], s[0][3]));
    float m1 = fmaxf(fmaxf(s[1][0], s[1][1]), fmaxf(s[1][2], s[1][3]));
    float m2 = fmaxf(fmaxf(s[2][0], s[2][1]), fmaxf(s[2][2], s[2][3]));
    float m3 = fmaxf(fmaxf(s[3][0], s[3][1]), fmaxf(s[3][2], s[3][3]));
    float tm = fmaxf(fmaxf(m01, m1), fmaxf(m2, m3));
    if (__any(tm > Mx + 11.5f)) {
      // group max -> rescale (rare; always fires on tile 0 where Mx = -inf)
      float mt = tm;
#pragma unroll
      for (int off = 1; off < 16; off <<= 1) mt = fmaxf(mt, __shfl_xor(mt, off, 16));
      const float mnew = fmaxf(Mx, mt);
      const float alpha = exp2f(Mx - mnew);  // tile 0: exp2(-inf) = 0
      Mx = mnew;
#pragma unroll
      for (int j = 0; j < 4; ++j) {
        Lp[j] *= alpha;
#pragma unroll
        for (int dsb = 0; dsb < 4; ++dsb) acc_o[dsb][j] *= alpha;
      }
    }
    // --- p = exp2(s - Mx); per-lane partial sums; store P (trunc bf16) ---
#pragma unroll
    for (int ks = 0; ks < 4; ++ks)
#pragma unroll
      for (int j = 0; j < 4; ++j) {
        const float p = exp2f(s[ks][j] - Mx);
        s[ks][j] = p;
        Lp[j] += p;
      }
#pragma unroll
    for (int ks = 0; ks < 4; ++ks)
#pragma unroll
      for (int j = 0; j < 4; ++j) {
        const int q = (l >> 4) * 4 + j, k = ks * 16 + (l & 15);
        Pt[w][q * 64 + ((((k >> 3) ^ (q & 7)) & 7) * 8) + (k & 7)] = f2b_rtz(s[ks][j]);
      }
    asm volatile("s_waitcnt lgkmcnt(0)" ::: "memory");

    // --- O += P V : b128 reads from swizzled Pt / Vt[cur] (d-major rows) ---
    __builtin_amdgcn_s_setprio(1);
#pragma unroll
    for (int kcn = 0; kcn < 2; ++kcn) {
      const int qr = l & 15;
      const sv8 pf = *(const sv8*)(&Pt[w][qr * 64 + (((kcn * 4 + (l >> 4)) ^ (qr & 7)) * 8)]);
#pragma unroll
      for (int dsb = 0; dsb < 4; ++dsb) {
        const int row = dsb * 16 + (l & 15);
        const int chunk = kcn * 4 + (l >> 4);
        const sv8 vf = *(const sv8*)(Vt[cur] + row * 64 + ((chunk ^ (row & 7)) * 8));
        acc_o[dsb] = __builtin_amdgcn_mfma_f32_16x16x32_bf16(pf, vf, acc_o[dsb], 0, 0, 0);
      }
    }
    __builtin_amdgcn_s_setprio(0);

    __syncthreads();  // drains prefetch vmcnt; all waves done reading [cur]
    cur = nx;
  }

  // ---- deferred denominator: one 16-lane reduce per q-row, then write O ----
#pragma unroll
  for (int j = 0; j < 4; ++j) {
    float t = Lp[j];
#pragma unroll
    for (int off = 1; off < 16; off <<= 1) t += __shfl_xor(t, off, 16);
    const float inv = 1.f / t;
    unsigned short* op = O + baseO + (size_t)(q0 + w * 16 + (l >> 4) * 4 + j) * Ee;
#pragma unroll
    for (int dsb = 0; dsb < 4; ++dsb)
      op[dsb * 16 + (l & 15)] = f2b(acc_o[dsb][j] * inv);
  }
}

extern "C" void kernel_launch(void* const* d_in, const int* in_sizes, int n_in,
                              void* d_out, int out_size, void* d_ws, size_t ws_size,
                              hipStream_t stream) {
  (void)in_sizes; (void)n_in; (void)out_size; (void)ws_size;
  const float* src  = (const float*)d_in[0];
  const float* Wq   = (const float*)d_in[1];
  const float* Wk   = (const float*)d_in[2];
  const float* Wv   = (const float*)d_in[3];
  const float* Wo   = (const float*)d_in[4];
  const float* W1   = (const float*)d_in[5];
  const float* b1   = (const float*)d_in[6];
  const float* W2   = (const float*)d_in[7];
  const float* b2   = (const float*)d_in[8];
  const float* ln1w = (const float*)d_in[9];
  const float* ln1b = (const float*)d_in[10];
  const float* ln2w = (const float*)d_in[11];
  const float* ln2b = (const float*)d_in[12];
  float* out = (float*)d_out;

  char* ws = (char*)d_ws;
  size_t off = 0;
  auto alloc = [&](size_t bytes) { char* p = ws + off; off += bytes; return p; };
  unsigned short* wqkv = (unsigned short*)alloc((size_t)3 * Ee * Ee * 2);  // Wq|Wk|Wv rows
  unsigned short* wo16 = (unsigned short*)alloc((size_t)Ee * Ee * 2);
  unsigned short* w116 = (unsigned short*)alloc((size_t)2 * FFd * Ee * 2); // interleaved
  unsigned short* w216 = (unsigned short*)alloc((size_t)Ee * FFd * 2);
  unsigned short* h16  = (unsigned short*)alloc((size_t)NN * Ee * 2);
  unsigned short* qkv  = (unsigned short*)alloc((size_t)NN * 3 * Ee * 2);  // [row][3E]
  unsigned short* a16  = (unsigned short*)alloc((size_t)NN * Ee * 2);
  float* xbuf          = (float*)alloc((size_t)NN * Ee * 4);
  unsigned short* vT   = (unsigned short*)alloc((size_t)NN * Ee * 2);      // [b][h][64][T]
  unsigned short* f16  = qkv;  // reuse qkv+a16 region (32 MB) after attention done

  const float s2 = 0.125f * 1.4426950408889634f;  // 1/sqrt(D) * log2(e), folded into Wq

  dim3 blk(256);
  cvt_kernel<<<dim3(Ee * Ee / 1024), blk, 0, stream>>>(Wq, wqkv, Ee * Ee, s2);
  cvt_kernel<<<dim3(Ee * Ee / 1024), blk, 0, stream>>>(Wk, wqkv + Ee * Ee, Ee * Ee, 1.0f);
  cvt_kernel<<<dim3(Ee * Ee / 1024), blk, 0, stream>>>(Wv, wqkv + 2 * Ee * Ee, Ee * Ee, 1.0f);
  cvt_kernel<<<dim3(Ee * Ee / 1024), blk, 0, stream>>>(Wo, wo16, Ee * Ee, 1.0f);
  cvt_w1_kernel<<<dim3(2 * FFd * Ee / 1024), blk, 0, stream>>>(W1, w116);
  cvt_kernel<<<dim3(Ee * FFd / 1024), blk, 0, stream>>>(W2, w216, Ee * FFd, 1.0f);

  ln_kernel<<<dim3(NN), blk, 0, stream>>>(src, ln1w, ln1b, h16);

  // fused QKV projection: [4096,1024] x [3072,1024]^T -> [4096,3072]
  gemm_bt<0, 0, 128, 0><<<dim3(3 * Ee / 128, NN / 128), blk, 0, stream>>>(h16, wqkv, qkv, nullptr, nullptr, 3 * Ee, Ee);

  // V transpose: [t][h*64+d] -> vT[b][h][d][t]
  vt_kernel<<<dim3(Tt / 64, Bb * Hh), blk, 0, stream>>>(qkv, vT);

  attn_kernel<<<dim3(1024), blk, 0, stream>>>(qkv, qkv + Ee, vT, a16, 3 * Ee);

  // Wo projection + residual (BN=64: 512 blocks, 2/CU)
  gemm_bt<1, 0, 64, 0><<<dim3(Ee / 64, NN / 128), blk, 0, stream>>>(a16, wo16, xbuf, nullptr, src, Ee, Ee);

  ln_kernel<<<dim3(NN), blk, 0, stream>>>(xbuf, ln2w, ln2b, h16);

  // W1 (block-16 interleaved) + lane-local GEGLU epilogue -> f16 [4096][4096]
  gemm_bt<0, 0, 128, 1><<<dim3(2 * FFd / 128, NN / 128), blk, 0, stream>>>(h16, w116, f16, b1, nullptr, 2 * FFd, Ee);

  // W2 projection + bias + residual (BN=64: 512 blocks, 2/CU)
  gemm_bt<1, 1, 64, 0><<<dim3(Ee / 64, NN / 128), blk, 0, stream>>>(f16, w216, out, b2, xbuf, Ee, FFd);
}

// Round 11
// 315.317 us; speedup vs baseline: 1.6367x; 1.0149x over previous
//
#include <hip/hip_runtime.h>
#include <stdint.h>
#include <math.h>

#define DEVI __device__ __forceinline__

typedef __attribute__((ext_vector_type(8))) short sv8;
typedef __attribute__((ext_vector_type(4))) short sv4;
typedef __attribute__((ext_vector_type(4))) float fv4;

typedef __attribute__((address_space(1))) void av1_t;
typedef __attribute__((address_space(3))) void av3_t;

constexpr int Bb = 2, Tt = 2048, Ee = 1024, Hh = 16, Dd = 64, FFd = 4096;
constexpr int NN = Bb * Tt;  // 4096 token rows
constexpr float EPSv = 1e-5f;

#define WAIT_VM(n) asm volatile("s_waitcnt vmcnt(" #n ")" ::: "memory")

DEVI float b2f(unsigned short s) {
  union { unsigned u; float f; } v; v.u = ((unsigned)s) << 16; return v.f;
}
DEVI unsigned short f2b(float f) {
  union { float f; unsigned u; } v; v.f = f;
  return (unsigned short)((v.u + 0x7FFFu + ((v.u >> 16) & 1u)) >> 16);
}
DEVI unsigned short f2b_rtz(float f) {  // truncation: 1 VALU op (softmax P only)
  union { float f; unsigned u; } v; v.f = f;
  return (unsigned short)(v.u >> 16);
}

// global -> LDS direct (16B per lane). LDS dest must be wave-uniform base + lane*16.
DEVI void load_lds16(const void* g, void* s) {
  __builtin_amdgcn_global_load_lds((av1_t*)(unsigned long long)g,
                                   (av3_t*)(unsigned)(unsigned long long)s,
                                   16, 0, 0);
}

// ---------------- fp32 -> bf16 convert (optional scale fold) ----------------
__global__ __launch_bounds__(256) void cvt_kernel(const float* __restrict__ in,
                                                  unsigned short* __restrict__ out, int n,
                                                  float scale) {
  int i = (blockIdx.x * 256 + threadIdx.x) * 4;
  if (i >= n) return;
  float4 v = *(const float4*)(in + i);
  sv4 o;
  o[0] = (short)f2b(v.x * scale); o[1] = (short)f2b(v.y * scale);
  o[2] = (short)f2b(v.z * scale); o[3] = (short)f2b(v.w * scale);
  *(sv4*)(out + i) = o;
}

// -------- W1 convert, block-16 interleave: a-row r -> 32*(r>>4)+(r&15);
//          gate-row (r-FFd) -> 32*((r-FFd)>>4)+16+(r&15). Even 16-col fragment = a,
//          odd = gate, SAME output cols -> lane-local GEGLU in the GEMM epilogue.
__global__ __launch_bounds__(256) void cvt_w1_kernel(const float* __restrict__ in,
                                                     unsigned short* __restrict__ out) {
  int i = (blockIdx.x * 256 + threadIdx.x) * 4;  // flat over 2*FFd*Ee
  const int r = i >> 10, c = i & 1023;
  const int rp = (r < FFd) ? ((r >> 4) * 32 + (r & 15))
                           : (((r - FFd) >> 4) * 32 + 16 + (r & 15));
  float4 v = *(const float4*)(in + i);
  sv4 o;
  o[0] = (short)f2b(v.x); o[1] = (short)f2b(v.y);
  o[2] = (short)f2b(v.z); o[3] = (short)f2b(v.w);
  *(sv4*)(out + (size_t)rp * Ee + c) = o;
}

// ---------------- V transpose: qkv V-slice [t][h*64+d] -> vT[b][h][d][t] ----------
__global__ __launch_bounds__(256) void vt_kernel(const unsigned short* __restrict__ qkv,
                                                 unsigned short* __restrict__ vT) {
  const int bh = blockIdx.y;               // b*16+h
  const int b = bh >> 4, h = bh & 15;
  const int tt = blockIdx.x * 64;          // token tile
  const int tid = threadIdx.x;
  __shared__ unsigned short tile[64][65];  // +1 pad
  const int tr = tid >> 2, tc4 = (tid & 3) * 16;
  const unsigned short* src = qkv + (size_t)(b * Tt + tt + tr) * (3 * Ee) + 2 * Ee + h * 64 + tc4;
  const sv8 a0 = *(const sv8*)src;
  const sv8 a1 = *(const sv8*)(src + 8);
#pragma unroll
  for (int j = 0; j < 8; ++j) { tile[tr][tc4 + j] = a0[j]; tile[tr][tc4 + 8 + j] = a1[j]; }
  __syncthreads();
  unsigned short* dst = vT + ((size_t)bh * 64 + tr) * Tt + tt + tc4;
  sv8 o0, o1;
#pragma unroll
  for (int j = 0; j < 8; ++j) { o0[j] = (short)tile[tc4 + j][tr]; o1[j] = (short)tile[tc4 + 8 + j][tr]; }
  *(sv8*)dst = o0;
  *(sv8*)(dst + 8) = o1;
}

// ---------------- LayerNorm (fp32 in, bf16 out), one block per row ----------------
__global__ __launch_bounds__(256) void ln_kernel(const float* __restrict__ x,
                                                 const float* __restrict__ g,
                                                 const float* __restrict__ b,
                                                 unsigned short* __restrict__ out) {
  const int row = blockIdx.x, tid = threadIdx.x;
  const float4 v = *(const float4*)(x + (size_t)row * Ee + tid * 4);
  float s = v.x + v.y + v.z + v.w;
  float ss = v.x * v.x + v.y * v.y + v.z * v.z + v.w * v.w;
#pragma unroll
  for (int off = 32; off; off >>= 1) { s += __shfl_down(s, off); ss += __shfl_down(ss, off); }
  __shared__ float red[16];
  const int w = tid >> 6, l = tid & 63;
  if (l == 0) { red[w] = s; red[8 + w] = ss; }
  __syncthreads();
  s = red[0] + red[1] + red[2] + red[3];
  ss = red[8] + red[9] + red[10] + red[11];
  const float mean = s * (1.f / Ee);
  const float rstd = rsqrtf(ss * (1.f / Ee) - mean * mean + EPSv);
  const float4 gv = *(const float4*)(g + tid * 4);
  const float4 bv = *(const float4*)(b + tid * 4);
  sv4 o;
  o[0] = (short)f2b((v.x - mean) * rstd * gv.x + bv.x);
  o[1] = (short)f2b((v.y - mean) * rstd * gv.y + bv.y);
  o[2] = (short)f2b((v.z - mean) * rstd * gv.z + bv.z);
  o[3] = (short)f2b((v.w - mean) * rstd * gv.w + bv.w);
  *(sv4*)(out + (size_t)row * Ee + tid * 4) = o;
}

// ---------------- bf16 GEMM: C[n,m] = sum_k A[n,k]*B[m,k] variants ----------------
// 128xBN tile, BK=32, 4 waves (2x2). DEPTH-2 pipeline (T4): 3 LDS buffers; iter t
// issues STAGE(t+2), computes tile t, then `s_waitcnt vmcnt(LPS)` + raw s_barrier —
// tile t+1 is guaranteed landed while tile t+2's loads stay in flight ACROSS the
// barrier (counted wait, never vmcnt(0) mid-loop). Chunk swizzle (T2) as in R10.
// GEGLU=1 (block-16 interleaved W1): lane-local a/gate epilogue, bf16 out stride M/2.
template <int OUTF32, int HASBIAS, int BN, int GEGLU>
__global__ __launch_bounds__(256) void gemm_bt(const unsigned short* __restrict__ A,
                                               const unsigned short* __restrict__ Bw,
                                               void* __restrict__ Cout,
                                               const float* __restrict__ bias,
                                               const float* __restrict__ res,
                                               int M, int K) {
  constexpr int NI = BN / 32;  // per-wave n-frags (wave covers BN/2 cols)
  __shared__ unsigned short lA[3][128 * 32];
  __shared__ unsigned short lB[3][BN * 32];
  const int tid = threadIdx.x;
  const int l = tid & 63, w = tid >> 6;
  const int wr = w >> 1, wc = w & 1;
  const int rowbase = blockIdx.y * 128, colbase = blockIdx.x * BN;

  const fv4 zero4 = {0.f, 0.f, 0.f, 0.f};
  fv4 acc[4][NI];
#pragma unroll
  for (int i = 0; i < 4; ++i)
#pragma unroll
    for (int j = 0; j < NI; ++j) acc[i][j] = zero4;

  // staging: A = 512 chunks of 8 bf16 (threads do c0,c1); B = BN*4 chunks.
  // source chunk pre-swizzled: x' = x ^ ((row>>1)&3) = (c&3) ^ ((c>>3)&3)
  const int c0 = tid, c1 = tid + 256;
  const int sw0 = ((c0 & 3) ^ ((c0 >> 3) & 3)) * 8;
  const int sw1 = ((c1 & 3) ^ ((c1 >> 3) & 3)) * 8;
  const unsigned short* Ag0 = A + (size_t)(rowbase + (c0 >> 2)) * K + sw0;
  const unsigned short* Ag1 = A + (size_t)(rowbase + (c1 >> 2)) * K + sw1;
  const unsigned short* Bg0 = Bw + (size_t)(colbase + (c0 >> 2)) * K + sw0;
  const unsigned short* Bg1 = Bw + (size_t)(colbase + ((BN == 128 ? c1 : c0) >> 2)) * K +
                              (BN == 128 ? sw1 : sw0);

  const int nk = K >> 5;

  auto stage = [&](int buf) {
    load_lds16(Ag0, lA[buf] + c0 * 8);
    load_lds16(Ag1, lA[buf] + c1 * 8);
    load_lds16(Bg0, lB[buf] + c0 * 8);
    if (BN == 128) load_lds16(Bg1, lB[buf] + c1 * 8);
    Ag0 += 32; Ag1 += 32; Bg0 += 32; Bg1 += 32;
  };

  // ---- prologue: stage tiles 0 and 1; wait only for tile 0 (counted) ----
  stage(0);
  stage(1);
  if constexpr (BN == 128) WAIT_VM(4); else WAIT_VM(3);
  __builtin_amdgcn_s_barrier();

  int cur = 0;
  for (int t = 0; t < nk; ++t) {
    const int pf = (cur + 2 >= 3) ? cur - 1 : cur + 2;  // (cur+2)%3
    if (t + 2 < nk) stage(pf);
    sv8 af[4], bfr[NI];
#pragma unroll
    for (int i = 0; i < 4; ++i) {
      const int ra = wr * 64 + i * 16 + (l & 15);
      af[i] = *(const sv8*)(lA[cur] + ra * 32 + (((l >> 4) ^ ((ra >> 1) & 3)) * 8));
    }
#pragma unroll
    for (int i = 0; i < NI; ++i) {
      const int rb = wc * (BN / 2) + i * 16 + (l & 15);
      bfr[i] = *(const sv8*)(lB[cur] + rb * 32 + (((l >> 4) ^ ((rb >> 1) & 3)) * 8));
    }
    __builtin_amdgcn_s_setprio(1);
#pragma unroll
    for (int mi = 0; mi < 4; ++mi)
#pragma unroll
      for (int ni = 0; ni < NI; ++ni)
        acc[mi][ni] = __builtin_amdgcn_mfma_f32_16x16x32_bf16(af[mi], bfr[ni], acc[mi][ni], 0, 0, 0);
    __builtin_amdgcn_s_setprio(0);
    // ---- end-of-iter sync: tile t+1 guaranteed landed; tile t+2 stays in flight ----
    if (t + 2 < nk) {
      if constexpr (BN == 128) WAIT_VM(4); else WAIT_VM(3);
      __builtin_amdgcn_s_barrier();
    } else if (t + 1 < nk) {
      WAIT_VM(0);
      __builtin_amdgcn_s_barrier();
    }
    cur = (cur + 1 >= 3) ? 0 : cur + 1;
  }

  // C/D layout: col = lane&15, row = (lane>>4)*4 + j   [measured m89/m91]
  const int r0 = rowbase + wr * 64 + ((l >> 4) * 4);
  const int ccol = colbase + wc * (BN / 2) + (l & 15);
#pragma unroll
  for (int mi = 0; mi < 4; ++mi) {
#pragma unroll
    for (int j = 0; j < 4; ++j) {
      const size_t r = (size_t)(r0 + mi * 16 + j);
      if (GEGLU) {
#pragma unroll
        for (int p = 0; p < NI / 2; ++p) {
          const int ca = ccol + p * 32;                      // even fragment (a); bit4 == 0
          const int ocol = ((ca >> 5) << 4) | (ca & 15);     // original column
          const float av = acc[mi][2 * p][j] + bias[ocol];
          const float gv = acc[mi][2 * p + 1][j] + bias[ocol + (M >> 1)];
          // tanh-approx gelu: 0.5*g*(1+tanh(0.79788456*(g+0.044715 g^3)))
          const float y = 0.7978845608028654f * (gv + 0.044715f * gv * gv * gv);
          const float e = exp2f(2.8853900817779268f * y);    // exp(2y)
          const float gel = gv * (1.f - 1.f / (e + 1.f));    // == 0.5*g*(1+tanh(y))
          ((unsigned short*)Cout)[r * (size_t)(M >> 1) + ocol] = f2b(av * gel);
        }
      } else {
#pragma unroll
        for (int ni = 0; ni < NI; ++ni) {
          const int c = ccol + ni * 16;
          float vv = acc[mi][ni][j];
          if (HASBIAS) vv += bias[c];
          if (OUTF32) {
            ((float*)Cout)[r * M + c] = res[r * M + c] + vv;
          } else {
            ((unsigned short*)Cout)[r * M + c] = f2b(vv);
          }
        }
      }
    }
  }
}

// ---------------- flash attention: 1 block = (b, h, 64 q-rows), 4 waves x 16 rows ---
// K AND V both staged via global_load_lds with pre-swizzled source (V from the
// pre-transposed vT[b][h][d][t] buffer) -> no reg-staging, ONE barrier per iter.
// Softmax: exp2 domain (scale folded into Wq), group max, deferred denominator.
// XCD-bijective swizzle: K/V working set resident in one XCD's L2.
__global__ __launch_bounds__(256) void attn_kernel(const unsigned short* __restrict__ Q,
                                                   const unsigned short* __restrict__ Kb,
                                                   const unsigned short* __restrict__ vT,
                                                   unsigned short* __restrict__ O,
                                                   int ld) {
  const int bidl = ((blockIdx.x & 7) << 7) + (blockIdx.x >> 3);  // 1024 = 8 XCD x 128
  const int bh = bidl >> 5;
  const int b = bh / Hh, h = bh % Hh;
  const int q0 = (bidl & 31) * 64;
  const int tid = threadIdx.x, l = tid & 63, w = tid >> 6;
  const size_t base = (size_t)b * Tt * ld + (size_t)h * Dd;
  const size_t baseO = (size_t)b * Tt * Ee + (size_t)h * Dd;
  const unsigned short* vTb = vT + (size_t)bh * 64 * Tt;  // [64 d][2048 t]

  __shared__ unsigned short Kt[2][64 * 64];
  __shared__ unsigned short Vt[2][64 * 64];
  __shared__ unsigned short Pt[4][16 * 64];

  // Q fragments held in registers: A-layout row = l&15, k-chunk = (l>>4)*8
  sv8 qf0, qf1;
  {
    const unsigned short* qp = Q + base + (size_t)(q0 + w * 16 + (l & 15)) * ld + (l >> 4) * 8;
    qf0 = *(const sv8*)qp;
    qf1 = *(const sv8*)(qp + 32);
  }

  const fv4 zero4 = {0.f, 0.f, 0.f, 0.f};
  fv4 acc_o[4];
#pragma unroll
  for (int i = 0; i < 4; ++i) acc_o[i] = zero4;
  float Mx = -INFINITY;
  float Lp[4];
#pragma unroll
  for (int j = 0; j < 4; ++j) Lp[j] = 0.f;

  const int c0 = tid, c1 = tid + 256;
  const int r0c = c0 >> 3, xc0 = c0 & 7;   // chunk -> (row, chunk-in-row)
  const int r1c = c1 >> 3, xc1 = c1 & 7;   // xc1 == xc0

  // ---- prologue: stage tile 0 (K rows = tokens; V rows = d from vT) ----
  load_lds16(Kb + base + (size_t)(r0c)*ld + (xc0 ^ (r0c & 7)) * 8, Kt[0] + c0 * 8);
  load_lds16(Kb + base + (size_t)(r1c)*ld + (xc1 ^ (r1c & 7)) * 8, Kt[0] + c1 * 8);
  load_lds16(vTb + (size_t)(r0c)*Tt + (xc0 ^ (r0c & 7)) * 8, Vt[0] + c0 * 8);
  load_lds16(vTb + (size_t)(r1c)*Tt + (xc1 ^ (r1c & 7)) * 8, Vt[0] + c1 * 8);
  __syncthreads();

  int cur = 0;
  for (int kt = 0; kt < Tt / 64; ++kt) {
    const int nx = cur ^ 1;
    // ---- prefetch tile kt+1 (async; drained by the end-of-iter barrier) ----
    if (kt + 1 < Tt / 64) {
      load_lds16(Kb + base + (size_t)((kt + 1) * 64 + r0c) * ld + (xc0 ^ (r0c & 7)) * 8, Kt[nx] + c0 * 8);
      load_lds16(Kb + base + (size_t)((kt + 1) * 64 + r1c) * ld + (xc1 ^ (r1c & 7)) * 8, Kt[nx] + c1 * 8);
      load_lds16(vTb + (size_t)(r0c)*Tt + (kt + 1) * 64 + (xc0 ^ (r0c & 7)) * 8, Vt[nx] + c0 * 8);
      load_lds16(vTb + (size_t)(r1c)*Tt + (kt + 1) * 64 + (xc1 ^ (r1c & 7)) * 8, Vt[nx] + c1 * 8);
    }

    // --- S = Q K^T (per wave: 16 q-rows x 64 k-cols) from Kt[cur]; pre-scaled ---
    fv4 s[4];
    __builtin_amdgcn_s_setprio(1);
#pragma unroll
    for (int ks = 0; ks < 4; ++ks) {
      const int row = ks * 16 + (l & 15);
      const sv8 kf0 = *(const sv8*)(Kt[cur] + row * 64 + (((l >> 4) ^ (row & 7)) * 8));
      const sv8 kf1 = *(const sv8*)(Kt[cur] + row * 64 + (((4 + (l >> 4)) ^ (row & 7)) * 8));
      fv4 t = zero4;
      t = __builtin_amdgcn_mfma_f32_16x16x32_bf16(qf0, kf0, t, 0, 0, 0);
      t = __builtin_amdgcn_mfma_f32_16x16x32_bf16(qf1, kf1, t, 0, 0, 0);
      s[ks] = t;
    }
    __builtin_amdgcn_s_setprio(0);

    // --- lane-local overflow check ---
    float m01 = fmaxf(fmaxf(s[0][0], s[0][1]), fmaxf(s[0][2], s[0][3]));
    float m1 = fmaxf(fmaxf(s[1][0], s[1][1]), fmaxf(s[1][2], s[1][3]));
    float m2 = fmaxf(fmaxf(s[2][0], s[2][1]), fmaxf(s[2][2], s[2][3]));
    float m3 = fmaxf(fmaxf(s[3][0], s[3][1]), fmaxf(s[3][2], s[3][3]));
    float tm = fmaxf(fmaxf(m01, m1), fmaxf(m2, m3));
    if (__any(tm > Mx + 11.5f)) {
      // group max -> rescale (rare; always fires on tile 0 where Mx = -inf)
      float mt = tm;
#pragma unroll
      for (int off = 1; off < 16; off <<= 1) mt = fmaxf(mt, __shfl_xor(mt, off, 16));
      const float mnew = fmaxf(Mx, mt);
      const float alpha = exp2f(Mx - mnew);  // tile 0: exp2(-inf) = 0
      Mx = mnew;
#pragma unroll
      for (int j = 0; j < 4; ++j) {
        Lp[j] *= alpha;
#pragma unroll
        for (int dsb = 0; dsb < 4; ++dsb) acc_o[dsb][j] *= alpha;
      }
    }
    // --- p = exp2(s - Mx); per-lane partial sums; store P (trunc bf16) ---
#pragma unroll
    for (int ks = 0; ks < 4; ++ks)
#pragma unroll
      for (int j = 0; j < 4; ++j) {
        const float p = exp2f(s[ks][j] - Mx);
        s[ks][j] = p;
        Lp[j] += p;
      }
#pragma unroll
    for (int ks = 0; ks < 4; ++ks)
#pragma unroll
      for (int j = 0; j < 4; ++j) {
        const int q = (l >> 4) * 4 + j, k = ks * 16 + (l & 15);
        Pt[w][q * 64 + ((((k >> 3) ^ (q & 7)) & 7) * 8) + (k & 7)] = f2b_rtz(s[ks][j]);
      }
    asm volatile("s_waitcnt lgkmcnt(0)" ::: "memory");

    // --- O += P V : b128 reads from swizzled Pt / Vt[cur] (d-major rows) ---
    __builtin_amdgcn_s_setprio(1);
#pragma unroll
    for (int kcn = 0; kcn < 2; ++kcn) {
      const int qr = l & 15;
      const sv8 pf = *(const sv8*)(&Pt[w][qr * 64 + (((kcn * 4 + (l >> 4)) ^ (qr & 7)) * 8)]);
#pragma unroll
      for (int dsb = 0; dsb < 4; ++dsb) {
        const int row = dsb * 16 + (l & 15);
        const int chunk = kcn * 4 + (l >> 4);
        const sv8 vf = *(const sv8*)(Vt[cur] + row * 64 + ((chunk ^ (row & 7)) * 8));
        acc_o[dsb] = __builtin_amdgcn_mfma_f32_16x16x32_bf16(pf, vf, acc_o[dsb], 0, 0, 0);
      }
    }
    __builtin_amdgcn_s_setprio(0);

    __syncthreads();  // drains prefetch vmcnt; all waves done reading [cur]
    cur = nx;
  }

  // ---- deferred denominator: one 16-lane reduce per q-row, then write O ----
#pragma unroll
  for (int j = 0; j < 4; ++j) {
    float t = Lp[j];
#pragma unroll
    for (int off = 1; off < 16; off <<= 1) t += __shfl_xor(t, off, 16);
    const float inv = 1.f / t;
    unsigned short* op = O + baseO + (size_t)(q0 + w * 16 + (l >> 4) * 4 + j) * Ee;
#pragma unroll
    for (int dsb = 0; dsb < 4; ++dsb)
      op[dsb * 16 + (l & 15)] = f2b(acc_o[dsb][j] * inv);
  }
}

extern "C" void kernel_launch(void* const* d_in, const int* in_sizes, int n_in,
                              void* d_out, int out_size, void* d_ws, size_t ws_size,
                              hipStream_t stream) {
  (void)in_sizes; (void)n_in; (void)out_size; (void)ws_size;
  const float* src  = (const float*)d_in[0];
  const float* Wq   = (const float*)d_in[1];
  const float* Wk   = (const float*)d_in[2];
  const float* Wv   = (const float*)d_in[3];
  const float* Wo   = (const float*)d_in[4];
  const float* W1   = (const float*)d_in[5];
  const float* b1   = (const float*)d_in[6];
  const float* W2   = (const float*)d_in[7];
  const float* b2   = (const float*)d_in[8];
  const float* ln1w = (const float*)d_in[9];
  const float* ln1b = (const float*)d_in[10];
  const float* ln2w = (const float*)d_in[11];
  const float* ln2b = (const float*)d_in[12];
  float* out = (float*)d_out;

  char* ws = (char*)d_ws;
  size_t off = 0;
  auto alloc = [&](size_t bytes) { char* p = ws + off; off += bytes; return p; };
  unsigned short* wqkv = (unsigned short*)alloc((size_t)3 * Ee * Ee * 2);  // Wq|Wk|Wv rows
  unsigned short* wo16 = (unsigned short*)alloc((size_t)Ee * Ee * 2);
  unsigned short* w116 = (unsigned short*)alloc((size_t)2 * FFd * Ee * 2); // interleaved
  unsigned short* w216 = (unsigned short*)alloc((size_t)Ee * FFd * 2);
  unsigned short* h16  = (unsigned short*)alloc((size_t)NN * Ee * 2);
  unsigned short* qkv  = (unsigned short*)alloc((size_t)NN * 3 * Ee * 2);  // [row][3E]
  unsigned short* a16  = (unsigned short*)alloc((size_t)NN * Ee * 2);
  float* xbuf          = (float*)alloc((size_t)NN * Ee * 4);
  unsigned short* vT   = (unsigned short*)alloc((size_t)NN * Ee * 2);      // [b][h][64][T]
  unsigned short* f16  = qkv;  // reuse qkv+a16 region (32 MB) after attention done

  const float s2 = 0.125f * 1.4426950408889634f;  // 1/sqrt(D) * log2(e), folded into Wq

  dim3 blk(256);
  cvt_kernel<<<dim3(Ee * Ee / 1024), blk, 0, stream>>>(Wq, wqkv, Ee * Ee, s2);
  cvt_kernel<<<dim3(Ee * Ee / 1024), blk, 0, stream>>>(Wk, wqkv + Ee * Ee, Ee * Ee, 1.0f);
  cvt_kernel<<<dim3(Ee * Ee / 1024), blk, 0, stream>>>(Wv, wqkv + 2 * Ee * Ee, Ee * Ee, 1.0f);
  cvt_kernel<<<dim3(Ee * Ee / 1024), blk, 0, stream>>>(Wo, wo16, Ee * Ee, 1.0f);
  cvt_w1_kernel<<<dim3(2 * FFd * Ee / 1024), blk, 0, stream>>>(W1, w116);
  cvt_kernel<<<dim3(Ee * FFd / 1024), blk, 0, stream>>>(W2, w216, Ee * FFd, 1.0f);

  ln_kernel<<<dim3(NN), blk, 0, stream>>>(src, ln1w, ln1b, h16);

  // fused QKV projection: [4096,1024] x [3072,1024]^T -> [4096,3072]
  gemm_bt<0, 0, 128, 0><<<dim3(3 * Ee / 128, NN / 128), blk, 0, stream>>>(h16, wqkv, qkv, nullptr, nullptr, 3 * Ee, Ee);

  // V transpose: [t][h*64+d] -> vT[b][h][d][t]
  vt_kernel<<<dim3(Tt / 64, Bb * Hh), blk, 0, stream>>>(qkv, vT);

  attn_kernel<<<dim3(1024), blk, 0, stream>>>(qkv, qkv + Ee, vT, a16, 3 * Ee);

  // Wo projection + residual (BN=64: 512 blocks, 2/CU)
  gemm_bt<1, 0, 64, 0><<<dim3(Ee / 64, NN / 128), blk, 0, stream>>>(a16, wo16, xbuf, nullptr, src, Ee, Ee);

  ln_kernel<<<dim3(NN), blk, 0, stream>>>(xbuf, ln2w, ln2b, h16);

  // W1 (block-16 interleaved) + lane-local GEGLU epilogue -> f16 [4096][4096]
  gemm_bt<0, 0, 128, 1><<<dim3(2 * FFd / 128, NN / 128), blk, 0, stream>>>(h16, w116, f16, b1, nullptr, 2 * FFd, Ee);

  // W2 projection + bias + residual (BN=64: 512 blocks, 2/CU)
  gemm_bt<1, 1, 64, 0><<<dim3(Ee / 64, NN / 128), blk, 0, stream>>>(f16, w216, out, b2, xbuf, Ee, FFd);
}

// Round 12
// 301.996 us; speedup vs baseline: 1.7089x; 1.0441x over previous
//
#include <hip/hip_runtime.h>
#include <stdint.h>
#include <math.h>

#define DEVI __device__ __forceinline__

typedef __attribute__((ext_vector_type(8))) short sv8;
typedef __attribute__((ext_vector_type(4))) short sv4;
typedef __attribute__((ext_vector_type(4))) float fv4;

typedef __attribute__((address_space(1))) void av1_t;
typedef __attribute__((address_space(3))) void av3_t;

constexpr int Bb = 2, Tt = 2048, Ee = 1024, Hh = 16, Dd = 64, FFd = 4096;
constexpr int NN = Bb * Tt;  // 4096 token rows
constexpr float EPSv = 1e-5f;

#define WAIT_VM(n) asm volatile("s_waitcnt vmcnt(" #n ")" ::: "memory")

DEVI float b2f(unsigned short s) {
  union { unsigned u; float f; } v; v.u = ((unsigned)s) << 16; return v.f;
}
DEVI unsigned short f2b(float f) {
  union { float f; unsigned u; } v; v.f = f;
  return (unsigned short)((v.u + 0x7FFFu + ((v.u >> 16) & 1u)) >> 16);
}
DEVI unsigned short f2b_rtz(float f) {  // truncation: 1 VALU op (softmax P only)
  union { float f; unsigned u; } v; v.f = f;
  return (unsigned short)(v.u >> 16);
}

// global -> LDS direct (16B per lane). LDS dest must be wave-uniform base + lane*16.
DEVI void load_lds16(const void* g, void* s) {
  __builtin_amdgcn_global_load_lds((av1_t*)(unsigned long long)g,
                                   (av3_t*)(unsigned)(unsigned long long)s,
                                   16, 0, 0);
}

// ---------------- fp32 -> bf16 convert (optional scale fold) ----------------
__global__ __launch_bounds__(256) void cvt_kernel(const float* __restrict__ in,
                                                  unsigned short* __restrict__ out, int n,
                                                  float scale) {
  int i = (blockIdx.x * 256 + threadIdx.x) * 4;
  if (i >= n) return;
  float4 v = *(const float4*)(in + i);
  sv4 o;
  o[0] = (short)f2b(v.x * scale); o[1] = (short)f2b(v.y * scale);
  o[2] = (short)f2b(v.z * scale); o[3] = (short)f2b(v.w * scale);
  *(sv4*)(out + i) = o;
}

// -------- W1 convert, block-16 interleave: a-row r -> 32*(r>>4)+(r&15);
//          gate-row (r-FFd) -> 32*((r-FFd)>>4)+16+(r&15). Even 16-col fragment = a,
//          odd = gate, SAME output cols -> lane-local GEGLU in the GEMM epilogue.
__global__ __launch_bounds__(256) void cvt_w1_kernel(const float* __restrict__ in,
                                                     unsigned short* __restrict__ out) {
  int i = (blockIdx.x * 256 + threadIdx.x) * 4;  // flat over 2*FFd*Ee
  const int r = i >> 10, c = i & 1023;
  const int rp = (r < FFd) ? ((r >> 4) * 32 + (r & 15))
                           : (((r - FFd) >> 4) * 32 + 16 + (r & 15));
  float4 v = *(const float4*)(in + i);
  sv4 o;
  o[0] = (short)f2b(v.x); o[1] = (short)f2b(v.y);
  o[2] = (short)f2b(v.z); o[3] = (short)f2b(v.w);
  *(sv4*)(out + (size_t)rp * Ee + c) = o;
}

// ---------------- V transpose: qkv V-slice [t][h*64+d] -> vT[b][h][d][t] ----------
__global__ __launch_bounds__(256) void vt_kernel(const unsigned short* __restrict__ qkv,
                                                 unsigned short* __restrict__ vT) {
  const int bh = blockIdx.y;               // b*16+h
  const int b = bh >> 4, h = bh & 15;
  const int tt = blockIdx.x * 64;          // token tile
  const int tid = threadIdx.x;
  __shared__ unsigned short tile[64][65];  // +1 pad
  const int tr = tid >> 2, tc4 = (tid & 3) * 16;
  const unsigned short* src = qkv + (size_t)(b * Tt + tt + tr) * (3 * Ee) + 2 * Ee + h * 64 + tc4;
  const sv8 a0 = *(const sv8*)src;
  const sv8 a1 = *(const sv8*)(src + 8);
#pragma unroll
  for (int j = 0; j < 8; ++j) { tile[tr][tc4 + j] = a0[j]; tile[tr][tc4 + 8 + j] = a1[j]; }
  __syncthreads();
  unsigned short* dst = vT + ((size_t)bh * 64 + tr) * Tt + tt + tc4;
  sv8 o0, o1;
#pragma unroll
  for (int j = 0; j < 8; ++j) { o0[j] = (short)tile[tc4 + j][tr]; o1[j] = (short)tile[tc4 + 8 + j][tr]; }
  *(sv8*)dst = o0;
  *(sv8*)(dst + 8) = o1;
}

// ---------------- LayerNorm (fp32 in, bf16 out), one block per row ----------------
__global__ __launch_bounds__(256) void ln_kernel(const float* __restrict__ x,
                                                 const float* __restrict__ g,
                                                 const float* __restrict__ b,
                                                 unsigned short* __restrict__ out) {
  const int row = blockIdx.x, tid = threadIdx.x;
  const float4 v = *(const float4*)(x + (size_t)row * Ee + tid * 4);
  float s = v.x + v.y + v.z + v.w;
  float ss = v.x * v.x + v.y * v.y + v.z * v.z + v.w * v.w;
#pragma unroll
  for (int off = 32; off; off >>= 1) { s += __shfl_down(s, off); ss += __shfl_down(ss, off); }
  __shared__ float red[16];
  const int w = tid >> 6, l = tid & 63;
  if (l == 0) { red[w] = s; red[8 + w] = ss; }
  __syncthreads();
  s = red[0] + red[1] + red[2] + red[3];
  ss = red[8] + red[9] + red[10] + red[11];
  const float mean = s * (1.f / Ee);
  const float rstd = rsqrtf(ss * (1.f / Ee) - mean * mean + EPSv);
  const float4 gv = *(const float4*)(g + tid * 4);
  const float4 bv = *(const float4*)(b + tid * 4);
  sv4 o;
  o[0] = (short)f2b((v.x - mean) * rstd * gv.x + bv.x);
  o[1] = (short)f2b((v.y - mean) * rstd * gv.y + bv.y);
  o[2] = (short)f2b((v.z - mean) * rstd * gv.z + bv.z);
  o[3] = (short)f2b((v.w - mean) * rstd * gv.w + bv.w);
  *(sv4*)(out + (size_t)row * Ee + tid * 4) = o;
}

// ---------------- bf16 GEMM (128xBN, 4 waves) — QKV / Wo / W2 ----------------
// Depth-2 pipeline (R11 structure). Chunk swizzle (T2).
template <int OUTF32, int HASBIAS, int BN, int GEGLU>
__global__ __launch_bounds__(256) void gemm_bt(const unsigned short* __restrict__ A,
                                               const unsigned short* __restrict__ Bw,
                                               void* __restrict__ Cout,
                                               const float* __restrict__ bias,
                                               const float* __restrict__ res,
                                               int M, int K) {
  constexpr int NI = BN / 32;  // per-wave n-frags (wave covers BN/2 cols)
  __shared__ unsigned short lA[3][128 * 32];
  __shared__ unsigned short lB[3][BN * 32];
  const int tid = threadIdx.x;
  const int l = tid & 63, w = tid >> 6;
  const int wr = w >> 1, wc = w & 1;
  const int rowbase = blockIdx.y * 128, colbase = blockIdx.x * BN;

  const fv4 zero4 = {0.f, 0.f, 0.f, 0.f};
  fv4 acc[4][NI];
#pragma unroll
  for (int i = 0; i < 4; ++i)
#pragma unroll
    for (int j = 0; j < NI; ++j) acc[i][j] = zero4;

  const int c0 = tid, c1 = tid + 256;
  const int sw0 = ((c0 & 3) ^ ((c0 >> 3) & 3)) * 8;
  const int sw1 = ((c1 & 3) ^ ((c1 >> 3) & 3)) * 8;
  const unsigned short* Ag0 = A + (size_t)(rowbase + (c0 >> 2)) * K + sw0;
  const unsigned short* Ag1 = A + (size_t)(rowbase + (c1 >> 2)) * K + sw1;
  const unsigned short* Bg0 = Bw + (size_t)(colbase + (c0 >> 2)) * K + sw0;
  const unsigned short* Bg1 = Bw + (size_t)(colbase + ((BN == 128 ? c1 : c0) >> 2)) * K +
                              (BN == 128 ? sw1 : sw0);

  const int nk = K >> 5;

  auto stage = [&](int buf) {
    load_lds16(Ag0, lA[buf] + c0 * 8);
    load_lds16(Ag1, lA[buf] + c1 * 8);
    load_lds16(Bg0, lB[buf] + c0 * 8);
    if (BN == 128) load_lds16(Bg1, lB[buf] + c1 * 8);
    Ag0 += 32; Ag1 += 32; Bg0 += 32; Bg1 += 32;
  };

  stage(0);
  stage(1);
  if constexpr (BN == 128) WAIT_VM(4); else WAIT_VM(3);
  __builtin_amdgcn_s_barrier();

  int cur = 0;
  for (int t = 0; t < nk; ++t) {
    const int pf = (cur + 2 >= 3) ? cur - 1 : cur + 2;  // (cur+2)%3
    if (t + 2 < nk) stage(pf);
    sv8 af[4], bfr[NI];
#pragma unroll
    for (int i = 0; i < 4; ++i) {
      const int ra = wr * 64 + i * 16 + (l & 15);
      af[i] = *(const sv8*)(lA[cur] + ra * 32 + (((l >> 4) ^ ((ra >> 1) & 3)) * 8));
    }
#pragma unroll
    for (int i = 0; i < NI; ++i) {
      const int rb = wc * (BN / 2) + i * 16 + (l & 15);
      bfr[i] = *(const sv8*)(lB[cur] + rb * 32 + (((l >> 4) ^ ((rb >> 1) & 3)) * 8));
    }
    __builtin_amdgcn_s_setprio(1);
#pragma unroll
    for (int mi = 0; mi < 4; ++mi)
#pragma unroll
      for (int ni = 0; ni < NI; ++ni)
        acc[mi][ni] = __builtin_amdgcn_mfma_f32_16x16x32_bf16(af[mi], bfr[ni], acc[mi][ni], 0, 0, 0);
    __builtin_amdgcn_s_setprio(0);
    if (t + 2 < nk) {
      if constexpr (BN == 128) WAIT_VM(4); else WAIT_VM(3);
      __builtin_amdgcn_s_barrier();
    } else if (t + 1 < nk) {
      WAIT_VM(0);
      __builtin_amdgcn_s_barrier();
    }
    cur = (cur + 1 >= 3) ? 0 : cur + 1;
  }

  const int r0 = rowbase + wr * 64 + ((l >> 4) * 4);
  const int ccol = colbase + wc * (BN / 2) + (l & 15);
#pragma unroll
  for (int mi = 0; mi < 4; ++mi) {
#pragma unroll
    for (int j = 0; j < 4; ++j) {
      const size_t r = (size_t)(r0 + mi * 16 + j);
      if (GEGLU) {
#pragma unroll
        for (int p = 0; p < NI / 2; ++p) {
          const int ca = ccol + p * 32;
          const int ocol = ((ca >> 5) << 4) | (ca & 15);
          const float av = acc[mi][2 * p][j] + bias[ocol];
          const float gv = acc[mi][2 * p + 1][j] + bias[ocol + (M >> 1)];
          const float y = 0.7978845608028654f * (gv + 0.044715f * gv * gv * gv);
          const float e = exp2f(2.8853900817779268f * y);
          const float gel = gv * (1.f - 1.f / (e + 1.f));
          ((unsigned short*)Cout)[r * (size_t)(M >> 1) + ocol] = f2b(av * gel);
        }
      } else {
#pragma unroll
        for (int ni = 0; ni < NI; ++ni) {
          const int c = ccol + ni * 16;
          float vv = acc[mi][ni][j];
          if (HASBIAS) vv += bias[c];
          if (OUTF32) {
            ((float*)Cout)[r * M + c] = res[r * M + c] + vv;
          } else {
            ((unsigned short*)Cout)[r * M + c] = f2b(vv);
          }
        }
      }
    }
  }
}

// ---------------- 256x256 phase-interleaved bf16 GEMM (T2+T3+T4+T5) — W1 ----------
// 512 threads = 8 waves (2 Mrow x 4 Ncol); per-wave output 128x64; BK=64 split into
// 2 K-halves per operand. LDS = 2 ops x 2 dbuf x 2 khalf x [256x32] = 128 KB.
// Staging quantum = one 16KB half (2 global_load_lds/thread), fixed order A0,B0,A1,B1.
// Per K-tile, 4 phases x 16 MFMA. Counted waits: each phase's required half is exactly
// 4 stage-issues old -> vmcnt(4)+s_barrier at ph0/ph2 ONLY; 2 halves always in flight
// across barriers (never drained mid-loop; tail tile uses vmcnt(0) at ph2).
// LDS chunk swizzle: chunk' = c ^ ((r>>1)&3) (per-lane constant on read side) ->
// conflict-free b128 reads; realized via pre-swizzled global source (rule #21).
template <int GEGLU>
__global__ __launch_bounds__(512, 2) void gemm256(const unsigned short* __restrict__ A,
                                                  const unsigned short* __restrict__ Bw,
                                                  void* __restrict__ Cout,
                                                  const float* __restrict__ bias,
                                                  int M, int K) {
  __shared__ unsigned short Ah[2][2][256 * 32];  // [dbuf][khalf]
  __shared__ unsigned short Bh[2][2][256 * 32];
  const int tid = threadIdx.x;
  const int l = tid & 63, w = tid >> 6;
  const int wrow = w >> 2, wcol = w & 3;   // 2 x 4 wave grid
  const int nbase = blockIdx.y * 256, mbase = blockIdx.x * 256;

  const fv4 zero4 = {0.f, 0.f, 0.f, 0.f};
  fv4 acc[8][4];
#pragma unroll
  for (int i = 0; i < 8; ++i)
#pragma unroll
    for (int j = 0; j < 4; ++j) acc[i][j] = zero4;

  // staging: each half = 1024 slots of 16B; thread handles slots tid and tid+512.
  const int s0 = tid, s1 = tid + 512;
  const int r0 = s0 >> 2, x0 = (((s0 & 3) ^ ((r0 >> 1) & 3))) * 8;
  const int r1 = s1 >> 2, x1 = (((s1 & 3) ^ ((r1 >> 1) & 3))) * 8;
  const unsigned short* As0 = A + (size_t)(nbase + r0) * K + x0;
  const unsigned short* As1 = A + (size_t)(nbase + r1) * K + x1;
  const unsigned short* Bs0 = Bw + (size_t)(mbase + r0) * K + x0;
  const unsigned short* Bs1 = Bw + (size_t)(mbase + r1) * K + x1;

  const int nk = K >> 6;

  auto stA = [&](int db, int kh, int kof) {
    load_lds16(As0 + kof + kh * 32, &Ah[db][kh][s0 * 8]);
    load_lds16(As1 + kof + kh * 32, &Ah[db][kh][s1 * 8]);
  };
  auto stB = [&](int db, int kh, int kof) {
    load_lds16(Bs0 + kof + kh * 32, &Bh[db][kh][s0 * 8]);
    load_lds16(Bs1 + kof + kh * 32, &Bh[db][kh][s1 * 8]);
  };

  // ds_read bases (elems): per-lane chunk position is LANE-CONSTANT:
  // chunk' = (l>>4) ^ ((r>>1)&3), and (r>>1)&3 == (l>>1)&3 since frag row = 16m+(l&15).
  const int cl = (((l >> 4) ^ ((l >> 1) & 3))) * 8;
  const int arl = (wrow * 128 + (l & 15)) * 32 + cl;
  const int brl = (wcol * 64 + (l & 15)) * 32 + cl;

  // prologue: tile 0's four halves, in the canonical order A0,B0,A1,B1
  stA(0, 0, 0); stB(0, 0, 0); stA(0, 1, 0); stB(0, 1, 0);

  for (int t = 0; t < nk; ++t) {
    const int st = t & 1, sf = st ^ 1;
    const int kof = (t + 1) * 64;
    const bool pre = (t + 1 < nk);
    sv8 af[8], b0, b1;

    // ---- ph0: gate on A0,B0 of tile t; stage A0(t+1); MFMA ks0 x ni0-1 ----
    WAIT_VM(4);
    __builtin_amdgcn_s_barrier();
    __builtin_amdgcn_sched_barrier(0);
    if (pre) stA(sf, 0, kof);
#pragma unroll
    for (int mi = 0; mi < 8; ++mi) af[mi] = *(const sv8*)(&Ah[st][0][arl + mi * 512]);
    b0 = *(const sv8*)(&Bh[st][0][brl]);
    b1 = *(const sv8*)(&Bh[st][0][brl + 512]);
    __builtin_amdgcn_s_setprio(1);
#pragma unroll
    for (int mi = 0; mi < 8; ++mi) {
      acc[mi][0] = __builtin_amdgcn_mfma_f32_16x16x32_bf16(af[mi], b0, acc[mi][0], 0, 0, 0);
      acc[mi][1] = __builtin_amdgcn_mfma_f32_16x16x32_bf16(af[mi], b1, acc[mi][1], 0, 0, 0);
    }
    __builtin_amdgcn_s_setprio(0);

    // ---- ph1: stage B0(t+1); MFMA ks0 x ni2-3 (af reused) ----
    if (pre) stB(sf, 0, kof);
    b0 = *(const sv8*)(&Bh[st][0][brl + 2 * 512]);
    b1 = *(const sv8*)(&Bh[st][0][brl + 3 * 512]);
    __builtin_amdgcn_s_setprio(1);
#pragma unroll
    for (int mi = 0; mi < 8; ++mi) {
      acc[mi][2] = __builtin_amdgcn_mfma_f32_16x16x32_bf16(af[mi], b0, acc[mi][2], 0, 0, 0);
      acc[mi][3] = __builtin_amdgcn_mfma_f32_16x16x32_bf16(af[mi], b1, acc[mi][3], 0, 0, 0);
    }
    __builtin_amdgcn_s_setprio(0);

    // ---- ph2: gate on A1,B1 of tile t; stage A1(t+1); MFMA ks1 x ni0-1 ----
    if (pre) { WAIT_VM(4); } else { WAIT_VM(0); }
    __builtin_amdgcn_s_barrier();
    __builtin_amdgcn_sched_barrier(0);
    if (pre) stA(sf, 1, kof);
#pragma unroll
    for (int mi = 0; mi < 8; ++mi) af[mi] = *(const sv8*)(&Ah[st][1][arl + mi * 512]);
    b0 = *(const sv8*)(&Bh[st][1][brl]);
    b1 = *(const sv8*)(&Bh[st][1][brl + 512]);
    __builtin_amdgcn_s_setprio(1);
#pragma unroll
    for (int mi = 0; mi < 8; ++mi) {
      acc[mi][0] = __builtin_amdgcn_mfma_f32_16x16x32_bf16(af[mi], b0, acc[mi][0], 0, 0, 0);
      acc[mi][1] = __builtin_amdgcn_mfma_f32_16x16x32_bf16(af[mi], b1, acc[mi][1], 0, 0, 0);
    }
    __builtin_amdgcn_s_setprio(0);

    // ---- ph3: stage B1(t+1); MFMA ks1 x ni2-3 ----
    if (pre) stB(sf, 1, kof);
    b0 = *(const sv8*)(&Bh[st][1][brl + 2 * 512]);
    b1 = *(const sv8*)(&Bh[st][1][brl + 3 * 512]);
    __builtin_amdgcn_s_setprio(1);
#pragma unroll
    for (int mi = 0; mi < 8; ++mi) {
      acc[mi][2] = __builtin_amdgcn_mfma_f32_16x16x32_bf16(af[mi], b0, acc[mi][2], 0, 0, 0);
      acc[mi][3] = __builtin_amdgcn_mfma_f32_16x16x32_bf16(af[mi], b1, acc[mi][3], 0, 0, 0);
    }
    __builtin_amdgcn_s_setprio(0);
  }

  // ---- epilogue: C/D layout col=lane&15, row=(l>>4)*4+j ----
  const int rbase = nbase + wrow * 128 + ((l >> 4) * 4);
  const int cbase = mbase + wcol * 64 + (l & 15);
#pragma unroll
  for (int mi = 0; mi < 8; ++mi) {
#pragma unroll
    for (int j = 0; j < 4; ++j) {
      const size_t r = (size_t)(rbase + mi * 16 + j);
      if (GEGLU) {
#pragma unroll
        for (int p = 0; p < 2; ++p) {
          const int ca = cbase + p * 32;                   // even fragment (a); bit4 == 0
          const int ocol = ((ca >> 5) << 4) | (ca & 15);   // original column
          const float av = acc[mi][2 * p][j] + bias[ocol];
          const float gv = acc[mi][2 * p + 1][j] + bias[ocol + (M >> 1)];
          const float y = 0.7978845608028654f * (gv + 0.044715f * gv * gv * gv);
          const float e = exp2f(2.8853900817779268f * y);  // exp(2y)
          const float gel = gv * (1.f - 1.f / (e + 1.f));  // == 0.5*g*(1+tanh(y))
          ((unsigned short*)Cout)[r * (size_t)(M >> 1) + ocol] = f2b(av * gel);
        }
      } else {
#pragma unroll
        for (int ni = 0; ni < 4; ++ni) {
          const int c = cbase + ni * 16;
          ((unsigned short*)Cout)[r * (size_t)M + c] = f2b(acc[mi][ni][j]);
        }
      }
    }
  }
}

// ---------------- flash attention (unchanged from R11) ----------------
__global__ __launch_bounds__(256) void attn_kernel(const unsigned short* __restrict__ Q,
                                                   const unsigned short* __restrict__ Kb,
                                                   const unsigned short* __restrict__ vT,
                                                   unsigned short* __restrict__ O,
                                                   int ld) {
  const int bidl = ((blockIdx.x & 7) << 7) + (blockIdx.x >> 3);  // 1024 = 8 XCD x 128
  const int bh = bidl >> 5;
  const int b = bh / Hh, h = bh % Hh;
  const int q0 = (bidl & 31) * 64;
  const int tid = threadIdx.x, l = tid & 63, w = tid >> 6;
  const size_t base = (size_t)b * Tt * ld + (size_t)h * Dd;
  const size_t baseO = (size_t)b * Tt * Ee + (size_t)h * Dd;
  const unsigned short* vTb = vT + (size_t)bh * 64 * Tt;  // [64 d][2048 t]

  __shared__ unsigned short Kt[2][64 * 64];
  __shared__ unsigned short Vt[2][64 * 64];
  __shared__ unsigned short Pt[4][16 * 64];

  sv8 qf0, qf1;
  {
    const unsigned short* qp = Q + base + (size_t)(q0 + w * 16 + (l & 15)) * ld + (l >> 4) * 8;
    qf0 = *(const sv8*)qp;
    qf1 = *(const sv8*)(qp + 32);
  }

  const fv4 zero4 = {0.f, 0.f, 0.f, 0.f};
  fv4 acc_o[4];
#pragma unroll
  for (int i = 0; i < 4; ++i) acc_o[i] = zero4;
  float Mx = -INFINITY;
  float Lp[4];
#pragma unroll
  for (int j = 0; j < 4; ++j) Lp[j] = 0.f;

  const int c0 = tid, c1 = tid + 256;
  const int r0c = c0 >> 3, xc0 = c0 & 7;
  const int r1c = c1 >> 3, xc1 = c1 & 7;

  load_lds16(Kb + base + (size_t)(r0c)*ld + (xc0 ^ (r0c & 7)) * 8, Kt[0] + c0 * 8);
  load_lds16(Kb + base + (size_t)(r1c)*ld + (xc1 ^ (r1c & 7)) * 8, Kt[0] + c1 * 8);
  load_lds16(vTb + (size_t)(r0c)*Tt + (xc0 ^ (r0c & 7)) * 8, Vt[0] + c0 * 8);
  load_lds16(vTb + (size_t)(r1c)*Tt + (xc1 ^ (r1c & 7)) * 8, Vt[0] + c1 * 8);
  __syncthreads();

  int cur = 0;
  for (int kt = 0; kt < Tt / 64; ++kt) {
    const int nx = cur ^ 1;
    if (kt + 1 < Tt / 64) {
      load_lds16(Kb + base + (size_t)((kt + 1) * 64 + r0c) * ld + (xc0 ^ (r0c & 7)) * 8, Kt[nx] + c0 * 8);
      load_lds16(Kb + base + (size_t)((kt + 1) * 64 + r1c) * ld + (xc1 ^ (r1c & 7)) * 8, Kt[nx] + c1 * 8);
      load_lds16(vTb + (size_t)(r0c)*Tt + (kt + 1) * 64 + (xc0 ^ (r0c & 7)) * 8, Vt[nx] + c0 * 8);
      load_lds16(vTb + (size_t)(r1c)*Tt + (kt + 1) * 64 + (xc1 ^ (r1c & 7)) * 8, Vt[nx] + c1 * 8);
    }

    fv4 s[4];
    __builtin_amdgcn_s_setprio(1);
#pragma unroll
    for (int ks = 0; ks < 4; ++ks) {
      const int row = ks * 16 + (l & 15);
      const sv8 kf0 = *(const sv8*)(Kt[cur] + row * 64 + (((l >> 4) ^ (row & 7)) * 8));
      const sv8 kf1 = *(const sv8*)(Kt[cur] + row * 64 + (((4 + (l >> 4)) ^ (row & 7)) * 8));
      fv4 t = zero4;
      t = __builtin_amdgcn_mfma_f32_16x16x32_bf16(qf0, kf0, t, 0, 0, 0);
      t = __builtin_amdgcn_mfma_f32_16x16x32_bf16(qf1, kf1, t, 0, 0, 0);
      s[ks] = t;
    }
    __builtin_amdgcn_s_setprio(0);

    float m01 = fmaxf(fmaxf(s[0][0], s[0][1]), fmaxf(s[0][2], s[0][3]));
    float m1 = fmaxf(fmaxf(s[1][0], s[1][1]), fmaxf(s[1][2], s[1][3]));
    float m2 = fmaxf(fmaxf(s[2][0], s[2][1]), fmaxf(s[2][2], s[2][3]));
    float m3 = fmaxf(fmaxf(s[3][0], s[3][1]), fmaxf(s[3][2], s[3][3]));
    float tm = fmaxf(fmaxf(m01, m1), fmaxf(m2, m3));
    if (__any(tm > Mx + 11.5f)) {
      float mt = tm;
#pragma unroll
      for (int off = 1; off < 16; off <<= 1) mt = fmaxf(mt, __shfl_xor(mt, off, 16));
      const float mnew = fmaxf(Mx, mt);
      const float alpha = exp2f(Mx - mnew);
      Mx = mnew;
#pragma unroll
      for (int j = 0; j < 4; ++j) {
        Lp[j] *= alpha;
#pragma unroll
        for (int dsb = 0; dsb < 4; ++dsb) acc_o[dsb][j] *= alpha;
      }
    }
#pragma unroll
    for (int ks = 0; ks < 4; ++ks)
#pragma unroll
      for (int j = 0; j < 4; ++j) {
        const float p = exp2f(s[ks][j] - Mx);
        s[ks][j] = p;
        Lp[j] += p;
      }
#pragma unroll
    for (int ks = 0; ks < 4; ++ks)
#pragma unroll
      for (int j = 0; j < 4; ++j) {
        const int q = (l >> 4) * 4 + j, k = ks * 16 + (l & 15);
        Pt[w][q * 64 + ((((k >> 3) ^ (q & 7)) & 7) * 8) + (k & 7)] = f2b_rtz(s[ks][j]);
      }
    asm volatile("s_waitcnt lgkmcnt(0)" ::: "memory");

    __builtin_amdgcn_s_setprio(1);
#pragma unroll
    for (int kcn = 0; kcn < 2; ++kcn) {
      const int qr = l & 15;
      const sv8 pf = *(const sv8*)(&Pt[w][qr * 64 + (((kcn * 4 + (l >> 4)) ^ (qr & 7)) * 8)]);
#pragma unroll
      for (int dsb = 0; dsb < 4; ++dsb) {
        const int row = dsb * 16 + (l & 15);
        const int chunk = kcn * 4 + (l >> 4);
        const sv8 vf = *(const sv8*)(Vt[cur] + row * 64 + ((chunk ^ (row & 7)) * 8));
        acc_o[dsb] = __builtin_amdgcn_mfma_f32_16x16x32_bf16(pf, vf, acc_o[dsb], 0, 0, 0);
      }
    }
    __builtin_amdgcn_s_setprio(0);

    __syncthreads();
    cur = nx;
  }

#pragma unroll
  for (int j = 0; j < 4; ++j) {
    float t = Lp[j];
#pragma unroll
    for (int off = 1; off < 16; off <<= 1) t += __shfl_xor(t, off, 16);
    const float inv = 1.f / t;
    unsigned short* op = O + baseO + (size_t)(q0 + w * 16 + (l >> 4) * 4 + j) * Ee;
#pragma unroll
    for (int dsb = 0; dsb < 4; ++dsb)
      op[dsb * 16 + (l & 15)] = f2b(acc_o[dsb][j] * inv);
  }
}

extern "C" void kernel_launch(void* const* d_in, const int* in_sizes, int n_in,
                              void* d_out, int out_size, void* d_ws, size_t ws_size,
                              hipStream_t stream) {
  (void)in_sizes; (void)n_in; (void)out_size; (void)ws_size;
  const float* src  = (const float*)d_in[0];
  const float* Wq   = (const float*)d_in[1];
  const float* Wk   = (const float*)d_in[2];
  const float* Wv   = (const float*)d_in[3];
  const float* Wo   = (const float*)d_in[4];
  const float* W1   = (const float*)d_in[5];
  const float* b1   = (const float*)d_in[6];
  const float* W2   = (const float*)d_in[7];
  const float* b2   = (const float*)d_in[8];
  const float* ln1w = (const float*)d_in[9];
  const float* ln1b = (const float*)d_in[10];
  const float* ln2w = (const float*)d_in[11];
  const float* ln2b = (const float*)d_in[12];
  float* out = (float*)d_out;

  char* ws = (char*)d_ws;
  size_t off = 0;
  auto alloc = [&](size_t bytes) { char* p = ws + off; off += bytes; return p; };
  unsigned short* wqkv = (unsigned short*)alloc((size_t)3 * Ee * Ee * 2);  // Wq|Wk|Wv rows
  unsigned short* wo16 = (unsigned short*)alloc((size_t)Ee * Ee * 2);
  unsigned short* w116 = (unsigned short*)alloc((size_t)2 * FFd * Ee * 2); // interleaved
  unsigned short* w216 = (unsigned short*)alloc((size_t)Ee * FFd * 2);
  unsigned short* h16  = (unsigned short*)alloc((size_t)NN * Ee * 2);
  unsigned short* qkv  = (unsigned short*)alloc((size_t)NN * 3 * Ee * 2);  // [row][3E]
  unsigned short* a16  = (unsigned short*)alloc((size_t)NN * Ee * 2);
  float* xbuf          = (float*)alloc((size_t)NN * Ee * 4);
  unsigned short* vT   = (unsigned short*)alloc((size_t)NN * Ee * 2);      // [b][h][64][T]
  unsigned short* f16  = qkv;  // reuse qkv+a16 region (32 MB) after attention done

  const float s2 = 0.125f * 1.4426950408889634f;  // 1/sqrt(D) * log2(e), folded into Wq

  dim3 blk(256);
  cvt_kernel<<<dim3(Ee * Ee / 1024), blk, 0, stream>>>(Wq, wqkv, Ee * Ee, s2);
  cvt_kernel<<<dim3(Ee * Ee / 1024), blk, 0, stream>>>(Wk, wqkv + Ee * Ee, Ee * Ee, 1.0f);
  cvt_kernel<<<dim3(Ee * Ee / 1024), blk, 0, stream>>>(Wv, wqkv + 2 * Ee * Ee, Ee * Ee, 1.0f);
  cvt_kernel<<<dim3(Ee * Ee / 1024), blk, 0, stream>>>(Wo, wo16, Ee * Ee, 1.0f);
  cvt_w1_kernel<<<dim3(2 * FFd * Ee / 1024), blk, 0, stream>>>(W1, w116);
  cvt_kernel<<<dim3(Ee * FFd / 1024), blk, 0, stream>>>(W2, w216, Ee * FFd, 1.0f);

  ln_kernel<<<dim3(NN), blk, 0, stream>>>(src, ln1w, ln1b, h16);

  // fused QKV projection: [4096,1024] x [3072,1024]^T -> [4096,3072]
  gemm_bt<0, 0, 128, 0><<<dim3(3 * Ee / 128, NN / 128), blk, 0, stream>>>(h16, wqkv, qkv, nullptr, nullptr, 3 * Ee, Ee);

  // V transpose: [t][h*64+d] -> vT[b][h][d][t]
  vt_kernel<<<dim3(Tt / 64, Bb * Hh), blk, 0, stream>>>(qkv, vT);

  attn_kernel<<<dim3(1024), blk, 0, stream>>>(qkv, qkv + Ee, vT, a16, 3 * Ee);

  // Wo projection + residual (BN=64: 512 blocks, 2/CU)
  gemm_bt<1, 0, 64, 0><<<dim3(Ee / 64, NN / 128), blk, 0, stream>>>(a16, wo16, xbuf, nullptr, src, Ee, Ee);

  ln_kernel<<<dim3(NN), blk, 0, stream>>>(xbuf, ln2w, ln2b, h16);

  // W1 (block-16 interleaved) + lane-local GEGLU, 256x256 phase-interleaved kernel
  gemm256<1><<<dim3(2 * FFd / 256, NN / 256), dim3(512), 0, stream>>>(h16, w116, f16, b1, 2 * FFd, Ee);

  // W2 projection + bias + residual (BN=64: 512 blocks, 2/CU)
  gemm_bt<1, 1, 64, 0><<<dim3(Ee / 64, NN / 128), blk, 0, stream>>>(f16, w216, out, b2, xbuf, Ee, FFd);
}